// Round 1
// baseline (2527.833 us; speedup 1.0000x reference)
//
#include <hip/hip_runtime.h>

typedef _Float16 f16;
typedef _Float16 h4v __attribute__((ext_vector_type(4)));

// ---------------------------------------------------------------- cast f32->f16
__global__ __launch_bounds__(256) void cast_k(f16* __restrict__ dst, const float* __restrict__ src, int n){
  for (int i = blockIdx.x*256 + threadIdx.x; i < n; i += gridDim.x*256)
    dst[i] = (f16)src[i];
}

// ---------------------------------------------------------------- conv1 (fused binarize)
// in: rgb (B,15000) f32 ; out a1 (Bc,24,98,36) f16. grid=Bc, block=256
__global__ __launch_bounds__(256) void conv1_k(const float* __restrict__ rgb, const float* __restrict__ w1,
                                               const float* __restrict__ b1, f16* __restrict__ a1, int ib){
  __shared__ __align__(16) f16 xi[15000];   // [h=200][w=75]
  __shared__ float wl[600];
  __shared__ float bl[24];
  const int tid = threadIdx.x;
  const int i = blockIdx.x;
  const float* img = rgb + (size_t)(ib + i)*15000;
  for (int q = tid; q < 15000; q += 256){
    float v = img[q];                 // q = a*200 + b ; a in [0,75), b in [0,200)
    int a = q/200, b = q - a*200;     // x[h=b][w=a]
    xi[b*75 + a] = (v > 0.f) ? (f16)1.0f : (f16)0.0f;
  }
  for (int j = tid; j < 600; j += 256) wl[j] = w1[j];
  if (tid < 24) bl[tid] = b1[tid];
  __syncthreads();
  for (int task = tid; task < 5292; task += 256){   // 6 co-groups x 882 sp-groups
    int sp_g = task % 882;
    int co_g = task / 882;            // 0..5 -> 4 co each
    int oh[4], ow[4];
    #pragma unroll
    for (int u=0;u<4;++u){ int p = sp_g*4+u; oh[u] = p/36; ow[u] = p - oh[u]*36; }
    float acc[4][4] = {};
    #pragma unroll 1
    for (int kh=0; kh<5; ++kh){
      #pragma unroll
      for (int kw=0; kw<5; ++kw){
        float wv[4];
        #pragma unroll
        for (int c=0;c<4;++c) wv[c] = wl[(co_g*4+c)*25 + kh*5 + kw];
        #pragma unroll
        for (int u=0;u<4;++u){
          float x = (float)xi[(2*oh[u]+kh)*75 + 2*ow[u]+kw];
          #pragma unroll
          for (int c=0;c<4;++c) acc[c][u] = fmaf(x, wv[c], acc[c][u]);
        }
      }
    }
    #pragma unroll
    for (int c=0;c<4;++c){
      float bb = bl[co_g*4+c];
      #pragma unroll
      for (int u=0;u<4;++u){
        float r = acc[c][u] + bb; if (r < 0.f) r = 0.f;
        a1[((size_t)i*24 + co_g*4+c)*3528 + oh[u]*36 + ow[u]] = (f16)r;
      }
    }
  }
}

// ---------------------------------------------------------------- conv2
// in a1 (Bc,24,98,36) f16 ; out a2 (Bc,36,47,16) f16. grid=Bc*6 (oh tiles of 8), block=192
__global__ __launch_bounds__(192) void conv2_k(const f16* __restrict__ a1, const f16* __restrict__ w2h,
                                               const float* __restrict__ b2, f16* __restrict__ a2){
  __shared__ __align__(16) f16 xt[16416];   // [24][19][36]
  __shared__ __align__(16) f16 wl[21600];   // [36][24][5][5]
  __shared__ float bl[36];
  const int tid = threadIdx.x;
  const int bx = blockIdx.x;
  const int i = bx / 6, t = bx - i*6;
  const int oh0 = t*8;
  const int ohn = (t==5) ? 7 : 8;
  const int r0 = 2*oh0;
  {
    const uint* src = (const uint*)a1;
    uint* d = (uint*)xt;
    for (int idx = tid; idx < 8208; idx += 192){
      int ci = idx / 342, rem = idx - ci*342;
      int rr = rem / 18, w2 = rem - rr*18;
      int r = r0 + rr;
      d[idx] = (r < 98) ? src[((size_t)i*24 + ci)*1764 + (size_t)r*18 + w2] : 0u;
    }
  }
  {
    const uint* src = (const uint*)w2h;
    uint* d = (uint*)wl;
    for (int j = tid; j < 10800; j += 192) d[j] = src[j];
  }
  if (tid < 36) bl[tid] = b2[tid];
  __syncthreads();
  const int co_g = tid >> 4;          // 0..11, 3 co each
  const int sp_g = tid & 15;
  const int oh_l = sp_g >> 1;
  const int ow0 = (sp_g & 1) * 8;
  if (oh_l < ohn){
    const int co0 = co_g*3;
    float acc[3][8];
    #pragma unroll
    for (int c=0;c<3;++c){ float bb = bl[co0+c];
      #pragma unroll
      for (int j=0;j<8;++j) acc[c][j] = bb; }
    #pragma unroll 1
    for (int ci=0; ci<24; ++ci){
      #pragma unroll 1
      for (int kh=0; kh<5; ++kh){
        const int rr = 2*oh_l + kh;
        const int base = ci*684 + rr*36 + 2*ow0;     // 8B-aligned (ci*1368 + rr*72 + 4*ow0 bytes)
        float in[19];
        {
          const h4v* p = (const h4v*)&xt[base];
          #pragma unroll
          for (int m=0;m<4;++m){ h4v v = p[m];
            in[4*m+0]=(float)v.x; in[4*m+1]=(float)v.y; in[4*m+2]=(float)v.z; in[4*m+3]=(float)v.w; }
          const f16* q = &xt[base];
          in[16]=(float)q[16]; in[17]=(float)q[17]; in[18]=(float)q[18];
        }
        float wt[3][5];
        #pragma unroll
        for (int c=0;c<3;++c)
          #pragma unroll
          for (int kw=0;kw<5;++kw)
            wt[c][kw] = (float)wl[(co0+c)*600 + ci*25 + kh*5 + kw];
        #pragma unroll
        for (int kw=0;kw<5;++kw){
          #pragma unroll
          for (int j=0;j<8;++j){
            float x = in[2*j+kw];
            acc[0][j] = fmaf(x, wt[0][kw], acc[0][j]);
            acc[1][j] = fmaf(x, wt[1][kw], acc[1][j]);
            acc[2][j] = fmaf(x, wt[2][kw], acc[2][j]);
          }
        }
      }
    }
    #pragma unroll
    for (int c=0;c<3;++c)
      #pragma unroll
      for (int j=0;j<8;++j){
        float r = acc[c][j]; if (r<0.f) r=0.f;
        a2[((size_t)i*36 + co0+c)*752 + (size_t)(oh0+oh_l)*16 + ow0 + j] = (f16)r;
      }
  }
}

// ---------------------------------------------------------------- conv3
// in a2 (Bc,36,47,16) ; out a3 (Bc,48,22,6). grid=Bc*4 (2 co-halves x 2 oh tiles), block=128
__global__ __launch_bounds__(128) void conv3_k(const f16* __restrict__ a2, const f16* __restrict__ w3h,
                                               const float* __restrict__ b3, f16* __restrict__ a3){
  __shared__ __align__(16) f16 xt[14400];  // [36][25][16]
  __shared__ __align__(16) f16 wl[21600];  // [24][900]
  __shared__ float bl[24];
  const int tid = threadIdx.x;
  const int bx = blockIdx.x;
  const int i  = bx >> 2;
  const int ch = (bx >> 1) & 1;
  const int t  = bx & 1;
  const int oh0 = t*11, r0 = t*22;
  {
    const uint* src = (const uint*)a2;
    uint* d = (uint*)xt;
    for (int idx = tid; idx < 7200; idx += 128){
      int ci = idx / 200, rem = idx - ci*200;        // rem = rr*8 + w2
      d[idx] = src[((size_t)i*36 + ci)*376 + (size_t)r0*8 + rem];
    }
  }
  {
    const uint* src = (const uint*)w3h + (size_t)ch*10800;
    uint* d = (uint*)wl;
    for (int j = tid; j < 10800; j += 128) d[j] = src[j];
  }
  if (tid < 24) bl[tid] = b3[ch*24 + tid];
  __syncthreads();
  for (int task = tid; task < 132; task += 128){
    const int co_g = task % 6;   // 4 co each
    const int sp_g = task / 6;   // 0..21, 3 sp each
    int oh_[3], ow_[3];
    #pragma unroll
    for (int u=0;u<3;++u){ int sp = sp_g*3+u; oh_[u] = sp/6; ow_[u] = sp - oh_[u]*6; }
    float acc[4][3] = {};
    #pragma unroll 1
    for (int ci=0; ci<36; ++ci){
      #pragma unroll 1
      for (int kh=0; kh<5; ++kh){
        float in[3][5];
        #pragma unroll
        for (int u=0;u<3;++u){
          const f16* q = &xt[ci*400 + (2*oh_[u]+kh)*16 + 2*ow_[u]];
          #pragma unroll
          for (int kw=0;kw<5;++kw) in[u][kw] = (float)q[kw];
        }
        float wt[4][5];
        #pragma unroll
        for (int c=0;c<4;++c)
          #pragma unroll
          for (int kw=0;kw<5;++kw)
            wt[c][kw] = (float)wl[(co_g*4+c)*900 + ci*25 + kh*5 + kw];
        #pragma unroll
        for (int c=0;c<4;++c)
          #pragma unroll
          for (int u=0;u<3;++u){
            float s = acc[c][u];
            #pragma unroll
            for (int kw=0;kw<5;++kw) s = fmaf(in[u][kw], wt[c][kw], s);
            acc[c][u] = s;
          }
      }
    }
    #pragma unroll
    for (int c=0;c<4;++c){
      float bb = bl[co_g*4+c];
      #pragma unroll
      for (int u=0;u<3;++u){
        float r = acc[c][u] + bb; if (r<0.f) r=0.f;
        a3[((size_t)i*48 + ch*24 + co_g*4+c)*132 + (size_t)(oh0+oh_[u])*6 + ow_[u]] = (f16)r;
      }
    }
  }
}

// ---------------------------------------------------------------- conv4
// in a3 (Bc,48,22,6) ; out a4 (Bc,64,20,4)=(Bc,5120). grid=Bc, block=256
__global__ __launch_bounds__(256) void conv4_k(const f16* __restrict__ a3, const f16* __restrict__ w4h,
                                               const float* __restrict__ b4, f16* __restrict__ a4){
  __shared__ __align__(16) f16 xt[6336];
  __shared__ __align__(16) f16 wl[27648];
  __shared__ float bl[64];
  const int tid = threadIdx.x;
  const int i = blockIdx.x;
  {
    const uint* src = (const uint*)a3 + (size_t)i*3168;
    uint* d = (uint*)xt;
    for (int j = tid; j < 3168; j += 256) d[j] = src[j];
  }
  {
    const uint* src = (const uint*)w4h;
    uint* d = (uint*)wl;
    for (int j = tid; j < 13824; j += 256) d[j] = src[j];
  }
  if (tid < 64) bl[tid] = b4[tid];
  __syncthreads();
  for (int task = tid; task < 320; task += 256){
    const int co_g = task % 16;   // 4 co each
    const int oh   = task / 16;   // 0..19
    float acc[4][4] = {};
    #pragma unroll 1
    for (int ci=0; ci<48; ++ci){
      #pragma unroll
      for (int kh=0; kh<3; ++kh){
        float in[6];
        const f16* q = &xt[ci*132 + (oh+kh)*6];
        #pragma unroll
        for (int m=0;m<6;++m) in[m] = (float)q[m];
        float wt[4][3];
        #pragma unroll
        for (int c=0;c<4;++c)
          #pragma unroll
          for (int kw=0;kw<3;++kw)
            wt[c][kw] = (float)wl[(co_g*4+c)*432 + ci*9 + kh*3 + kw];
        #pragma unroll
        for (int c=0;c<4;++c)
          #pragma unroll
          for (int ow=0; ow<4; ++ow){
            float s = acc[c][ow];
            #pragma unroll
            for (int kw=0;kw<3;++kw) s = fmaf(in[ow+kw], wt[c][kw], s);
            acc[c][ow] = s;
          }
      }
    }
    #pragma unroll
    for (int c=0;c<4;++c){
      float bb = bl[co_g*4+c];
      #pragma unroll
      for (int ow=0;ow<4;++ow){
        float r = acc[c][ow]+bb; if (r<0.f) r=0.f;
        a4[(size_t)i*5120 + (co_g*4+c)*80 + oh*4 + ow] = (f16)r;
      }
    }
  }
}

// ---------------------------------------------------------------- fc1 (K-split partials)
// grid (Bc/32, 10); block 256. x1p[s][img][j]
__global__ __launch_bounds__(256) void fc1p_k(const f16* __restrict__ a4, const float* __restrict__ fc1W,
                                              float* __restrict__ x1p, int Bc){
  __shared__ __align__(16) f16 xa[8192];   // [32][256]
  __shared__ __align__(16) f16 Wc[25600];  // [256][100]
  const int tid = threadIdx.x;
  const int bx = blockIdx.x;
  const int s  = blockIdx.y;
  const int img_g = tid / 25;   // 0..7 (x4 imgs)  (only tid<200 compute)
  const int j_g   = tid % 25;   // x4 j
  float acc[4][4] = {};
  for (int cc=0; cc<2; ++cc){
    const int k0 = s*512 + cc*256;
    __syncthreads();
    {
      const uint* src = (const uint*)a4;
      uint* d = (uint*)xa;
      for (int idx = tid; idx < 4096; idx += 256){
        int il = idx >> 7, w2 = idx & 127;
        d[idx] = src[((size_t)(bx*32 + il))*2560 + (k0>>1) + w2];
      }
      const float* wsrc = fc1W + (size_t)k0*100;
      for (int idx = tid; idx < 25600; idx += 256) Wc[idx] = (f16)wsrc[idx];
    }
    __syncthreads();
    if (tid < 200){
      #pragma unroll 1
      for (int kk=0; kk<256; ++kk){
        float xv[4], wv[4];
        #pragma unroll
        for (int a=0;a<4;++a) xv[a] = (float)xa[(img_g*4+a)*256 + kk];
        #pragma unroll
        for (int b=0;b<4;++b) wv[b] = (float)Wc[kk*100 + j_g*4 + b];
        #pragma unroll
        for (int a=0;a<4;++a)
          #pragma unroll
          for (int b=0;b<4;++b) acc[a][b] = fmaf(xv[a], wv[b], acc[a][b]);
      }
    }
  }
  if (tid < 200){
    #pragma unroll
    for (int a=0;a<4;++a)
      #pragma unroll
      for (int b=0;b<4;++b)
        x1p[((size_t)s*Bc + bx*32 + img_g*4 + a)*100 + j_g*4 + b] = acc[a][b];
  }
}

__global__ __launch_bounds__(256) void fc1r_k(const float* __restrict__ x1p, const float* __restrict__ fc1b,
                                              float* __restrict__ x1, int Bc){
  int tt = blockIdx.x*256 + threadIdx.x;
  if (tt >= Bc*100) return;
  int il = tt / 100, j = tt - il*100;
  float s = fc1b[j];
  #pragma unroll
  for (int k=0;k<10;++k) s += x1p[((size_t)k*Bc + il)*100 + j];
  x1[tt] = s > 0.f ? s : 0.f;
}

// ---------------------------------------------------------------- fc2..fc4 + AEBS head
// grid Bc/4, block 256 (4 imgs x 64 lanes)
__global__ __launch_bounds__(256) void tail_k(const float* __restrict__ x1,
    const float* __restrict__ dist, const float* __restrict__ speed,
    const float* __restrict__ fW2, const float* __restrict__ fb2,
    const float* __restrict__ fW3, const float* __restrict__ fb3,
    const float* __restrict__ fW4, const float* __restrict__ fb4,
    const float* __restrict__ aW1, const float* __restrict__ ab1,
    const float* __restrict__ aW2, const float* __restrict__ ab2,
    const float* __restrict__ aW3, const float* __restrict__ ab3,
    float* __restrict__ out, int ib){
  __shared__ float w2s[5000], b2s[50], w3s[500], b3s[10], w4s[10];
  __shared__ float wa1s[36], ba1s[12], wa2s[288], ba2s[24], wa3s[96], ba3s[4];
  __shared__ float b4s;
  __shared__ float x1s[4][100], h2[4][50], h3[4][10], stg[4], hb1[4][12], hb2[4][24];
  const int tid = threadIdx.x;
  for (int j=tid;j<5000;j+=256) w2s[j]=fW2[j];
  for (int j=tid;j<500;j+=256)  w3s[j]=fW3[j];
  for (int j=tid;j<288;j+=256)  wa2s[j]=aW2[j];
  if (tid<50) b2s[tid]=fb2[tid];
  if (tid<10) b3s[tid]=fb3[tid];
  if (tid<10) w4s[tid]=fW4[tid];
  if (tid==0) b4s=fb4[0];
  if (tid<36) wa1s[tid]=aW1[tid];
  if (tid<12) ba1s[tid]=ab1[tid];
  if (tid<24) ba2s[tid]=ab2[tid];
  if (tid<96) wa3s[tid]=aW3[tid];
  if (tid<4)  ba3s[tid]=ab3[tid];
  for (int idx=tid; idx<400; idx+=256){
    int gg = idx/100, k = idx-gg*100;
    x1s[gg][k] = x1[(size_t)(blockIdx.x*4+gg)*100 + k];
  }
  __syncthreads();
  const int g = tid >> 6, lane = tid & 63;
  const int img_l = blockIdx.x*4 + g;
  if (lane < 50){
    float s = b2s[lane];
    #pragma unroll 4
    for (int k=0;k<100;++k) s = fmaf(x1s[g][k], w2s[k*50+lane], s);
    h2[g][lane] = s > 0.f ? s : 0.f;
  }
  __syncthreads();
  if (lane < 10){
    float s = b3s[lane];
    #pragma unroll
    for (int k=0;k<50;++k) s = fmaf(h2[g][k], w3s[k*10+lane], s);
    h3[g][lane] = s > 0.f ? s : 0.f;
  }
  __syncthreads();
  if (lane == 0){
    float s = b4s;
    #pragma unroll
    for (int k=0;k<10;++k) s = fmaf(h3[g][k], w4s[k], s);
    stg[g] = s;
  }
  __syncthreads();
  if (lane < 12){
    float s0 = stg[g], dd = dist[ib+img_l], sp = speed[ib+img_l];
    float s = ba1s[lane] + s0*wa1s[lane] + dd*wa1s[12+lane] + sp*wa1s[24+lane];
    hb1[g][lane] = s > 0.f ? s : 0.f;
  }
  __syncthreads();
  if (lane < 24){
    float s = ba2s[lane];
    #pragma unroll
    for (int k=0;k<12;++k) s = fmaf(hb1[g][k], wa2s[k*24+lane], s);
    hb2[g][lane] = s > 0.f ? s : 0.f;
  }
  __syncthreads();
  if (lane < 4){
    float s = ba3s[lane];
    #pragma unroll
    for (int k=0;k<24;++k) s = fmaf(hb2[g][k], wa3s[k*4+lane], s);
    out[(size_t)(ib+img_l)*4 + lane] = s;
  }
}

// ================================================================ host
extern "C" void kernel_launch(void* const* d_in, const int* in_sizes, int n_in,
                              void* d_out, int out_size, void* d_ws, size_t ws_size,
                              hipStream_t stream){
  const float* rgb   = (const float*)d_in[0];
  const float* dist  = (const float*)d_in[1];
  const float* speed = (const float*)d_in[2];
  const float* cw1 = (const float*)d_in[3];
  const float* cb1 = (const float*)d_in[4];
  const float* cw2 = (const float*)d_in[5];
  const float* cb2 = (const float*)d_in[6];
  const float* cw3 = (const float*)d_in[7];
  const float* cb3 = (const float*)d_in[8];
  const float* cw4 = (const float*)d_in[9];
  const float* cb4 = (const float*)d_in[10];
  const float* fW1 = (const float*)d_in[11];
  const float* fb1 = (const float*)d_in[12];
  const float* fW2 = (const float*)d_in[13];
  const float* fb2 = (const float*)d_in[14];
  const float* fW3 = (const float*)d_in[15];
  const float* fb3 = (const float*)d_in[16];
  const float* fW4 = (const float*)d_in[17];
  const float* fb4 = (const float*)d_in[18];
  const float* aW1 = (const float*)d_in[19];
  const float* ab1 = (const float*)d_in[20];
  const float* aW2 = (const float*)d_in[21];
  const float* ab2 = (const float*)d_in[22];
  const float* aW3 = (const float*)d_in[23];
  const float* ab3 = (const float*)d_in[24];
  float* out = (float*)d_out;
  const int B = in_sizes[0] / 15000;

  auto ALN = [](size_t x){ return (x + 255) & ~(size_t)255; };
  const size_t fixed = ALN(21600*2) + ALN(43200*2) + ALN(27648*2);

  int nc = 1;
  while (nc < 32){
    size_t Bc = (size_t)(B / nc);
    size_t need = fixed + ALN(Bc*169344) + ALN(Bc*54144) + ALN(Bc*12672)
                        + ALN(Bc*10240)  + ALN(Bc*400)   + ALN(Bc*4000);
    if (need <= ws_size) break;
    nc *= 2;
  }
  const int Bc = B / nc;

  char* ws = (char*)d_ws;
  size_t o = 0;
  auto alloc = [&](size_t bytes)->char*{ char* p = ws + o; o += ALN(bytes); return p; };
  f16* w2h = (f16*)alloc(21600*2);
  f16* w3h = (f16*)alloc(43200*2);
  f16* w4h = (f16*)alloc(27648*2);
  f16* a1  = (f16*)alloc((size_t)Bc*169344);
  f16* a2  = (f16*)alloc((size_t)Bc*54144);
  f16* a3  = (f16*)alloc((size_t)Bc*12672);
  f16* a4  = (f16*)alloc((size_t)Bc*10240);
  float* x1  = (float*)alloc((size_t)Bc*400);
  float* x1p = (float*)alloc((size_t)Bc*4000);

  cast_k<<<dim3(64), dim3(256), 0, stream>>>(w2h, cw2, 21600);
  cast_k<<<dim3(128),dim3(256), 0, stream>>>(w3h, cw3, 43200);
  cast_k<<<dim3(96), dim3(256), 0, stream>>>(w4h, cw4, 27648);

  for (int c = 0; c < nc; ++c){
    const int ib = c*Bc;
    conv1_k<<<dim3(Bc),   dim3(256), 0, stream>>>(rgb, cw1, cb1, a1, ib);
    conv2_k<<<dim3(Bc*6), dim3(192), 0, stream>>>(a1, w2h, cb2, a2);
    conv3_k<<<dim3(Bc*4), dim3(128), 0, stream>>>(a2, w3h, cb3, a3);
    conv4_k<<<dim3(Bc),   dim3(256), 0, stream>>>(a3, w4h, cb4, a4);
    fc1p_k<<<dim3(Bc/32, 10), dim3(256), 0, stream>>>(a4, fW1, x1p, Bc);
    fc1r_k<<<dim3((Bc*100+255)/256), dim3(256), 0, stream>>>(x1p, fb1, x1, Bc);
    tail_k<<<dim3(Bc/4), dim3(256), 0, stream>>>(x1, dist, speed,
        fW2, fb2, fW3, fb3, fW4, fb4, aW1, ab1, aW2, ab2, aW3, ab3, out, ib);
  }
}

// Round 2
// 877.268 us; speedup vs baseline: 2.8815x; 2.8815x over previous
//
#include <hip/hip_runtime.h>

typedef _Float16 f16;
typedef __fp16 hh2 __attribute__((ext_vector_type(2)));

// ---- fdot2: v_dot2_f32_f16 (f16 pair dot, f32 accum) with compile-safe fallback
#if defined(__has_builtin)
#if __has_builtin(__builtin_amdgcn_fdot2)
#define HAVE_FDOT2 1
#endif
#endif
static __device__ inline hh2 as_h2(unsigned u){ union{unsigned u; hh2 h;} x; x.u = u; return x.h; }
static __device__ inline float fdot2(unsigned xu, unsigned wu, float c){
#ifdef HAVE_FDOT2
  return __builtin_amdgcn_fdot2(as_h2(xu), as_h2(wu), c, false);
#else
  hh2 a = as_h2(xu), b = as_h2(wu);
  return fmaf((float)a.x, (float)b.x, fmaf((float)a.y, (float)b.y, c));
#endif
}

// ---------------------------------------------------------------- weight repack
// w2r [p25][co36][ci24] f16
__global__ __launch_bounds__(256) void repack2_k(f16* __restrict__ dst, const float* __restrict__ src){
  for (int idx = blockIdx.x*256 + threadIdx.x; idx < 21600; idx += gridDim.x*256){
    int ci = idx % 24, r = idx / 24, co = r % 36, p = r / 36;
    dst[idx] = (f16)src[(co*24 + ci)*25 + p];
  }
}
// w3r [p25][co48][ci40 pad0] f16
__global__ __launch_bounds__(256) void repack3_k(f16* __restrict__ dst, const float* __restrict__ src){
  for (int idx = blockIdx.x*256 + threadIdx.x; idx < 48000; idx += gridDim.x*256){
    int ci = idx % 40, r = idx / 40, co = r % 48, p = r / 48;
    dst[idx] = (ci < 36) ? (f16)src[(co*36 + ci)*25 + p] : (f16)0.0f;
  }
}
// w4r [p9][co64][ci48] f16
__global__ __launch_bounds__(256) void repack4_k(f16* __restrict__ dst, const float* __restrict__ src){
  for (int idx = blockIdx.x*256 + threadIdx.x; idx < 27648; idx += gridDim.x*256){
    int ci = idx % 48, r = idx / 48, co = r % 64, p = r / 64;
    dst[idx] = (f16)src[(co*48 + ci)*9 + p];
  }
}

// ---------------------------------------------------------------- conv1 (fused binarize)
// rgb (B,15000) f32 [w75][h200] -> a1 NHWC (Bc,98,36,24) f16. grid=Bc*7 (oh tiles of 14), block=128
__global__ __launch_bounds__(128) void conv1_k(const float* __restrict__ rgb, const float* __restrict__ w1,
                                               const float* __restrict__ b1, f16* __restrict__ a1, int ib){
  __shared__ float xi[31*76];   // [hh31][w75(+1)]
  __shared__ float wr[600];     // [p25][co24]
  __shared__ float bl[24];
  const int tid = threadIdx.x, bx = blockIdx.x;
  const int i = bx / 7, t = bx - i*7;
  const int oh0 = t*14;
  const float* img = rgb + (size_t)(ib + i)*15000;
  for (int idx = tid; idx < 2325; idx += 128){
    int a = idx / 31, hh = idx - a*31;          // a = w, hh = local h
    float v = img[a*200 + 2*oh0 + hh];
    xi[hh*76 + a] = (v > 0.f) ? 1.0f : 0.0f;
  }
  for (int idx = tid; idx < 600; idx += 128){
    int p = idx / 24, co = idx - p*24;
    wr[idx] = w1[co*25 + p];
  }
  if (tid < 24) bl[tid] = b1[tid];
  __syncthreads();
  int ohl[4], owl[4]; bool act[4];
  #pragma unroll
  for (int u=0;u<4;++u){
    int sp = u*128 + tid;
    act[u] = sp < 504;
    int s = act[u] ? sp : 0;
    ohl[u] = s / 36; owl[u] = s - ohl[u]*36;
  }
  float acc[4][24] = {};
  #pragma unroll 1
  for (int kh=0; kh<5; ++kh){
    #pragma unroll 1
    for (int kw=0; kw<5; ++kw){
      float wv[24];
      #pragma unroll
      for (int c=0;c<24;++c) wv[c] = wr[(kh*5+kw)*24 + c];
      #pragma unroll
      for (int u=0;u<4;++u){
        float x = xi[(2*ohl[u]+kh)*76 + 2*owl[u]+kw];
        #pragma unroll
        for (int c=0;c<24;++c) acc[u][c] = fmaf(x, wv[c], acc[u][c]);
      }
    }
  }
  #pragma unroll
  for (int u=0;u<4;++u){
    if (!act[u]) continue;
    union { f16 h[24]; uint4 q[3]; } pk;
    #pragma unroll
    for (int c=0;c<24;++c){
      float r = acc[u][c] + bl[c]; if (r < 0.f) r = 0.f;
      pk.h[c] = (f16)r;
    }
    size_t base = (((size_t)i*98 + oh0 + ohl[u])*36 + owl[u])*24;
    uint4* dst = (uint4*)(a1 + base);
    dst[0] = pk.q[0]; dst[1] = pk.q[1]; dst[2] = pk.q[2];
  }
}

// ---------------------------------------------------------------- conv2
// a1 NHWC (Bc,98,36,24) -> a2 NHWC (Bc,47,16,36). grid=Bc*6 (oh tiles of 8), block=192
__global__ __launch_bounds__(192) void conv2_k(const f16* __restrict__ a1, const f16* __restrict__ w2r,
                                               const float* __restrict__ b2, f16* __restrict__ a2){
  __shared__ __align__(16) f16 xt[19*872];   // [rr19][col36][ci24] rowstride 872 (436 dw % 32 = 20)
  __shared__ float bl[36];
  const int tid = threadIdx.x, bx = blockIdx.x;
  const int i = bx / 6, t = bx - i*6;
  const int oh0 = t*8, ohn = (t==5) ? 7 : 8, r0 = oh0*2;
  {
    const uint* src = (const uint*)a1;
    uint* d = (uint*)xt;
    for (int idx = tid; idx < 8208; idx += 192){
      int rr = idx / 432, q = idx - rr*432;
      int r = r0 + rr;
      d[rr*436 + q] = (r < 98) ? src[((size_t)i*98 + r)*432 + q] : 0u;
    }
  }
  if (tid < 36) bl[tid] = b2[tid];
  __syncthreads();
  const int co_g = tid >> 5, slot = tid & 31;
  const int oh_l = slot >> 2, ow0 = (slot & 3)*4, co0 = co_g*6;
  const bool act = oh_l < ohn;
  float acc[6][4];
  #pragma unroll
  for (int c=0;c<6;++c){ float bb = bl[co0+c];
    #pragma unroll
    for (int u=0;u<4;++u) acc[c][u] = bb; }
  #pragma unroll 1
  for (int kh=0; kh<5; ++kh){
    const int rr = 2*oh_l + kh;
    #pragma unroll 1
    for (int kw=0; kw<5; ++kw){
      const uint4* wp = (const uint4*)(w2r + ((kh*5+kw)*36 + co0)*24);   // 6co x 24ci = 18 uint4
      uint4 wv[18];
      #pragma unroll
      for (int m=0;m<18;++m) wv[m] = wp[m];
      #pragma unroll
      for (int u=0;u<4;++u){
        const int col = 2*(ow0+u) + kw;
        const uint4* xp = (const uint4*)(xt + rr*872 + col*24);
        uint4 xv0 = xp[0], xv1 = xp[1], xv2 = xp[2];
        unsigned xs[12] = {xv0.x,xv0.y,xv0.z,xv0.w, xv1.x,xv1.y,xv1.z,xv1.w, xv2.x,xv2.y,xv2.z,xv2.w};
        #pragma unroll
        for (int c=0;c<6;++c){
          const uint4 w0 = wv[c*3], w1 = wv[c*3+1], w2 = wv[c*3+2];
          unsigned ws[12] = {w0.x,w0.y,w0.z,w0.w, w1.x,w1.y,w1.z,w1.w, w2.x,w2.y,w2.z,w2.w};
          float s = acc[c][u];
          #pragma unroll
          for (int p=0;p<12;++p) s = fdot2(xs[p], ws[p], s);
          acc[c][u] = s;
        }
      }
    }
  }
  if (act){
    #pragma unroll
    for (int u=0;u<4;++u){
      union { f16 h[6]; unsigned w[3]; } pk;
      #pragma unroll
      for (int c=0;c<6;++c){ float r = acc[c][u]; if (r<0.f) r=0.f; pk.h[c] = (f16)r; }
      size_t ob = (((size_t)i*47 + oh0 + oh_l)*16 + (ow0+u))*36 + co0;
      unsigned* dst = (unsigned*)(a2 + ob);
      dst[0] = pk.w[0]; dst[1] = pk.w[1]; dst[2] = pk.w[2];
    }
  }
}

// ---------------------------------------------------------------- conv3
// a2 NHWC (Bc,47,16,36) -> a3 NHWC (Bc,22,6,48). grid=Bc*2 (oh tiles of 11), block=192
__global__ __launch_bounds__(192) void conv3_k(const f16* __restrict__ a2, const f16* __restrict__ w3r,
                                               const float* __restrict__ b3, f16* __restrict__ a3){
  __shared__ __align__(16) f16 xt[25*648];   // [rr25][col16][ci40 pad] rowstride 648 (324 dw % 32 = 4)
  __shared__ float bl[48];
  const int tid = threadIdx.x, bx = blockIdx.x;
  const int i = bx >> 1, t = bx & 1;
  const int oh0 = t*11, r0 = t*22;
  {
    const uint* src = (const uint*)a2;
    uint* d = (uint*)xt;
    for (int idx = tid; idx < 8000; idx += 192){
      int rr = idx / 320, q = idx - rr*320;
      int c = q / 20, j = q - c*20;
      uint v = (j < 18) ? src[((size_t)i*47 + r0 + rr)*288 + c*18 + j] : 0u;
      d[rr*324 + c*20 + j] = v;
    }
  }
  if (tid < 48) bl[tid] = b3[tid];
  __syncthreads();
  const int co_g = tid / 24, slot = tid - co_g*24;
  const int oh_r = slot >> 1, ow0 = (slot & 1)*3, co0 = co_g*6;
  const bool act = oh_r < 11;
  const int oh_l = act ? oh_r : 0;
  float acc[6][3];
  #pragma unroll
  for (int c=0;c<6;++c){ float bb = bl[co0+c];
    #pragma unroll
    for (int u=0;u<3;++u) acc[c][u] = bb; }
  #pragma unroll 1
  for (int kh=0; kh<5; ++kh){
    const int rr = 2*oh_l + kh;
    #pragma unroll 1
    for (int kw=0; kw<5; ++kw){
      unsigned xs[3][20];
      #pragma unroll
      for (int u=0;u<3;++u){
        const int col = 2*(ow0+u) + kw;
        const uint4* xp = (const uint4*)(xt + rr*648 + col*40);
        #pragma unroll
        for (int m=0;m<5;++m){
          uint4 v = xp[m];
          xs[u][m*4+0]=v.x; xs[u][m*4+1]=v.y; xs[u][m*4+2]=v.z; xs[u][m*4+3]=v.w;
        }
      }
      #pragma unroll
      for (int c=0;c<6;++c){
        const uint4* wp = (const uint4*)(w3r + ((kh*5+kw)*48 + co0 + c)*40);
        unsigned ws[20];
        #pragma unroll
        for (int m=0;m<5;++m){
          uint4 v = wp[m];
          ws[m*4+0]=v.x; ws[m*4+1]=v.y; ws[m*4+2]=v.z; ws[m*4+3]=v.w;
        }
        #pragma unroll
        for (int u=0;u<3;++u){
          float s = acc[c][u];
          #pragma unroll
          for (int p=0;p<20;++p) s = fdot2(xs[u][p], ws[p], s);
          acc[c][u] = s;
        }
      }
    }
  }
  if (act){
    #pragma unroll
    for (int u=0;u<3;++u){
      union { f16 h[6]; unsigned w[3]; } pk;
      #pragma unroll
      for (int c=0;c<6;++c){ float r = acc[c][u]; if (r<0.f) r=0.f; pk.h[c] = (f16)r; }
      size_t ob = (((size_t)i*22 + oh0 + oh_l)*6 + (ow0+u))*48 + co0;
      unsigned* dst = (unsigned*)(a3 + ob);
      dst[0] = pk.w[0]; dst[1] = pk.w[1]; dst[2] = pk.w[2];
    }
  }
}

// ---------------------------------------------------------------- conv4
// a3 NHWC (Bc,22,6,48) -> a4 (Bc, sp80, co64) f16. grid=Bc, block=256
__global__ __launch_bounds__(256) void conv4_k(const f16* __restrict__ a3, const f16* __restrict__ w4r,
                                               const float* __restrict__ b4, f16* __restrict__ a4){
  __shared__ __align__(16) f16 xt[22*336];   // [row22][col6][ci48 pad56]
  __shared__ float bl[64];
  const int tid = threadIdx.x;
  const int i = blockIdx.x;
  {
    const uint* src = (const uint*)a3 + (size_t)i*3168;
    uint* d = (uint*)xt;
    for (int idx = tid; idx < 3168; idx += 256){
      int sp = idx / 24, j = idx - sp*24;
      int row = sp / 6, c = sp - row*6;
      d[row*168 + c*28 + j] = src[idx];
    }
  }
  if (tid < 64) bl[tid] = b4[tid];
  __syncthreads();
  for (int task = tid; task < 640; task += 256){
    const int co_o = task / 80, sp = task - co_o*80;
    const int oh = sp >> 2, ow = sp & 3, co0 = co_o*8;
    float acc[8];
    #pragma unroll
    for (int c=0;c<8;++c) acc[c] = bl[co0+c];
    #pragma unroll 1
    for (int kh=0; kh<3; ++kh){
      #pragma unroll 1
      for (int kw=0; kw<3; ++kw){
        const uint4* xp = (const uint4*)(xt + (oh+kh)*336 + (ow+kw)*56);
        unsigned xs[24];
        #pragma unroll
        for (int m=0;m<6;++m){
          uint4 v = xp[m];
          xs[m*4+0]=v.x; xs[m*4+1]=v.y; xs[m*4+2]=v.z; xs[m*4+3]=v.w;
        }
        #pragma unroll
        for (int c=0;c<8;++c){
          const uint4* wp = (const uint4*)(w4r + ((kh*3+kw)*64 + co0 + c)*48);
          float s = acc[c];
          #pragma unroll
          for (int m=0;m<6;++m){
            uint4 v = wp[m];
            s = fdot2(xs[m*4+0], v.x, s); s = fdot2(xs[m*4+1], v.y, s);
            s = fdot2(xs[m*4+2], v.z, s); s = fdot2(xs[m*4+3], v.w, s);
          }
          acc[c] = s;
        }
      }
    }
    union { f16 h[8]; uint4 q; } pk;
    #pragma unroll
    for (int c=0;c<8;++c){ float r = acc[c]; if (r<0.f) r=0.f; pk.h[c] = (f16)r; }
    *(uint4*)(a4 + ((size_t)i*80 + sp)*64 + co0) = pk.q;
  }
}

// ---------------------------------------------------------------- fc1 (K-split partials; W rows permuted for NHWC a4)
__global__ __launch_bounds__(256) void fc1p_k(const f16* __restrict__ a4, const float* __restrict__ fc1W,
                                              float* __restrict__ x1p, int Bc){
  __shared__ __align__(16) f16 xa[8192];   // [32 img][256 k]
  __shared__ __align__(16) f16 Wc[25600];  // [256 k][100 j]
  const int tid = threadIdx.x;
  const int bx = blockIdx.x;
  const int s  = blockIdx.y;
  const int img_g = tid / 25;
  const int j_g   = tid % 25;
  float acc[4][4] = {};
  for (int cc=0; cc<2; ++cc){
    const int k0 = s*512 + cc*256;
    __syncthreads();
    {
      const uint* src = (const uint*)a4;
      uint* d = (uint*)xa;
      for (int idx = tid; idx < 4096; idx += 256){
        int il = idx >> 7, w2 = idx & 127;
        d[idx] = src[((size_t)(bx*32 + il))*2560 + (k0>>1) + w2];
      }
      for (int idx = tid; idx < 25600; idx += 256){
        int kk = idx / 100, j = idx - kk*100;
        int k = k0 + kk;
        int row = (k & 63)*80 + (k >> 6);   // NHWC k -> original NCHW-flat row
        Wc[idx] = (f16)fc1W[(size_t)row*100 + j];
      }
    }
    __syncthreads();
    if (tid < 200){
      #pragma unroll 1
      for (int kk=0; kk<256; ++kk){
        float xv[4], wv[4];
        #pragma unroll
        for (int a=0;a<4;++a) xv[a] = (float)xa[(img_g*4+a)*256 + kk];
        #pragma unroll
        for (int b=0;b<4;++b) wv[b] = (float)Wc[kk*100 + j_g*4 + b];
        #pragma unroll
        for (int a=0;a<4;++a)
          #pragma unroll
          for (int b=0;b<4;++b) acc[a][b] = fmaf(xv[a], wv[b], acc[a][b]);
      }
    }
  }
  if (tid < 200){
    #pragma unroll
    for (int a=0;a<4;++a)
      #pragma unroll
      for (int b=0;b<4;++b)
        x1p[((size_t)s*Bc + bx*32 + img_g*4 + a)*100 + j_g*4 + b] = acc[a][b];
  }
}

__global__ __launch_bounds__(256) void fc1r_k(const float* __restrict__ x1p, const float* __restrict__ fc1b,
                                              float* __restrict__ x1, int Bc){
  int tt = blockIdx.x*256 + threadIdx.x;
  if (tt >= Bc*100) return;
  int il = tt / 100, j = tt - il*100;
  float s = fc1b[j];
  #pragma unroll
  for (int k=0;k<10;++k) s += x1p[((size_t)k*Bc + il)*100 + j];
  x1[tt] = s > 0.f ? s : 0.f;
}

// ---------------------------------------------------------------- fc2..fc4 + AEBS head
__global__ __launch_bounds__(256) void tail_k(const float* __restrict__ x1,
    const float* __restrict__ dist, const float* __restrict__ speed,
    const float* __restrict__ fW2, const float* __restrict__ fb2,
    const float* __restrict__ fW3, const float* __restrict__ fb3,
    const float* __restrict__ fW4, const float* __restrict__ fb4,
    const float* __restrict__ aW1, const float* __restrict__ ab1,
    const float* __restrict__ aW2, const float* __restrict__ ab2,
    const float* __restrict__ aW3, const float* __restrict__ ab3,
    float* __restrict__ out, int ib){
  __shared__ float w2s[5000], b2s[50], w3s[500], b3s[10], w4s[10];
  __shared__ float wa1s[36], ba1s[12], wa2s[288], ba2s[24], wa3s[96], ba3s[4];
  __shared__ float b4s;
  __shared__ float x1s[4][100], h2[4][50], h3[4][10], stg[4], hb1[4][12], hb2[4][24];
  const int tid = threadIdx.x;
  for (int j=tid;j<5000;j+=256) w2s[j]=fW2[j];
  for (int j=tid;j<500;j+=256)  w3s[j]=fW3[j];
  for (int j=tid;j<288;j+=256)  wa2s[j]=aW2[j];
  if (tid<50) b2s[tid]=fb2[tid];
  if (tid<10) b3s[tid]=fb3[tid];
  if (tid<10) w4s[tid]=fW4[tid];
  if (tid==0) b4s=fb4[0];
  if (tid<36) wa1s[tid]=aW1[tid];
  if (tid<12) ba1s[tid]=ab1[tid];
  if (tid<24) ba2s[tid]=ab2[tid];
  if (tid<96) wa3s[tid]=aW3[tid];
  if (tid<4)  ba3s[tid]=ab3[tid];
  for (int idx=tid; idx<400; idx+=256){
    int gg = idx/100, k = idx-gg*100;
    x1s[gg][k] = x1[(size_t)(blockIdx.x*4+gg)*100 + k];
  }
  __syncthreads();
  const int g = tid >> 6, lane = tid & 63;
  const int img_l = blockIdx.x*4 + g;
  if (lane < 50){
    float s = b2s[lane];
    #pragma unroll 4
    for (int k=0;k<100;++k) s = fmaf(x1s[g][k], w2s[k*50+lane], s);
    h2[g][lane] = s > 0.f ? s : 0.f;
  }
  __syncthreads();
  if (lane < 10){
    float s = b3s[lane];
    #pragma unroll
    for (int k=0;k<50;++k) s = fmaf(h2[g][k], w3s[k*10+lane], s);
    h3[g][lane] = s > 0.f ? s : 0.f;
  }
  __syncthreads();
  if (lane == 0){
    float s = b4s;
    #pragma unroll
    for (int k=0;k<10;++k) s = fmaf(h3[g][k], w4s[k], s);
    stg[g] = s;
  }
  __syncthreads();
  if (lane < 12){
    float s0 = stg[g], dd = dist[ib+img_l], sp = speed[ib+img_l];
    float s = ba1s[lane] + s0*wa1s[lane] + dd*wa1s[12+lane] + sp*wa1s[24+lane];
    hb1[g][lane] = s > 0.f ? s : 0.f;
  }
  __syncthreads();
  if (lane < 24){
    float s = ba2s[lane];
    #pragma unroll
    for (int k=0;k<12;++k) s = fmaf(hb1[g][k], wa2s[k*24+lane], s);
    hb2[g][lane] = s > 0.f ? s : 0.f;
  }
  __syncthreads();
  if (lane < 4){
    float s = ba3s[lane];
    #pragma unroll
    for (int k=0;k<24;++k) s = fmaf(hb2[g][k], wa3s[k*4+lane], s);
    out[(size_t)(ib+img_l)*4 + lane] = s;
  }
}

// ================================================================ host
extern "C" void kernel_launch(void* const* d_in, const int* in_sizes, int n_in,
                              void* d_out, int out_size, void* d_ws, size_t ws_size,
                              hipStream_t stream){
  const float* rgb   = (const float*)d_in[0];
  const float* dist  = (const float*)d_in[1];
  const float* speed = (const float*)d_in[2];
  const float* cw1 = (const float*)d_in[3];
  const float* cb1 = (const float*)d_in[4];
  const float* cw2 = (const float*)d_in[5];
  const float* cb2 = (const float*)d_in[6];
  const float* cw3 = (const float*)d_in[7];
  const float* cb3 = (const float*)d_in[8];
  const float* cw4 = (const float*)d_in[9];
  const float* cb4 = (const float*)d_in[10];
  const float* fW1 = (const float*)d_in[11];
  const float* fb1 = (const float*)d_in[12];
  const float* fW2 = (const float*)d_in[13];
  const float* fb2 = (const float*)d_in[14];
  const float* fW3 = (const float*)d_in[15];
  const float* fb3 = (const float*)d_in[16];
  const float* fW4 = (const float*)d_in[17];
  const float* fb4 = (const float*)d_in[18];
  const float* aW1 = (const float*)d_in[19];
  const float* ab1 = (const float*)d_in[20];
  const float* aW2 = (const float*)d_in[21];
  const float* ab2 = (const float*)d_in[22];
  const float* aW3 = (const float*)d_in[23];
  const float* ab3 = (const float*)d_in[24];
  float* out = (float*)d_out;
  const int B = in_sizes[0] / 15000;

  auto ALN = [](size_t x){ return (x + 255) & ~(size_t)255; };
  const size_t fixed = ALN(21600*2) + ALN(48000*2) + ALN(27648*2);

  int nc = 1;
  while (nc < 32){
    size_t Bc = (size_t)(B / nc);
    size_t need = fixed + ALN(Bc*169344) + ALN(Bc*54144) + ALN(Bc*12672)
                        + ALN(Bc*10240)  + ALN(Bc*400)   + ALN(Bc*4000);
    if (need <= ws_size) break;
    nc *= 2;
  }
  const int Bc = B / nc;

  char* ws = (char*)d_ws;
  size_t o = 0;
  auto alloc = [&](size_t bytes)->char*{ char* p = ws + o; o += ALN(bytes); return p; };
  f16* w2r = (f16*)alloc(21600*2);
  f16* w3r = (f16*)alloc(48000*2);
  f16* w4r = (f16*)alloc(27648*2);
  f16* a1  = (f16*)alloc((size_t)Bc*169344);
  f16* a2  = (f16*)alloc((size_t)Bc*54144);
  f16* a3  = (f16*)alloc((size_t)Bc*12672);
  f16* a4  = (f16*)alloc((size_t)Bc*10240);
  float* x1  = (float*)alloc((size_t)Bc*400);
  float* x1p = (float*)alloc((size_t)Bc*4000);

  repack2_k<<<dim3(85),  dim3(256), 0, stream>>>(w2r, cw2);
  repack3_k<<<dim3(188), dim3(256), 0, stream>>>(w3r, cw3);
  repack4_k<<<dim3(108), dim3(256), 0, stream>>>(w4r, cw4);

  for (int c = 0; c < nc; ++c){
    const int ib = c*Bc;
    conv1_k<<<dim3(Bc*7), dim3(128), 0, stream>>>(rgb, cw1, cb1, a1, ib);
    conv2_k<<<dim3(Bc*6), dim3(192), 0, stream>>>(a1, w2r, cb2, a2);
    conv3_k<<<dim3(Bc*2), dim3(192), 0, stream>>>(a2, w3r, cb3, a3);
    conv4_k<<<dim3(Bc),   dim3(256), 0, stream>>>(a3, w4r, cb4, a4);
    fc1p_k<<<dim3(Bc/32, 10), dim3(256), 0, stream>>>(a4, fW1, x1p, Bc);
    fc1r_k<<<dim3((Bc*100+255)/256), dim3(256), 0, stream>>>(x1p, fb1, x1, Bc);
    tail_k<<<dim3(Bc/4), dim3(256), 0, stream>>>(x1, dist, speed,
        fW2, fb2, fW3, fb3, fW4, fb4, aW1, ab1, aW2, ab2, aW3, ab3, out, ib);
  }
}

// Round 3
// 803.682 us; speedup vs baseline: 3.1453x; 1.0916x over previous
//
#include <hip/hip_runtime.h>

typedef _Float16 f16;
typedef __fp16 hh2 __attribute__((ext_vector_type(2)));

// ---- fdot2: v_dot2_f32_f16 (f16 pair dot, f32 accum) with compile-safe fallback
#if defined(__has_builtin)
#if __has_builtin(__builtin_amdgcn_fdot2)
#define HAVE_FDOT2 1
#endif
#endif
static __device__ inline hh2 as_h2(unsigned u){ union{unsigned u; hh2 h;} x; x.u = u; return x.h; }
static __device__ inline float fdot2(unsigned xu, unsigned wu, float c){
#ifdef HAVE_FDOT2
  return __builtin_amdgcn_fdot2(as_h2(xu), as_h2(wu), c, false);
#else
  hh2 a = as_h2(xu), b = as_h2(wu);
  return fmaf((float)a.x, (float)b.x, fmaf((float)a.y, (float)b.y, c));
#endif
}

// ---------------------------------------------------------------- weight repack
// w2r [p25][co36][ci24] f16
__global__ __launch_bounds__(256) void repack2_k(f16* __restrict__ dst, const float* __restrict__ src){
  for (int idx = blockIdx.x*256 + threadIdx.x; idx < 21600; idx += gridDim.x*256){
    int ci = idx % 24, r = idx / 24, co = r % 36, p = r / 36;
    dst[idx] = (f16)src[(co*24 + ci)*25 + p];
  }
}
// w3r [p25][co48][ci40 pad0] f16
__global__ __launch_bounds__(256) void repack3_k(f16* __restrict__ dst, const float* __restrict__ src){
  for (int idx = blockIdx.x*256 + threadIdx.x; idx < 48000; idx += gridDim.x*256){
    int ci = idx % 40, r = idx / 40, co = r % 48, p = r / 48;
    dst[idx] = (ci < 36) ? (f16)src[(co*36 + ci)*25 + p] : (f16)0.0f;
  }
}
// w4r [p9][co64][ci48] f16
__global__ __launch_bounds__(256) void repack4_k(f16* __restrict__ dst, const float* __restrict__ src){
  for (int idx = blockIdx.x*256 + threadIdx.x; idx < 27648; idx += gridDim.x*256){
    int ci = idx % 48, r = idx / 48, co = r % 64, p = r / 64;
    dst[idx] = (f16)src[(co*48 + ci)*9 + p];
  }
}

// ---------------------------------------------------------------- conv1 (fused binarize)
// rgb (B,15000) f32 [w75][h200] -> a1 NHWC (Bc,98,36,24) f16. grid=Bc*7 (oh tiles of 14), block=128
__global__ __launch_bounds__(128) void conv1_k(const float* __restrict__ rgb, const float* __restrict__ w1,
                                               const float* __restrict__ b1, f16* __restrict__ a1, int ib){
  __shared__ float xi[31*76];   // [hh31][w75(+1)]
  __shared__ float wr[600];     // [p25][co24]
  __shared__ float bl[24];
  const int tid = threadIdx.x, bx = blockIdx.x;
  const int i = bx / 7, t = bx - i*7;
  const int oh0 = t*14;
  const float* img = rgb + (size_t)(ib + i)*15000;
  for (int idx = tid; idx < 2325; idx += 128){
    int a = idx / 31, hh = idx - a*31;          // a = w, hh = local h
    float v = img[a*200 + 2*oh0 + hh];
    xi[hh*76 + a] = (v > 0.f) ? 1.0f : 0.0f;
  }
  for (int idx = tid; idx < 600; idx += 128){
    int p = idx / 24, co = idx - p*24;
    wr[idx] = w1[co*25 + p];
  }
  if (tid < 24) bl[tid] = b1[tid];
  __syncthreads();
  int ohl[4], owl[4]; bool act[4];
  #pragma unroll
  for (int u=0;u<4;++u){
    int sp = u*128 + tid;
    act[u] = sp < 504;
    int s = act[u] ? sp : 0;
    ohl[u] = s / 36; owl[u] = s - ohl[u]*36;
  }
  float acc[4][24] = {};
  #pragma unroll 1
  for (int kh=0; kh<5; ++kh){
    #pragma unroll 1
    for (int kw=0; kw<5; ++kw){
      float wv[24];
      #pragma unroll
      for (int c=0;c<24;++c) wv[c] = wr[(kh*5+kw)*24 + c];
      #pragma unroll
      for (int u=0;u<4;++u){
        float x = xi[(2*ohl[u]+kh)*76 + 2*owl[u]+kw];
        #pragma unroll
        for (int c=0;c<24;++c) acc[u][c] = fmaf(x, wv[c], acc[u][c]);
      }
    }
  }
  #pragma unroll
  for (int u=0;u<4;++u){
    if (!act[u]) continue;
    union { f16 h[24]; uint4 q[3]; } pk;
    #pragma unroll
    for (int c=0;c<24;++c){
      float r = acc[u][c] + bl[c]; if (r < 0.f) r = 0.f;
      pk.h[c] = (f16)r;
    }
    size_t base = (((size_t)i*98 + oh0 + ohl[u])*36 + owl[u])*24;
    uint4* dst = (uint4*)(a1 + base);
    dst[0] = pk.q[0]; dst[1] = pk.q[1]; dst[2] = pk.q[2];
  }
}

// ---------------------------------------------------------------- conv2
// a1 NHWC (Bc,98,36,24) -> a2 NHWC (Bc,47,16,36). grid=Bc*6 (oh tiles of 8), block=384 (6 waves)
// wave w -> co [6w, 6w+6); lane covers 2 px of the 8x16 tile. x in LDS parity-split:
// xt[par][rr19][col'18][ci24] -> lane col-stride 48B = 12dw: 8 lanes' b128 tile all 32 banks.
__global__ __launch_bounds__(384) void conv2_k(const f16* __restrict__ a1, const f16* __restrict__ w2r,
                                               const float* __restrict__ b2, f16* __restrict__ a2){
  __shared__ __align__(16) f16 xt[2*19*18*24];   // 32832 B
  const int tid = threadIdx.x, bx = blockIdx.x;
  const int i = bx / 6, t = bx - i*6;
  const int oh0 = t*8, r0 = t*16;
  const int npx = (t==5) ? 112 : 128;
  {
    const uint* src = (const uint*)a1 + (size_t)i*98*432;
    uint* d = (uint*)xt;
    for (int idx = tid; idx < 8208; idx += 384){
      int rr = idx / 432, q = idx - rr*432;
      int col = q / 12, cdw = q - col*12;
      int r = r0 + rr;
      uint v = (r < 98) ? src[r*432 + q] : 0u;
      d[(((col&1)*19 + rr)*18 + (col>>1))*12 + cdw] = v;
    }
  }
  __syncthreads();
  const int wv = tid >> 6, lane = tid & 63;
  const int co0 = wv*6;
  const int oh_l0 = lane >> 4, ow = lane & 15;
  float acc[2][6];
  #pragma unroll
  for (int c=0;c<6;++c){
    float bb = b2[co0+c];
    acc[0][c] = bb; acc[1][c] = bb;
  }
  #pragma unroll 1
  for (int kh=0; kh<5; ++kh){
    #pragma unroll 1
    for (int kw=0; kw<5; ++kw){
      const int par = kw & 1, kws = kw >> 1;
      unsigned xs[2][12];
      #pragma unroll
      for (int u=0;u<2;++u){
        const int rr = 2*(oh_l0 + 4*u) + kh;
        const uint4* xp = (const uint4*)(xt + ((((par*19) + rr)*18) + (ow + kws))*24);
        #pragma unroll
        for (int m=0;m<3;++m){
          uint4 v = xp[m];
          xs[u][m*4+0]=v.x; xs[u][m*4+1]=v.y; xs[u][m*4+2]=v.z; xs[u][m*4+3]=v.w;
        }
      }
      const int ro = __builtin_amdgcn_readfirstlane(((kh*5+kw)*36 + co0)*24);
      const f16* wb = w2r + ro;
      #pragma unroll
      for (int c=0;c<6;++c){
        const uint4* wp = (const uint4*)(wb + c*24);
        uint4 w0 = wp[0], w1 = wp[1], w2 = wp[2];
        unsigned ws_[12] = {w0.x,w0.y,w0.z,w0.w, w1.x,w1.y,w1.z,w1.w, w2.x,w2.y,w2.z,w2.w};
        #pragma unroll
        for (int u=0;u<2;++u){
          float s = acc[u][c];
          #pragma unroll
          for (int p=0;p<12;++p) s = fdot2(xs[u][p], ws_[p], s);
          acc[u][c] = s;
        }
      }
    }
  }
  #pragma unroll
  for (int u=0;u<2;++u){
    int px = u*64 + lane;
    if (px >= npx) continue;
    int oh_l = px >> 4;
    union { f16 h[6]; unsigned w[3]; } pk;
    #pragma unroll
    for (int c=0;c<6;++c){ float r = acc[u][c]; if (r<0.f) r=0.f; pk.h[c]=(f16)r; }
    unsigned* dst = (unsigned*)(a2 + (((size_t)i*47 + oh0+oh_l)*16 + ow)*36 + co0);
    dst[0]=pk.w[0]; dst[1]=pk.w[1]; dst[2]=pk.w[2];
  }
}

// ---------------------------------------------------------------- conv3
// a2 NHWC (Bc,47,16,36) -> a3 NHWC (Bc,22,6,48). grid=Bc*3 (oh tiles of 8), block=384 (6 waves)
// wave w -> co [8w, 8w+8); lane -> px (oh=lane>>3, ow=lane&7; ow 6,7 computed + discarded).
__global__ __launch_bounds__(384) void conv3_k(const f16* __restrict__ a2, const f16* __restrict__ w3r,
                                               const float* __restrict__ b3, f16* __restrict__ a3){
  __shared__ __align__(16) f16 xt[2*19*10*40];   // 30400 B, [par][rr19][col'10][ci40]
  const int tid = threadIdx.x, bx = blockIdx.x;
  const int i = bx / 3, t = bx - i*3;
  const int oh0 = t*8, r0 = t*16;
  {
    const uint* src = (const uint*)a2;
    uint* d = (uint*)xt;
    for (int idx = tid; idx < 7600; idx += 384){
      int cdw = idx % 20, rest = idx / 20;
      int c2 = rest % 10, rest2 = rest / 10;
      int rr = rest2 % 19, par = rest2 / 19;
      int col = c2*2 + par, r = r0 + rr;
      uint v = (r < 47 && col < 16 && cdw < 18) ? src[(((size_t)i*47 + r)*16 + col)*18 + cdw] : 0u;
      d[idx] = v;
    }
  }
  __syncthreads();
  const int wv = tid >> 6, lane = tid & 63;
  const int co0 = wv*8;
  const int oh_l = lane >> 3, ow = lane & 7;
  float acc[8];
  #pragma unroll
  for (int c=0;c<8;++c) acc[c] = b3[co0+c];
  #pragma unroll 1
  for (int kh=0; kh<5; ++kh){
    #pragma unroll 1
    for (int kw=0; kw<5; ++kw){
      const int par = kw & 1, kws = kw >> 1;
      const int rr = 2*oh_l + kh;
      const uint4* xp = (const uint4*)(xt + (((par*19 + rr)*10) + (ow + kws))*40);
      unsigned xs[20];
      #pragma unroll
      for (int m=0;m<5;++m){
        uint4 v = xp[m];
        xs[m*4+0]=v.x; xs[m*4+1]=v.y; xs[m*4+2]=v.z; xs[m*4+3]=v.w;
      }
      const int ro = __builtin_amdgcn_readfirstlane(((kh*5+kw)*48 + co0)*40);
      const f16* wb = w3r + ro;
      #pragma unroll
      for (int c=0;c<8;++c){
        const uint4* wp = (const uint4*)(wb + c*40);
        unsigned ws_[20];
        #pragma unroll
        for (int m=0;m<5;++m){
          uint4 v = wp[m];
          ws_[m*4+0]=v.x; ws_[m*4+1]=v.y; ws_[m*4+2]=v.z; ws_[m*4+3]=v.w;
        }
        float s = acc[c];
        #pragma unroll
        for (int p=0;p<20;++p) s = fdot2(xs[p], ws_[p], s);
        acc[c] = s;
      }
    }
  }
  if (ow < 6 && oh0 + oh_l < 22){
    union { f16 h[8]; uint4 q; } pk;
    #pragma unroll
    for (int c=0;c<8;++c){ float r = acc[c]; if (r<0.f) r=0.f; pk.h[c]=(f16)r; }
    *(uint4*)(a3 + (((size_t)i*22 + oh0+oh_l)*6 + ow)*48 + co0) = pk.q;
  }
}

// ---------------------------------------------------------------- conv4
// a3 NHWC (Bc,22,6,48) -> a4 (Bc, sp80, co64) f16. grid=Bc, block=256 (4 waves)
// wave w -> co [16w,16w+16); lane 2 px (u=1: lanes<16). ci pad 48->56 (28dw stride, ~2-way).
__global__ __launch_bounds__(256) void conv4_k(const f16* __restrict__ a3, const f16* __restrict__ w4r,
                                               const float* __restrict__ b4, f16* __restrict__ a4){
  __shared__ __align__(16) f16 xt[22*6*56];   // 14784 B
  const int tid = threadIdx.x;
  const int i = blockIdx.x;
  {
    const uint* src = (const uint*)a3 + (size_t)i*3168;
    uint* d = (uint*)xt;
    for (int idx = tid; idx < 3168; idx += 256){
      int cdw = idx % 24, sp = idx / 24;           // sp = row*6+col
      d[sp*28 + cdw] = src[idx];
    }
  }
  __syncthreads();
  const int wv = tid >> 6, lane = tid & 63;
  const int co0 = wv*16;
  float acc[2][16];
  #pragma unroll
  for (int c=0;c<16;++c){
    float bb = b4[co0+c];
    acc[0][c] = bb; acc[1][c] = bb;
  }
  const int oh_u0 = lane >> 2, ow = lane & 3;
  const int oh_u1 = (lane < 16) ? 16 + (lane >> 2) : oh_u0;   // clamp inactive lanes in-bounds
  #pragma unroll 1
  for (int kh=0; kh<3; ++kh){
    #pragma unroll 1
    for (int kw=0; kw<3; ++kw){
      unsigned xs[2][24];
      #pragma unroll
      for (int u=0;u<2;++u){
        const int rr = (u ? oh_u1 : oh_u0) + kh;
        const uint4* xp = (const uint4*)(xt + (rr*6 + (ow+kw))*56);
        #pragma unroll
        for (int m=0;m<6;++m){
          uint4 v = xp[m];
          xs[u][m*4+0]=v.x; xs[u][m*4+1]=v.y; xs[u][m*4+2]=v.z; xs[u][m*4+3]=v.w;
        }
      }
      const int ro = __builtin_amdgcn_readfirstlane(((kh*3+kw)*64 + co0)*48);
      const f16* wb = w4r + ro;
      #pragma unroll
      for (int c=0;c<16;++c){
        const uint4* wp = (const uint4*)(wb + c*48);
        unsigned ws_[24];
        #pragma unroll
        for (int m=0;m<6;++m){
          uint4 v = wp[m];
          ws_[m*4+0]=v.x; ws_[m*4+1]=v.y; ws_[m*4+2]=v.z; ws_[m*4+3]=v.w;
        }
        #pragma unroll
        for (int u=0;u<2;++u){
          float s = acc[u][c];
          #pragma unroll
          for (int p=0;p<24;++p) s = fdot2(xs[u][p], ws_[p], s);
          acc[u][c] = s;
        }
      }
    }
  }
  #pragma unroll
  for (int u=0;u<2;++u){
    if (u == 1 && lane >= 16) continue;
    int sp = (u ? (64 + lane) : lane);
    union { f16 h[16]; uint4 q[2]; } pk;
    #pragma unroll
    for (int c=0;c<16;++c){ float r = acc[u][c]; if (r<0.f) r=0.f; pk.h[c]=(f16)r; }
    uint4* dst = (uint4*)(a4 + ((size_t)i*80 + sp)*64 + co0);
    dst[0] = pk.q[0]; dst[1] = pk.q[1];
  }
}

// ---------------------------------------------------------------- fc1 (K-split partials; W rows permuted for NHWC a4)
__global__ __launch_bounds__(256) void fc1p_k(const f16* __restrict__ a4, const float* __restrict__ fc1W,
                                              float* __restrict__ x1p, int Bc){
  __shared__ __align__(16) f16 xa[8192];   // [32 img][256 k]
  __shared__ __align__(16) f16 Wc[25600];  // [256 k][100 j]
  const int tid = threadIdx.x;
  const int bx = blockIdx.x;
  const int s  = blockIdx.y;
  const int img_g = tid / 25;
  const int j_g   = tid % 25;
  float acc[4][4] = {};
  for (int cc=0; cc<2; ++cc){
    const int k0 = s*512 + cc*256;
    __syncthreads();
    {
      const uint* src = (const uint*)a4;
      uint* d = (uint*)xa;
      for (int idx = tid; idx < 4096; idx += 256){
        int il = idx >> 7, w2 = idx & 127;
        d[idx] = src[((size_t)(bx*32 + il))*2560 + (k0>>1) + w2];
      }
      for (int idx = tid; idx < 25600; idx += 256){
        int kk = idx / 100, j = idx - kk*100;
        int k = k0 + kk;
        int row = (k & 63)*80 + (k >> 6);   // NHWC k -> original NCHW-flat row
        Wc[idx] = (f16)fc1W[(size_t)row*100 + j];
      }
    }
    __syncthreads();
    if (tid < 200){
      #pragma unroll 1
      for (int kk=0; kk<256; ++kk){
        float xv[4], wv[4];
        #pragma unroll
        for (int a=0;a<4;++a) xv[a] = (float)xa[(img_g*4+a)*256 + kk];
        #pragma unroll
        for (int b=0;b<4;++b) wv[b] = (float)Wc[kk*100 + j_g*4 + b];
        #pragma unroll
        for (int a=0;a<4;++a)
          #pragma unroll
          for (int b=0;b<4;++b) acc[a][b] = fmaf(xv[a], wv[b], acc[a][b]);
      }
    }
  }
  if (tid < 200){
    #pragma unroll
    for (int a=0;a<4;++a)
      #pragma unroll
      for (int b=0;b<4;++b)
        x1p[((size_t)s*Bc + bx*32 + img_g*4 + a)*100 + j_g*4 + b] = acc[a][b];
  }
}

__global__ __launch_bounds__(256) void fc1r_k(const float* __restrict__ x1p, const float* __restrict__ fc1b,
                                              float* __restrict__ x1, int Bc){
  int tt = blockIdx.x*256 + threadIdx.x;
  if (tt >= Bc*100) return;
  int il = tt / 100, j = tt - il*100;
  float s = fc1b[j];
  #pragma unroll
  for (int k=0;k<10;++k) s += x1p[((size_t)k*Bc + il)*100 + j];
  x1[tt] = s > 0.f ? s : 0.f;
}

// ---------------------------------------------------------------- fc2..fc4 + AEBS head
__global__ __launch_bounds__(256) void tail_k(const float* __restrict__ x1,
    const float* __restrict__ dist, const float* __restrict__ speed,
    const float* __restrict__ fW2, const float* __restrict__ fb2,
    const float* __restrict__ fW3, const float* __restrict__ fb3,
    const float* __restrict__ fW4, const float* __restrict__ fb4,
    const float* __restrict__ aW1, const float* __restrict__ ab1,
    const float* __restrict__ aW2, const float* __restrict__ ab2,
    const float* __restrict__ aW3, const float* __restrict__ ab3,
    float* __restrict__ out, int ib){
  __shared__ float w2s[5000], b2s[50], w3s[500], b3s[10], w4s[10];
  __shared__ float wa1s[36], ba1s[12], wa2s[288], ba2s[24], wa3s[96], ba3s[4];
  __shared__ float b4s;
  __shared__ float x1s[4][100], h2[4][50], h3[4][10], stg[4], hb1[4][12], hb2[4][24];
  const int tid = threadIdx.x;
  for (int j=tid;j<5000;j+=256) w2s[j]=fW2[j];
  for (int j=tid;j<500;j+=256)  w3s[j]=fW3[j];
  for (int j=tid;j<288;j+=256)  wa2s[j]=aW2[j];
  if (tid<50) b2s[tid]=fb2[tid];
  if (tid<10) b3s[tid]=fb3[tid];
  if (tid<10) w4s[tid]=fW4[tid];
  if (tid==0) b4s=fb4[0];
  if (tid<36) wa1s[tid]=aW1[tid];
  if (tid<12) ba1s[tid]=ab1[tid];
  if (tid<24) ba2s[tid]=ab2[tid];
  if (tid<96) wa3s[tid]=aW3[tid];
  if (tid<4)  ba3s[tid]=ab3[tid];
  for (int idx=tid; idx<400; idx+=256){
    int gg = idx/100, k = idx-gg*100;
    x1s[gg][k] = x1[(size_t)(blockIdx.x*4+gg)*100 + k];
  }
  __syncthreads();
  const int g = tid >> 6, lane = tid & 63;
  const int img_l = blockIdx.x*4 + g;
  if (lane < 50){
    float s = b2s[lane];
    #pragma unroll 4
    for (int k=0;k<100;++k) s = fmaf(x1s[g][k], w2s[k*50+lane], s);
    h2[g][lane] = s > 0.f ? s : 0.f;
  }
  __syncthreads();
  if (lane < 10){
    float s = b3s[lane];
    #pragma unroll
    for (int k=0;k<50;++k) s = fmaf(h2[g][k], w3s[k*10+lane], s);
    h3[g][lane] = s > 0.f ? s : 0.f;
  }
  __syncthreads();
  if (lane == 0){
    float s = b4s;
    #pragma unroll
    for (int k=0;k<10;++k) s = fmaf(h3[g][k], w4s[k], s);
    stg[g] = s;
  }
  __syncthreads();
  if (lane < 12){
    float s0 = stg[g], dd = dist[ib+img_l], sp = speed[ib+img_l];
    float s = ba1s[lane] + s0*wa1s[lane] + dd*wa1s[12+lane] + sp*wa1s[24+lane];
    hb1[g][lane] = s > 0.f ? s : 0.f;
  }
  __syncthreads();
  if (lane < 24){
    float s = ba2s[lane];
    #pragma unroll
    for (int k=0;k<12;++k) s = fmaf(hb1[g][k], wa2s[k*24+lane], s);
    hb2[g][lane] = s > 0.f ? s : 0.f;
  }
  __syncthreads();
  if (lane < 4){
    float s = ba3s[lane];
    #pragma unroll
    for (int k=0;k<24;++k) s = fmaf(hb2[g][k], wa3s[k*4+lane], s);
    out[(size_t)(ib+img_l)*4 + lane] = s;
  }
}

// ================================================================ host
extern "C" void kernel_launch(void* const* d_in, const int* in_sizes, int n_in,
                              void* d_out, int out_size, void* d_ws, size_t ws_size,
                              hipStream_t stream){
  const float* rgb   = (const float*)d_in[0];
  const float* dist  = (const float*)d_in[1];
  const float* speed = (const float*)d_in[2];
  const float* cw1 = (const float*)d_in[3];
  const float* cb1 = (const float*)d_in[4];
  const float* cw2 = (const float*)d_in[5];
  const float* cb2 = (const float*)d_in[6];
  const float* cw3 = (const float*)d_in[7];
  const float* cb3 = (const float*)d_in[8];
  const float* cw4 = (const float*)d_in[9];
  const float* cb4 = (const float*)d_in[10];
  const float* fW1 = (const float*)d_in[11];
  const float* fb1 = (const float*)d_in[12];
  const float* fW2 = (const float*)d_in[13];
  const float* fb2 = (const float*)d_in[14];
  const float* fW3 = (const float*)d_in[15];
  const float* fb3 = (const float*)d_in[16];
  const float* fW4 = (const float*)d_in[17];
  const float* fb4 = (const float*)d_in[18];
  const float* aW1 = (const float*)d_in[19];
  const float* ab1 = (const float*)d_in[20];
  const float* aW2 = (const float*)d_in[21];
  const float* ab2 = (const float*)d_in[22];
  const float* aW3 = (const float*)d_in[23];
  const float* ab3 = (const float*)d_in[24];
  float* out = (float*)d_out;
  const int B = in_sizes[0] / 15000;

  auto ALN = [](size_t x){ return (x + 255) & ~(size_t)255; };
  const size_t fixed = ALN(21600*2) + ALN(48000*2) + ALN(27648*2);

  int nc = 1;
  while (nc < 32){
    size_t Bc = (size_t)(B / nc);
    size_t need = fixed + ALN(Bc*169344) + ALN(Bc*54144) + ALN(Bc*12672)
                        + ALN(Bc*10240)  + ALN(Bc*400)   + ALN(Bc*4000);
    if (need <= ws_size) break;
    nc *= 2;
  }
  const int Bc = B / nc;

  char* ws = (char*)d_ws;
  size_t o = 0;
  auto alloc = [&](size_t bytes)->char*{ char* p = ws + o; o += ALN(bytes); return p; };
  f16* w2r = (f16*)alloc(21600*2);
  f16* w3r = (f16*)alloc(48000*2);
  f16* w4r = (f16*)alloc(27648*2);
  f16* a1  = (f16*)alloc((size_t)Bc*169344);
  f16* a2  = (f16*)alloc((size_t)Bc*54144);
  f16* a3  = (f16*)alloc((size_t)Bc*12672);
  f16* a4  = (f16*)alloc((size_t)Bc*10240);
  float* x1  = (float*)alloc((size_t)Bc*400);
  float* x1p = (float*)alloc((size_t)Bc*4000);

  repack2_k<<<dim3(85),  dim3(256), 0, stream>>>(w2r, cw2);
  repack3_k<<<dim3(188), dim3(256), 0, stream>>>(w3r, cw3);
  repack4_k<<<dim3(108), dim3(256), 0, stream>>>(w4r, cw4);

  for (int c = 0; c < nc; ++c){
    const int ib = c*Bc;
    conv1_k<<<dim3(Bc*7), dim3(128), 0, stream>>>(rgb, cw1, cb1, a1, ib);
    conv2_k<<<dim3(Bc*6), dim3(384), 0, stream>>>(a1, w2r, cb2, a2);
    conv3_k<<<dim3(Bc*3), dim3(384), 0, stream>>>(a2, w3r, cb3, a3);
    conv4_k<<<dim3(Bc),   dim3(256), 0, stream>>>(a3, w4r, cb4, a4);
    fc1p_k<<<dim3(Bc/32, 10), dim3(256), 0, stream>>>(a4, fW1, x1p, Bc);
    fc1r_k<<<dim3((Bc*100+255)/256), dim3(256), 0, stream>>>(x1p, fb1, x1, Bc);
    tail_k<<<dim3(Bc/4), dim3(256), 0, stream>>>(x1, dist, speed,
        fW2, fb2, fW3, fb3, fW4, fb4, aW1, ab1, aW2, ab2, aW3, ab3, out, ib);
  }
}

// Round 4
// 646.163 us; speedup vs baseline: 3.9121x; 1.2438x over previous
//
#include <hip/hip_runtime.h>

typedef _Float16 f16;
typedef __fp16 hh2 __attribute__((ext_vector_type(2)));
typedef _Float16 f16x8 __attribute__((ext_vector_type(8)));
typedef float f32x4 __attribute__((ext_vector_type(4)));

// ---- fdot2: v_dot2_f32_f16 (f16 pair dot, f32 accum) with compile-safe fallback
#if defined(__has_builtin)
#if __has_builtin(__builtin_amdgcn_fdot2)
#define HAVE_FDOT2 1
#endif
#endif
static __device__ inline hh2 as_h2(unsigned u){ union{unsigned u; hh2 h;} x; x.u = u; return x.h; }
static __device__ inline float fdot2(unsigned xu, unsigned wu, float c){
#ifdef HAVE_FDOT2
  return __builtin_amdgcn_fdot2(as_h2(xu), as_h2(wu), c, false);
#else
  hh2 a = as_h2(xu), b = as_h2(wu);
  return fmaf((float)a.x, (float)b.x, fmaf((float)a.y, (float)b.y, c));
#endif
}

// ---------------------------------------------------------------- weight repack
// w2m: MFMA A-fragments. [s25][mt3][lane64][8] ; lane: co = mt*16+(l&15), k = (l>>4)*8+i (ci, >=24 -> 0)
__global__ __launch_bounds__(256) void repack2m_k(f16* __restrict__ dst, const float* __restrict__ src){
  for (int idx = blockIdx.x*256 + threadIdx.x; idx < 38400; idx += gridDim.x*256){
    int i = idx & 7, l = (idx >> 3) & 63, rest = idx >> 9;
    int mt = rest % 3, s = rest / 3;
    int co = mt*16 + (l & 15);
    int kloc = (l >> 4)*8 + i;
    dst[idx] = (co < 36 && kloc < 24) ? (f16)src[(co*24 + kloc)*25 + s] : (f16)0.0f;
  }
}
// w3r [p25][co48][ci40 pad0] f16
__global__ __launch_bounds__(256) void repack3_k(f16* __restrict__ dst, const float* __restrict__ src){
  for (int idx = blockIdx.x*256 + threadIdx.x; idx < 48000; idx += gridDim.x*256){
    int ci = idx % 40, r = idx / 40, co = r % 48, p = r / 48;
    dst[idx] = (ci < 36) ? (f16)src[(co*36 + ci)*25 + p] : (f16)0.0f;
  }
}
// w4r [p9][co64][ci48] f16
__global__ __launch_bounds__(256) void repack4_k(f16* __restrict__ dst, const float* __restrict__ src){
  for (int idx = blockIdx.x*256 + threadIdx.x; idx < 27648; idx += gridDim.x*256){
    int ci = idx % 48, r = idx / 48, co = r % 64, p = r / 64;
    dst[idx] = (f16)src[(co*48 + ci)*9 + p];
  }
}

// ---------------------------------------------------------------- conv1 (fused binarize)
// rgb (B,15000) f32 [w75][h200] -> a1 NHWC (Bc,98,36,24) f16. grid=Bc*7 (oh tiles of 14), block=128
__global__ __launch_bounds__(128) void conv1_k(const float* __restrict__ rgb, const float* __restrict__ w1,
                                               const float* __restrict__ b1, f16* __restrict__ a1, int ib){
  __shared__ float xi[31*76];   // [hh31][w75(+1)]
  __shared__ float wr[600];     // [p25][co24]
  __shared__ float bl[24];
  const int tid = threadIdx.x, bx = blockIdx.x;
  const int i = bx / 7, t = bx - i*7;
  const int oh0 = t*14;
  const float* img = rgb + (size_t)(ib + i)*15000;
  for (int idx = tid; idx < 2325; idx += 128){
    int a = idx / 31, hh = idx - a*31;          // a = w, hh = local h
    float v = img[a*200 + 2*oh0 + hh];
    xi[hh*76 + a] = (v > 0.f) ? 1.0f : 0.0f;
  }
  for (int idx = tid; idx < 600; idx += 128){
    int p = idx / 24, co = idx - p*24;
    wr[idx] = w1[co*25 + p];
  }
  if (tid < 24) bl[tid] = b1[tid];
  __syncthreads();
  int ohl[4], owl[4]; bool act[4];
  #pragma unroll
  for (int u=0;u<4;++u){
    int sp = u*128 + tid;
    act[u] = sp < 504;
    int s = act[u] ? sp : 0;
    ohl[u] = s / 36; owl[u] = s - ohl[u]*36;
  }
  float acc[4][24] = {};
  #pragma unroll 1
  for (int kh=0; kh<5; ++kh){
    #pragma unroll 1
    for (int kw=0; kw<5; ++kw){
      float wv[24];
      #pragma unroll
      for (int c=0;c<24;++c) wv[c] = wr[(kh*5+kw)*24 + c];
      #pragma unroll
      for (int u=0;u<4;++u){
        float x = xi[(2*ohl[u]+kh)*76 + 2*owl[u]+kw];
        #pragma unroll
        for (int c=0;c<24;++c) acc[u][c] = fmaf(x, wv[c], acc[u][c]);
      }
    }
  }
  #pragma unroll
  for (int u=0;u<4;++u){
    if (!act[u]) continue;
    union { f16 h[24]; uint4 q[3]; } pk;
    #pragma unroll
    for (int c=0;c<24;++c){
      float r = acc[u][c] + bl[c]; if (r < 0.f) r = 0.f;
      pk.h[c] = (f16)r;
    }
    size_t base = (((size_t)i*98 + oh0 + ohl[u])*36 + owl[u])*24;
    uint4* dst = (uint4*)(a1 + base);
    dst[0] = pk.q[0]; dst[1] = pk.q[1]; dst[2] = pk.q[2];
  }
}

// ---------------------------------------------------------------- conv2 (MFMA implicit GEMM)
// a1 NHWC (Bc,98,36,24) -> a2 NHWC (Bc,47,16,36). grid=Bc*3 (oh tiles of 16), block=256 (4 waves)
// D[co48][px16] per (mt,row): A = w2m fragments (global, coalesced), B = x from LDS.
// K = 25 steps of 32 (ci pad 32; zeros are in A, B's j=3 group reads clamped finite data).
__global__ __launch_bounds__(256) void conv2_k(const f16* __restrict__ a1, const f16* __restrict__ w2m,
                                               const float* __restrict__ b2, f16* __restrict__ a2){
  __shared__ __align__(16) f16 xt[2*35*18*24];   // [par][rr35][colp18][ci24] = 60480 B
  const int tid = threadIdx.x, bx = blockIdx.x;
  const int i = bx / 3, t = bx - i*3;
  const int oh0 = t*16, r0 = t*32;
  {
    const uint* src = (const uint*)a1 + (size_t)i*98*432/2*2;   // 98*432 dw per image
    const uint* s2 = (const uint*)a1 + (size_t)i*42336;
    (void)src;
    uint* d = (uint*)xt;
    for (int idx = tid; idx < 15120; idx += 256){
      int rr = idx / 432, q = idx - rr*432;
      int col = q / 12, cdw = q - col*12;
      int r = r0 + rr;
      uint v = (r < 98) ? s2[(size_t)r*432 + q] : 0u;
      d[(((col & 1)*35 + rr)*18 + (col >> 1))*12 + cdw] = v;
    }
  }
  __syncthreads();
  const int wv = tid >> 6, lane = tid & 63;
  const int n_ow = lane & 15;          // px col (ow), N index
  const int jgrp = lane >> 4;
  const int ci0 = (jgrp == 3) ? 0 : jgrp*8;
  // bias into accumulators: row (co) = mt*16 + jgrp*4 + reg
  f32x4 acc[3][4];
  #pragma unroll
  for (int mt=0; mt<3; ++mt){
    f32x4 bv;
    #pragma unroll
    for (int reg=0; reg<4; ++reg){
      int co = mt*16 + jgrp*4 + reg;
      bv[reg] = (co < 36) ? b2[co] : 0.0f;
    }
    #pragma unroll
    for (int u=0; u<4; ++u) acc[mt][u] = bv;
  }
  const f16* agl = w2m + (size_t)lane*8;
  #pragma unroll 1
  for (int kh=0; kh<5; ++kh){
    #pragma unroll
    for (int kw=0; kw<5; ++kw){
      const int s = kh*5 + kw;
      f16x8 af[3];
      #pragma unroll
      for (int mt=0; mt<3; ++mt)
        af[mt] = *(const f16x8*)(agl + (size_t)(s*3 + mt)*512);
      const int par = kw & 1, kws = kw >> 1;
      const int colp = n_ow + kws;
      const f16* bb0 = xt + ((par*35 + kh)*18 + colp)*24 + ci0;   // rr = 8wv+2u+kh added below
      f16x8 bf[4];
      #pragma unroll
      for (int u=0; u<4; ++u)
        bf[u] = *(const f16x8*)(bb0 + (8*wv + 2*u)*432);
      #pragma unroll
      for (int mt=0; mt<3; ++mt)
        #pragma unroll
        for (int u=0; u<4; ++u)
          acc[mt][u] = __builtin_amdgcn_mfma_f32_16x16x32_f16(af[mt], bf[u], acc[mt][u], 0, 0, 0);
    }
  }
  // store: D col = px (n_ow), rows = co = mt*16 + jgrp*4 + reg (4 consecutive f16 -> b64)
  #pragma unroll
  for (int u=0; u<4; ++u){
    const int oh = oh0 + 4*wv + u;
    if (oh >= 47) continue;
    #pragma unroll
    for (int mt=0; mt<3; ++mt){
      const int co0s = mt*16 + jgrp*4;
      if (co0s >= 36) continue;
      union { f16 h[4]; uint2 q; } pk;
      #pragma unroll
      for (int reg=0; reg<4; ++reg){
        float r = acc[mt][u][reg]; if (r < 0.f) r = 0.f;
        pk.h[reg] = (f16)r;
      }
      *(uint2*)(a2 + (((size_t)i*47 + oh)*16 + n_ow)*36 + co0s) = pk.q;
    }
  }
}

// ---------------------------------------------------------------- conv3
// a2 NHWC (Bc,47,16,36) -> a3 NHWC (Bc,22,6,48). grid=Bc*3 (oh tiles of 8), block=384 (6 waves)
__global__ __launch_bounds__(384) void conv3_k(const f16* __restrict__ a2, const f16* __restrict__ w3r,
                                               const float* __restrict__ b3, f16* __restrict__ a3){
  __shared__ __align__(16) f16 xt[2*19*10*40];   // 30400 B, [par][rr19][col'10][ci40]
  const int tid = threadIdx.x, bx = blockIdx.x;
  const int i = bx / 3, t = bx - i*3;
  const int oh0 = t*8, r0 = t*16;
  {
    const uint* src = (const uint*)a2;
    uint* d = (uint*)xt;
    for (int idx = tid; idx < 7600; idx += 384){
      int cdw = idx % 20, rest = idx / 20;
      int c2 = rest % 10, rest2 = rest / 10;
      int rr = rest2 % 19, par = rest2 / 19;
      int col = c2*2 + par, r = r0 + rr;
      uint v = (r < 47 && col < 16 && cdw < 18) ? src[(((size_t)i*47 + r)*16 + col)*18 + cdw] : 0u;
      d[idx] = v;
    }
  }
  __syncthreads();
  const int wv = tid >> 6, lane = tid & 63;
  const int co0 = wv*8;
  const int oh_l = lane >> 3, ow = lane & 7;
  float acc[8];
  #pragma unroll
  for (int c=0;c<8;++c) acc[c] = b3[co0+c];
  #pragma unroll 1
  for (int kh=0; kh<5; ++kh){
    #pragma unroll 1
    for (int kw=0; kw<5; ++kw){
      const int par = kw & 1, kws = kw >> 1;
      const int rr = 2*oh_l + kh;
      const uint4* xp = (const uint4*)(xt + (((par*19 + rr)*10) + (ow + kws))*40);
      unsigned xs[20];
      #pragma unroll
      for (int m=0;m<5;++m){
        uint4 v = xp[m];
        xs[m*4+0]=v.x; xs[m*4+1]=v.y; xs[m*4+2]=v.z; xs[m*4+3]=v.w;
      }
      const int ro = __builtin_amdgcn_readfirstlane(((kh*5+kw)*48 + co0)*40);
      const f16* wb = w3r + ro;
      #pragma unroll
      for (int c=0;c<8;++c){
        const uint4* wp = (const uint4*)(wb + c*40);
        unsigned ws_[20];
        #pragma unroll
        for (int m=0;m<5;++m){
          uint4 v = wp[m];
          ws_[m*4+0]=v.x; ws_[m*4+1]=v.y; ws_[m*4+2]=v.z; ws_[m*4+3]=v.w;
        }
        float s = acc[c];
        #pragma unroll
        for (int p=0;p<20;++p) s = fdot2(xs[p], ws_[p], s);
        acc[c] = s;
      }
    }
  }
  if (ow < 6 && oh0 + oh_l < 22){
    union { f16 h[8]; uint4 q; } pk;
    #pragma unroll
    for (int c=0;c<8;++c){ float r = acc[c]; if (r<0.f) r=0.f; pk.h[c]=(f16)r; }
    *(uint4*)(a3 + (((size_t)i*22 + oh0+oh_l)*6 + ow)*48 + co0) = pk.q;
  }
}

// ---------------------------------------------------------------- conv4
// a3 NHWC (Bc,22,6,48) -> a4 (Bc, sp80, co64) f16. grid=Bc, block=256 (4 waves)
__global__ __launch_bounds__(256) void conv4_k(const f16* __restrict__ a3, const f16* __restrict__ w4r,
                                               const float* __restrict__ b4, f16* __restrict__ a4){
  __shared__ __align__(16) f16 xt[22*6*56];   // 14784 B
  const int tid = threadIdx.x;
  const int i = blockIdx.x;
  {
    const uint* src = (const uint*)a3 + (size_t)i*3168;
    uint* d = (uint*)xt;
    for (int idx = tid; idx < 3168; idx += 256){
      int cdw = idx % 24, sp = idx / 24;           // sp = row*6+col
      d[sp*28 + cdw] = src[idx];
    }
  }
  __syncthreads();
  const int wv = tid >> 6, lane = tid & 63;
  const int co0 = wv*16;
  float acc[2][16];
  #pragma unroll
  for (int c=0;c<16;++c){
    float bb = b4[co0+c];
    acc[0][c] = bb; acc[1][c] = bb;
  }
  const int oh_u0 = lane >> 2, ow = lane & 3;
  const int oh_u1 = (lane < 16) ? 16 + (lane >> 2) : oh_u0;   // clamp inactive lanes in-bounds
  #pragma unroll 1
  for (int kh=0; kh<3; ++kh){
    #pragma unroll 1
    for (int kw=0; kw<3; ++kw){
      unsigned xs[2][24];
      #pragma unroll
      for (int u=0;u<2;++u){
        const int rr = (u ? oh_u1 : oh_u0) + kh;
        const uint4* xp = (const uint4*)(xt + (rr*6 + (ow+kw))*56);
        #pragma unroll
        for (int m=0;m<6;++m){
          uint4 v = xp[m];
          xs[u][m*4+0]=v.x; xs[u][m*4+1]=v.y; xs[u][m*4+2]=v.z; xs[u][m*4+3]=v.w;
        }
      }
      const int ro = __builtin_amdgcn_readfirstlane(((kh*3+kw)*64 + co0)*48);
      const f16* wb = w4r + ro;
      #pragma unroll
      for (int c=0;c<16;++c){
        const uint4* wp = (const uint4*)(wb + c*48);
        unsigned ws_[24];
        #pragma unroll
        for (int m=0;m<6;++m){
          uint4 v = wp[m];
          ws_[m*4+0]=v.x; ws_[m*4+1]=v.y; ws_[m*4+2]=v.z; ws_[m*4+3]=v.w;
        }
        #pragma unroll
        for (int u=0;u<2;++u){
          float s = acc[u][c];
          #pragma unroll
          for (int p=0;p<24;++p) s = fdot2(xs[u][p], ws_[p], s);
          acc[u][c] = s;
        }
      }
    }
  }
  #pragma unroll
  for (int u=0;u<2;++u){
    if (u == 1 && lane >= 16) continue;
    int sp = (u ? (64 + lane) : lane);
    union { f16 h[16]; uint4 q[2]; } pk;
    #pragma unroll
    for (int c=0;c<16;++c){ float r = acc[u][c]; if (r<0.f) r=0.f; pk.h[c]=(f16)r; }
    uint4* dst = (uint4*)(a4 + ((size_t)i*80 + sp)*64 + co0);
    dst[0] = pk.q[0]; dst[1] = pk.q[1];
  }
}

// ---------------------------------------------------------------- fc1 (K-split partials; W rows permuted for NHWC a4)
__global__ __launch_bounds__(256) void fc1p_k(const f16* __restrict__ a4, const float* __restrict__ fc1W,
                                              float* __restrict__ x1p, int Bc){
  __shared__ __align__(16) f16 xa[8192];   // [32 img][256 k]
  __shared__ __align__(16) f16 Wc[25600];  // [256 k][100 j]
  const int tid = threadIdx.x;
  const int bx = blockIdx.x;
  const int s  = blockIdx.y;
  const int img_g = tid / 25;
  const int j_g   = tid % 25;
  float acc[4][4] = {};
  for (int cc=0; cc<2; ++cc){
    const int k0 = s*512 + cc*256;
    __syncthreads();
    {
      const uint* src = (const uint*)a4;
      uint* d = (uint*)xa;
      for (int idx = tid; idx < 4096; idx += 256){
        int il = idx >> 7, w2 = idx & 127;
        d[idx] = src[((size_t)(bx*32 + il))*2560 + (k0>>1) + w2];
      }
      for (int idx = tid; idx < 25600; idx += 256){
        int kk = idx / 100, j = idx - kk*100;
        int k = k0 + kk;
        int row = (k & 63)*80 + (k >> 6);   // NHWC k -> original NCHW-flat row
        Wc[idx] = (f16)fc1W[(size_t)row*100 + j];
      }
    }
    __syncthreads();
    if (tid < 200){
      #pragma unroll 1
      for (int kk=0; kk<256; ++kk){
        float xv[4], wv[4];
        #pragma unroll
        for (int a=0;a<4;++a) xv[a] = (float)xa[(img_g*4+a)*256 + kk];
        #pragma unroll
        for (int b=0;b<4;++b) wv[b] = (float)Wc[kk*100 + j_g*4 + b];
        #pragma unroll
        for (int a=0;a<4;++a)
          #pragma unroll
          for (int b=0;b<4;++b) acc[a][b] = fmaf(xv[a], wv[b], acc[a][b]);
      }
    }
  }
  if (tid < 200){
    #pragma unroll
    for (int a=0;a<4;++a)
      #pragma unroll
      for (int b=0;b<4;++b)
        x1p[((size_t)s*Bc + bx*32 + img_g*4 + a)*100 + j_g*4 + b] = acc[a][b];
  }
}

__global__ __launch_bounds__(256) void fc1r_k(const float* __restrict__ x1p, const float* __restrict__ fc1b,
                                              float* __restrict__ x1, int Bc){
  int tt = blockIdx.x*256 + threadIdx.x;
  if (tt >= Bc*100) return;
  int il = tt / 100, j = tt - il*100;
  float s = fc1b[j];
  #pragma unroll
  for (int k=0;k<10;++k) s += x1p[((size_t)k*Bc + il)*100 + j];
  x1[tt] = s > 0.f ? s : 0.f;
}

// ---------------------------------------------------------------- fc2..fc4 + AEBS head
__global__ __launch_bounds__(256) void tail_k(const float* __restrict__ x1,
    const float* __restrict__ dist, const float* __restrict__ speed,
    const float* __restrict__ fW2, const float* __restrict__ fb2,
    const float* __restrict__ fW3, const float* __restrict__ fb3,
    const float* __restrict__ fW4, const float* __restrict__ fb4,
    const float* __restrict__ aW1, const float* __restrict__ ab1,
    const float* __restrict__ aW2, const float* __restrict__ ab2,
    const float* __restrict__ aW3, const float* __restrict__ ab3,
    float* __restrict__ out, int ib){
  __shared__ float w2s[5000], b2s[50], w3s[500], b3s[10], w4s[10];
  __shared__ float wa1s[36], ba1s[12], wa2s[288], ba2s[24], wa3s[96], ba3s[4];
  __shared__ float b4s;
  __shared__ float x1s[4][100], h2[4][50], h3[4][10], stg[4], hb1[4][12], hb2[4][24];
  const int tid = threadIdx.x;
  for (int j=tid;j<5000;j+=256) w2s[j]=fW2[j];
  for (int j=tid;j<500;j+=256)  w3s[j]=fW3[j];
  for (int j=tid;j<288;j+=256)  wa2s[j]=aW2[j];
  if (tid<50) b2s[tid]=fb2[tid];
  if (tid<10) b3s[tid]=fb3[tid];
  if (tid<10) w4s[tid]=fW4[tid];
  if (tid==0) b4s=fb4[0];
  if (tid<36) wa1s[tid]=aW1[tid];
  if (tid<12) ba1s[tid]=ab1[tid];
  if (tid<24) ba2s[tid]=ab2[tid];
  if (tid<96) wa3s[tid]=aW3[tid];
  if (tid<4)  ba3s[tid]=ab3[tid];
  for (int idx=tid; idx<400; idx+=256){
    int gg = idx/100, k = idx-gg*100;
    x1s[gg][k] = x1[(size_t)(blockIdx.x*4+gg)*100 + k];
  }
  __syncthreads();
  const int g = tid >> 6, lane = tid & 63;
  const int img_l = blockIdx.x*4 + g;
  if (lane < 50){
    float s = b2s[lane];
    #pragma unroll 4
    for (int k=0;k<100;++k) s = fmaf(x1s[g][k], w2s[k*50+lane], s);
    h2[g][lane] = s > 0.f ? s : 0.f;
  }
  __syncthreads();
  if (lane < 10){
    float s = b3s[lane];
    #pragma unroll
    for (int k=0;k<50;++k) s = fmaf(h2[g][k], w3s[k*10+lane], s);
    h3[g][lane] = s > 0.f ? s : 0.f;
  }
  __syncthreads();
  if (lane == 0){
    float s = b4s;
    #pragma unroll
    for (int k=0;k<10;++k) s = fmaf(h3[g][k], w4s[k], s);
    stg[g] = s;
  }
  __syncthreads();
  if (lane < 12){
    float s0 = stg[g], dd = dist[ib+img_l], sp = speed[ib+img_l];
    float s = ba1s[lane] + s0*wa1s[lane] + dd*wa1s[12+lane] + sp*wa1s[24+lane];
    hb1[g][lane] = s > 0.f ? s : 0.f;
  }
  __syncthreads();
  if (lane < 24){
    float s = ba2s[lane];
    #pragma unroll
    for (int k=0;k<12;++k) s = fmaf(hb1[g][k], wa2s[k*24+lane], s);
    hb2[g][lane] = s > 0.f ? s : 0.f;
  }
  __syncthreads();
  if (lane < 4){
    float s = ba3s[lane];
    #pragma unroll
    for (int k=0;k<24;++k) s = fmaf(hb2[g][k], wa3s[k*4+lane], s);
    out[(size_t)(ib+img_l)*4 + lane] = s;
  }
}

// ================================================================ host
extern "C" void kernel_launch(void* const* d_in, const int* in_sizes, int n_in,
                              void* d_out, int out_size, void* d_ws, size_t ws_size,
                              hipStream_t stream){
  const float* rgb   = (const float*)d_in[0];
  const float* dist  = (const float*)d_in[1];
  const float* speed = (const float*)d_in[2];
  const float* cw1 = (const float*)d_in[3];
  const float* cb1 = (const float*)d_in[4];
  const float* cw2 = (const float*)d_in[5];
  const float* cb2 = (const float*)d_in[6];
  const float* cw3 = (const float*)d_in[7];
  const float* cb3 = (const float*)d_in[8];
  const float* cw4 = (const float*)d_in[9];
  const float* cb4 = (const float*)d_in[10];
  const float* fW1 = (const float*)d_in[11];
  const float* fb1 = (const float*)d_in[12];
  const float* fW2 = (const float*)d_in[13];
  const float* fb2 = (const float*)d_in[14];
  const float* fW3 = (const float*)d_in[15];
  const float* fb3 = (const float*)d_in[16];
  const float* fW4 = (const float*)d_in[17];
  const float* fb4 = (const float*)d_in[18];
  const float* aW1 = (const float*)d_in[19];
  const float* ab1 = (const float*)d_in[20];
  const float* aW2 = (const float*)d_in[21];
  const float* ab2 = (const float*)d_in[22];
  const float* aW3 = (const float*)d_in[23];
  const float* ab3 = (const float*)d_in[24];
  float* out = (float*)d_out;
  const int B = in_sizes[0] / 15000;

  auto ALN = [](size_t x){ return (x + 255) & ~(size_t)255; };
  const size_t fixed = ALN(76800) + ALN(96000) + ALN(55296);

  int nc = 1;
  while (nc < 32){
    size_t Bc = (size_t)(B / nc);
    size_t need = fixed + ALN(Bc*169344) + ALN(Bc*54144) + ALN(Bc*12672)
                        + ALN(Bc*10240)  + ALN(Bc*400)   + ALN(Bc*4000);
    if (need <= ws_size) break;
    nc *= 2;
  }
  const int Bc = B / nc;

  char* ws = (char*)d_ws;
  size_t o = 0;
  auto alloc = [&](size_t bytes)->char*{ char* p = ws + o; o += ALN(bytes); return p; };
  f16* w2m = (f16*)alloc(76800);
  f16* w3r = (f16*)alloc(96000);
  f16* w4r = (f16*)alloc(55296);
  f16* a1  = (f16*)alloc((size_t)Bc*169344);
  f16* a2  = (f16*)alloc((size_t)Bc*54144);
  f16* a3  = (f16*)alloc((size_t)Bc*12672);
  f16* a4  = (f16*)alloc((size_t)Bc*10240);
  float* x1  = (float*)alloc((size_t)Bc*400);
  float* x1p = (float*)alloc((size_t)Bc*4000);

  repack2m_k<<<dim3(150), dim3(256), 0, stream>>>(w2m, cw2);
  repack3_k<<<dim3(188), dim3(256), 0, stream>>>(w3r, cw3);
  repack4_k<<<dim3(108), dim3(256), 0, stream>>>(w4r, cw4);

  for (int c = 0; c < nc; ++c){
    const int ib = c*Bc;
    conv1_k<<<dim3(Bc*7), dim3(128), 0, stream>>>(rgb, cw1, cb1, a1, ib);
    conv2_k<<<dim3(Bc*3), dim3(256), 0, stream>>>(a1, w2m, cb2, a2);
    conv3_k<<<dim3(Bc*3), dim3(384), 0, stream>>>(a2, w3r, cb3, a3);
    conv4_k<<<dim3(Bc),   dim3(256), 0, stream>>>(a3, w4r, cb4, a4);
    fc1p_k<<<dim3(Bc/32, 10), dim3(256), 0, stream>>>(a4, fW1, x1p, Bc);
    fc1r_k<<<dim3((Bc*100+255)/256), dim3(256), 0, stream>>>(x1p, fb1, x1, Bc);
    tail_k<<<dim3(Bc/4), dim3(256), 0, stream>>>(x1, dist, speed,
        fW2, fb2, fW3, fb3, fW4, fb4, aW1, ab1, aW2, ab2, aW3, ab3, out, ib);
  }
}

// Round 6
// 366.032 us; speedup vs baseline: 6.9061x; 1.7653x over previous
//
#include <hip/hip_runtime.h>

typedef _Float16 f16;
typedef _Float16 f16x4 __attribute__((ext_vector_type(4)));
typedef _Float16 f16x8 __attribute__((ext_vector_type(8)));
typedef float f32x4 __attribute__((ext_vector_type(4)));

// ---------------------------------------------------------------- weight repacks (MFMA A-fragments)
// w2m: [s25][mt3][lane64][8] ; co = mt*16+(l&15), k = (l>>4)*8+i (ci, >=24 -> 0)
__global__ __launch_bounds__(256) void repack2m_k(f16* __restrict__ dst, const float* __restrict__ src){
  for (int idx = blockIdx.x*256 + threadIdx.x; idx < 38400; idx += gridDim.x*256){
    int i = idx & 7, l = (idx >> 3) & 63, rest = idx >> 9;
    int mt = rest % 3, s = rest / 3;
    int co = mt*16 + (l & 15);
    int kloc = (l >> 4)*8 + i;
    dst[idx] = (co < 36 && kloc < 24) ? (f16)src[(co*24 + kloc)*25 + s] : (f16)0.0f;
  }
}
// w3m: [s29][mt3][lane64][8] ; main s<25: k=ci 0..31 ; extra s=25+e: ke=e*32+(l>>4)*8+i ->
//   ke<100: p=ke>>2 (tap), ci=32+(ke&3) ; else 0.   cw3 (48,36,5,5)
__global__ __launch_bounds__(256) void repack3m_k(f16* __restrict__ dst, const float* __restrict__ src){
  for (int idx = blockIdx.x*256 + threadIdx.x; idx < 44544; idx += gridDim.x*256){
    int i = idx & 7, l = (idx >> 3) & 63, rest = idx >> 9;
    int mt = rest % 3, s = rest / 3;
    int co = mt*16 + (l & 15);
    f16 v = (f16)0.0f;
    if (s < 25){
      int ci = (l >> 4)*8 + i;              // 0..31 < 36 always real
      v = (f16)src[(co*36 + ci)*25 + s];
    } else {
      int ke = (s - 25)*32 + (l >> 4)*8 + i;
      if (ke < 100){
        int p = ke >> 2, ci = 32 + (ke & 3);
        v = (f16)src[(co*36 + ci)*25 + p];
      }
    }
    dst[idx] = v;
  }
}
// w4m: [s14][mt4][lane64][8] ; k = s*32+(l>>4)*8+i ; k<432: pos=k/48, ci=k%48 ; else 0. cw4 (64,48,3,3)
__global__ __launch_bounds__(256) void repack4m_k(f16* __restrict__ dst, const float* __restrict__ src){
  for (int idx = blockIdx.x*256 + threadIdx.x; idx < 28672; idx += gridDim.x*256){
    int i = idx & 7, l = (idx >> 3) & 63, rest = idx >> 9;
    int mt = rest & 3, s = rest >> 2;
    int co = mt*16 + (l & 15);
    int k = s*32 + (l >> 4)*8 + i;
    f16 v = (f16)0.0f;
    if (k < 432){
      int pos = k / 48, ci = k - pos*48;
      v = (f16)src[(co*48 + ci)*9 + pos];
    }
    dst[idx] = v;
  }
}

// ---------------------------------------------------------------- conv1 (fused binarize)
// rgb (B,15000) f32 [w75][h200] -> a1 NHWC (Bc,98,36,24) f16. grid=Bc*7 (oh tiles of 14), block=128
__global__ __launch_bounds__(128) void conv1_k(const float* __restrict__ rgb, const float* __restrict__ w1,
                                               const float* __restrict__ b1, f16* __restrict__ a1, int ib){
  __shared__ float xi[31*76];   // [hh31][w75(+1)]
  __shared__ float wr[600];     // [p25][co24]
  __shared__ float bl[24];
  const int tid = threadIdx.x, bx = blockIdx.x;
  const int i = bx / 7, t = bx - i*7;
  const int oh0 = t*14;
  const float* img = rgb + (size_t)(ib + i)*15000;
  for (int idx = tid; idx < 2325; idx += 128){
    int a = idx / 31, hh = idx - a*31;          // a = w, hh = local h
    float v = img[a*200 + 2*oh0 + hh];
    xi[hh*76 + a] = (v > 0.f) ? 1.0f : 0.0f;
  }
  for (int idx = tid; idx < 600; idx += 128){
    int p = idx / 24, co = idx - p*24;
    wr[idx] = w1[co*25 + p];
  }
  if (tid < 24) bl[tid] = b1[tid];
  __syncthreads();
  int ohl[4], owl[4]; bool act[4];
  #pragma unroll
  for (int u=0;u<4;++u){
    int sp = u*128 + tid;
    act[u] = sp < 504;
    int s = act[u] ? sp : 0;
    ohl[u] = s / 36; owl[u] = s - ohl[u]*36;
  }
  float acc[4][24] = {};
  #pragma unroll 1
  for (int kh=0; kh<5; ++kh){
    #pragma unroll 1
    for (int kw=0; kw<5; ++kw){
      float wv[24];
      #pragma unroll
      for (int c=0;c<24;++c) wv[c] = wr[(kh*5+kw)*24 + c];
      #pragma unroll
      for (int u=0;u<4;++u){
        float x = xi[(2*ohl[u]+kh)*76 + 2*owl[u]+kw];
        #pragma unroll
        for (int c=0;c<24;++c) acc[u][c] = fmaf(x, wv[c], acc[u][c]);
      }
    }
  }
  #pragma unroll
  for (int u=0;u<4;++u){
    if (!act[u]) continue;
    union { f16 h[24]; uint4 q[3]; } pk;
    #pragma unroll
    for (int c=0;c<24;++c){
      float r = acc[u][c] + bl[c]; if (r < 0.f) r = 0.f;
      pk.h[c] = (f16)r;
    }
    size_t base = (((size_t)i*98 + oh0 + ohl[u])*36 + owl[u])*24;
    uint4* dst = (uint4*)(a1 + base);
    dst[0] = pk.q[0]; dst[1] = pk.q[1]; dst[2] = pk.q[2];
  }
}

// ---------------------------------------------------------------- conv2 (MFMA implicit GEMM)
// a1 NHWC (Bc,98,36,24) -> a2 NHWC (Bc,47,16,36). grid=Bc*3 (oh tiles of 16), block=256 (4 waves)
__global__ __launch_bounds__(256) void conv2_k(const f16* __restrict__ a1, const f16* __restrict__ w2m,
                                               const float* __restrict__ b2, f16* __restrict__ a2){
  __shared__ __align__(16) f16 xt[2*35*18*24];   // [par][rr35][colp18][ci24] = 60480 B
  const int tid = threadIdx.x, bx = blockIdx.x;
  const int i = bx / 3, t = bx - i*3;
  const int oh0 = t*16, r0 = t*32;
  {
    const uint4* s4 = (const uint4*)((const uint*)a1 + (size_t)i*42336);
    uint4* d = (uint4*)xt;
    // 35 rows x 108 uint4 per row; col = 12 dw -> 3 uint4
    for (int idx = tid; idx < 3780; idx += 256){
      int rr = idx / 108, q4 = idx - rr*108;
      int col = q4 / 3, c4 = q4 - col*3;
      int r = r0 + rr;
      uint4 v = (r < 98) ? s4[(size_t)r*108 + q4] : (uint4){0,0,0,0};
      d[((((col & 1)*35 + rr)*18 + (col >> 1))*3) + c4] = v;
    }
  }
  __syncthreads();
  const int wv = tid >> 6, lane = tid & 63;
  const int n_ow = lane & 15;
  const int jgrp = lane >> 4;
  const int ci0 = (jgrp == 3) ? 0 : jgrp*8;
  f32x4 acc[3][4];
  #pragma unroll
  for (int mt=0; mt<3; ++mt){
    f32x4 bv;
    #pragma unroll
    for (int reg=0; reg<4; ++reg){
      int co = mt*16 + jgrp*4 + reg;
      bv[reg] = (co < 36) ? b2[co] : 0.0f;
    }
    #pragma unroll
    for (int u=0; u<4; ++u) acc[mt][u] = bv;
  }
  const f16* agl = w2m + (size_t)lane*8;
  #pragma unroll 1
  for (int kh=0; kh<5; ++kh){
    #pragma unroll
    for (int kw=0; kw<5; ++kw){
      const int s = kh*5 + kw;
      f16x8 af[3];
      #pragma unroll
      for (int mt=0; mt<3; ++mt)
        af[mt] = *(const f16x8*)(agl + (size_t)(s*3 + mt)*512);
      const int par = kw & 1, kws = kw >> 1;
      const int colp = n_ow + kws;
      const f16* bb0 = xt + ((par*35 + kh)*18 + colp)*24 + ci0;
      f16x8 bf[4];
      #pragma unroll
      for (int u=0; u<4; ++u)
        bf[u] = *(const f16x8*)(bb0 + (8*wv + 2*u)*432);
      #pragma unroll
      for (int mt=0; mt<3; ++mt)
        #pragma unroll
        for (int u=0; u<4; ++u)
          acc[mt][u] = __builtin_amdgcn_mfma_f32_16x16x32_f16(af[mt], bf[u], acc[mt][u], 0, 0, 0);
    }
  }
  #pragma unroll
  for (int u=0; u<4; ++u){
    const int oh = oh0 + 4*wv + u;
    if (oh >= 47) continue;
    #pragma unroll
    for (int mt=0; mt<3; ++mt){
      const int co0s = mt*16 + jgrp*4;
      if (co0s >= 36) continue;
      union { f16 h[4]; uint2 q; } pk;
      #pragma unroll
      for (int reg=0; reg<4; ++reg){
        float r = acc[mt][u][reg]; if (r < 0.f) r = 0.f;
        pk.h[reg] = (f16)r;
      }
      *(uint2*)(a2 + (((size_t)i*47 + oh)*16 + n_ow)*36 + co0s) = pk.q;
    }
  }
}

// ---------------------------------------------------------------- conv3 (MFMA implicit GEMM)
// a2 NHWC (Bc,47,16,36) -> a3 NHWC (Bc,22,6,48). grid=Bc, block=192 (3 waves; wave q-> nt {3w..3w+2})
// LDS layout: addr_f16(r,jg,c,i) = r*680 + jg*136 + c*8 + i  (jg=ci/8, 5 groups; strides decorrelate banks)
// K: 25 main steps (ci 0..31) + 4 extra steps packing ci32..35 of all 25 taps (A has zeros for pads).
__global__ __launch_bounds__(192) void conv3_k(const f16* __restrict__ a2, const f16* __restrict__ w3m,
                                               const float* __restrict__ b3, f16* __restrict__ a3){
  __shared__ __align__(16) f16 xt[47*680];   // 63920 B
  const int tid = threadIdx.x, i = blockIdx.x;
  {
    const uint2* s2 = (const uint2*)((const uint*)a2 + (size_t)i*13536);
    uint2* d = (uint2*)xt;   // dst dw pairs: offsets even
    for (int idx = tid; idx < 6768; idx += 192){
      int d2 = idx % 9, rc = idx / 9;        // d2: dw-pair 0..8 (dwi = 2*d2)
      int c = rc & 15, r = rc >> 4;
      int dwi = d2*2, jg = dwi >> 2, part = dwi & 3;
      d[(r*340 + jg*68 + c*4 + part) >> 1] = s2[idx];   // FIX: jg stride 68 dw (=136 f16)
    }
  }
  __syncthreads();
  const int wv = tid / 64, lane = tid & 63;
  const int npx = lane & 15, jg = lane >> 4;
  int baseq[3]; int ohl[3], owl[3];
  #pragma unroll
  for (int q=0;q<3;++q){
    int px = (wv*3+q)*16 + npx; if (px > 131) px = 131;
    ohl[q] = px/6; owl[q] = px - ohl[q]*6;
    baseq[q] = 2*ohl[q]*680 + jg*136 + 2*owl[q]*8;
  }
  f32x4 acc[3][3];  // [mt][q]
  #pragma unroll
  for (int mt=0;mt<3;++mt){
    f32x4 bv;
    #pragma unroll
    for (int reg=0;reg<4;++reg) bv[reg] = b3[mt*16 + jg*4 + reg];
    acc[mt][0]=bv; acc[mt][1]=bv; acc[mt][2]=bv;
  }
  const f16* agl = w3m + (size_t)lane*8;
  #pragma unroll 1
  for (int kh=0; kh<5; ++kh){
    #pragma unroll
    for (int kw=0; kw<5; ++kw){
      const int s = kh*5 + kw;
      f16x8 af[3];
      #pragma unroll
      for (int mt=0;mt<3;++mt)
        af[mt] = *(const f16x8*)(agl + (size_t)(s*3 + mt)*512);
      f16x8 bf[3];
      #pragma unroll
      for (int q=0;q<3;++q)
        bf[q] = *(const f16x8*)(xt + baseq[q] + kh*680 + kw*8);
      #pragma unroll
      for (int mt=0;mt<3;++mt)
        #pragma unroll
        for (int q=0;q<3;++q)
          acc[mt][q] = __builtin_amdgcn_mfma_f32_16x16x32_f16(af[mt], bf[q], acc[mt][q], 0, 0, 0);
    }
  }
  // extra 4 K-steps: leftovers ci32..35, tap p = e*8 + jg*2 (+1); clamped taps have zero A
  #pragma unroll
  for (int e=0;e<4;++e){
    const int s = 25 + e;
    f16x8 af[3];
    #pragma unroll
    for (int mt=0;mt<3;++mt)
      af[mt] = *(const f16x8*)(agl + (size_t)(s*3 + mt)*512);
    int p1 = e*8 + jg*2; int p2 = p1 + 1;
    if (p1 > 24) p1 = 24;
    if (p2 > 24) p2 = 24;
    const int kh1 = p1/5, kw1 = p1 - kh1*5;
    const int kh2 = p2/5, kw2 = p2 - kh2*5;
    #pragma unroll
    for (int q=0;q<3;++q){
      f16x4 lo = *(const f16x4*)(xt + (2*ohl[q]+kh1)*680 + 544 + (2*owl[q]+kw1)*8);
      f16x4 hi = *(const f16x4*)(xt + (2*ohl[q]+kh2)*680 + 544 + (2*owl[q]+kw2)*8);
      f16x8 bq = __builtin_shufflevector(lo, hi, 0,1,2,3,4,5,6,7);
      #pragma unroll
      for (int mt=0;mt<3;++mt)
        acc[mt][q] = __builtin_amdgcn_mfma_f32_16x16x32_f16(af[mt], bq, acc[mt][q], 0, 0, 0);
    }
  }
  #pragma unroll
  for (int q=0;q<3;++q){
    int px = (wv*3+q)*16 + npx;
    if (px >= 132) continue;
    int oh = px/6, ow = px - oh*6;
    #pragma unroll
    for (int mt=0;mt<3;++mt){
      union { f16 h[4]; uint2 q2; } pk;
      #pragma unroll
      for (int reg=0;reg<4;++reg){
        float r = acc[mt][q][reg]; if (r < 0.f) r = 0.f;
        pk.h[reg] = (f16)r;
      }
      *(uint2*)(a3 + (((size_t)i*22 + oh)*6 + ow)*48 + mt*16 + jg*4) = pk.q2;
    }
  }
}

// ---------------------------------------------------------------- conv4 (MFMA implicit GEMM)
// a3 NHWC (Bc,22,6,48) -> a4 (Bc, sp80, co64) f16. grid=Bc, block=256 (4 waves; wave = mt)
// K: k = pos*48 + ci, 14 steps of 32 (432 -> pad 448, A zeros). LDS [r22][c6][ci56 pad].
__global__ __launch_bounds__(256) void conv4_k(const f16* __restrict__ a3, const f16* __restrict__ w4m,
                                               const float* __restrict__ b4, f16* __restrict__ a4){
  __shared__ __align__(16) f16 xt[22*6*56];   // 14784 B
  const int tid = threadIdx.x;
  const int i = blockIdx.x;
  {
    const uint4* s4 = (const uint4*)((const uint*)a3 + (size_t)i*3168);
    uint4* d = (uint4*)xt;
    for (int idx = tid; idx < 792; idx += 256){
      int d4 = idx % 6, sp = idx / 6;
      d[(sp*28 + d4*4) >> 2] = s4[idx];
    }
  }
  __syncthreads();
  const int wv = tid >> 6, lane = tid & 63;
  const int npx = lane & 15, jg = lane >> 4;
  f32x4 acc[5];
  {
    f32x4 bv;
    #pragma unroll
    for (int reg=0;reg<4;++reg) bv[reg] = b4[wv*16 + jg*4 + reg];
    #pragma unroll
    for (int nt=0;nt<5;++nt) acc[nt] = bv;
  }
  int ohn[5], own[5];
  #pragma unroll
  for (int nt=0;nt<5;++nt){
    int px = nt*16 + npx;
    ohn[nt] = px >> 2; own[nt] = px & 3;
  }
  const f16* agl = w4m + (size_t)lane*8;
  #pragma unroll 1
  for (int s=0; s<14; ++s){
    f16x8 af = *(const f16x8*)(agl + (size_t)(s*4 + wv)*512);
    int k8 = s*32 + jg*8;
    int pos, ci0;
    if (k8 >= 432){ pos = 8; ci0 = 40; }
    else { pos = k8 / 48; ci0 = k8 - pos*48; }
    const int kh = pos/3, kw = pos - kh*3;
    #pragma unroll
    for (int nt=0;nt<5;++nt){
      const int r = ohn[nt] + kh, c = own[nt] + kw;
      f16x8 bq = *(const f16x8*)(xt + (r*6 + c)*56 + ci0);
      acc[nt] = __builtin_amdgcn_mfma_f32_16x16x32_f16(af, bq, acc[nt], 0, 0, 0);
    }
  }
  #pragma unroll
  for (int nt=0;nt<5;++nt){
    int px = nt*16 + npx;
    union { f16 h[4]; uint2 q2; } pk;
    #pragma unroll
    for (int reg=0;reg<4;++reg){
      float r = acc[nt][reg]; if (r < 0.f) r = 0.f;
      pk.h[reg] = (f16)r;
    }
    *(uint2*)(a4 + ((size_t)i*80 + px)*64 + wv*16 + jg*4) = pk.q2;
  }
}

// ---------------------------------------------------------------- fc1 (K-split partials; W rows permuted for NHWC a4)
__global__ __launch_bounds__(256) void fc1p_k(const f16* __restrict__ a4, const float* __restrict__ fc1W,
                                              float* __restrict__ x1p, int Bc){
  __shared__ __align__(16) f16 xa[8192];   // [32 img][256 k]
  __shared__ __align__(16) f16 Wc[25600];  // [256 k][100 j]
  const int tid = threadIdx.x;
  const int bx = blockIdx.x;
  const int s  = blockIdx.y;
  const int img_g = tid / 25;
  const int j_g   = tid % 25;
  float acc[4][4] = {};
  for (int cc=0; cc<2; ++cc){
    const int k0 = s*512 + cc*256;
    __syncthreads();
    {
      const uint* src = (const uint*)a4;
      uint* d = (uint*)xa;
      for (int idx = tid; idx < 4096; idx += 256){
        int il = idx >> 7, w2 = idx & 127;
        d[idx] = src[((size_t)(bx*32 + il))*2560 + (k0>>1) + w2];
      }
      for (int idx = tid; idx < 25600; idx += 256){
        int kk = idx / 100, j = idx - kk*100;
        int k = k0 + kk;
        int row = (k & 63)*80 + (k >> 6);   // NHWC k -> original NCHW-flat row
        Wc[idx] = (f16)fc1W[(size_t)row*100 + j];
      }
    }
    __syncthreads();
    if (tid < 200){
      #pragma unroll 1
      for (int kk=0; kk<256; ++kk){
        float xv[4], wv[4];
        #pragma unroll
        for (int a=0;a<4;++a) xv[a] = (float)xa[(img_g*4+a)*256 + kk];
        #pragma unroll
        for (int b=0;b<4;++b) wv[b] = (float)Wc[kk*100 + j_g*4 + b];
        #pragma unroll
        for (int a=0;a<4;++a)
          #pragma unroll
          for (int b=0;b<4;++b) acc[a][b] = fmaf(xv[a], wv[b], acc[a][b]);
      }
    }
  }
  if (tid < 200){
    #pragma unroll
    for (int a=0;a<4;++a)
      #pragma unroll
      for (int b=0;b<4;++b)
        x1p[((size_t)s*Bc + bx*32 + img_g*4 + a)*100 + j_g*4 + b] = acc[a][b];
  }
}

__global__ __launch_bounds__(256) void fc1r_k(const float* __restrict__ x1p, const float* __restrict__ fc1b,
                                              float* __restrict__ x1, int Bc){
  int tt = blockIdx.x*256 + threadIdx.x;
  if (tt >= Bc*100) return;
  int il = tt / 100, j = tt - il*100;
  float s = fc1b[j];
  #pragma unroll
  for (int k=0;k<10;++k) s += x1p[((size_t)k*Bc + il)*100 + j];
  x1[tt] = s > 0.f ? s : 0.f;
}

// ---------------------------------------------------------------- fc2..fc4 + AEBS head
__global__ __launch_bounds__(256) void tail_k(const float* __restrict__ x1,
    const float* __restrict__ dist, const float* __restrict__ speed,
    const float* __restrict__ fW2, const float* __restrict__ fb2,
    const float* __restrict__ fW3, const float* __restrict__ fb3,
    const float* __restrict__ fW4, const float* __restrict__ fb4,
    const float* __restrict__ aW1, const float* __restrict__ ab1,
    const float* __restrict__ aW2, const float* __restrict__ ab2,
    const float* __restrict__ aW3, const float* __restrict__ ab3,
    float* __restrict__ out, int ib){
  __shared__ float w2s[5000], b2s[50], w3s[500], b3s[10], w4s[10];
  __shared__ float wa1s[36], ba1s[12], wa2s[288], ba2s[24], wa3s[96], ba3s[4];
  __shared__ float b4s;
  __shared__ float x1s[4][100], h2[4][50], h3[4][10], stg[4], hb1[4][12], hb2[4][24];
  const int tid = threadIdx.x;
  for (int j=tid;j<5000;j+=256) w2s[j]=fW2[j];
  for (int j=tid;j<500;j+=256)  w3s[j]=fW3[j];
  for (int j=tid;j<288;j+=256)  wa2s[j]=aW2[j];
  if (tid<50) b2s[tid]=fb2[tid];
  if (tid<10) b3s[tid]=fb3[tid];
  if (tid<10) w4s[tid]=fW4[tid];
  if (tid==0) b4s=fb4[0];
  if (tid<36) wa1s[tid]=aW1[tid];
  if (tid<12) ba1s[tid]=ab1[tid];
  if (tid<24) ba2s[tid]=ab2[tid];
  if (tid<96) wa3s[tid]=aW3[tid];
  if (tid<4)  ba3s[tid]=ab3[tid];
  for (int idx=tid; idx<400; idx+=256){
    int gg = idx/100, k = idx-gg*100;
    x1s[gg][k] = x1[(size_t)(blockIdx.x*4+gg)*100 + k];
  }
  __syncthreads();
  const int g = tid >> 6, lane = tid & 63;
  const int img_l = blockIdx.x*4 + g;
  if (lane < 50){
    float s = b2s[lane];
    #pragma unroll 4
    for (int k=0;k<100;++k) s = fmaf(x1s[g][k], w2s[k*50+lane], s);
    h2[g][lane] = s > 0.f ? s : 0.f;
  }
  __syncthreads();
  if (lane < 10){
    float s = b3s[lane];
    #pragma unroll
    for (int k=0;k<50;++k) s = fmaf(h2[g][k], w3s[k*10+lane], s);
    h3[g][lane] = s > 0.f ? s : 0.f;
  }
  __syncthreads();
  if (lane == 0){
    float s = b4s;
    #pragma unroll
    for (int k=0;k<10;++k) s = fmaf(h3[g][k], w4s[k], s);
    stg[g] = s;
  }
  __syncthreads();
  if (lane < 12){
    float s0 = stg[g], dd = dist[ib+img_l], sp = speed[ib+img_l];
    float s = ba1s[lane] + s0*wa1s[lane] + dd*wa1s[12+lane] + sp*wa1s[24+lane];
    hb1[g][lane] = s > 0.f ? s : 0.f;
  }
  __syncthreads();
  if (lane < 24){
    float s = ba2s[lane];
    #pragma unroll
    for (int k=0;k<12;++k) s = fmaf(hb1[g][k], wa2s[k*24+lane], s);
    hb2[g][lane] = s > 0.f ? s : 0.f;
  }
  __syncthreads();
  if (lane < 4){
    float s = ba3s[lane];
    #pragma unroll
    for (int k=0;k<24;++k) s = fmaf(hb2[g][k], wa3s[k*4+lane], s);
    out[(size_t)(ib+img_l)*4 + lane] = s;
  }
}

// ================================================================ host
extern "C" void kernel_launch(void* const* d_in, const int* in_sizes, int n_in,
                              void* d_out, int out_size, void* d_ws, size_t ws_size,
                              hipStream_t stream){
  const float* rgb   = (const float*)d_in[0];
  const float* dist  = (const float*)d_in[1];
  const float* speed = (const float*)d_in[2];
  const float* cw1 = (const float*)d_in[3];
  const float* cb1 = (const float*)d_in[4];
  const float* cw2 = (const float*)d_in[5];
  const float* cb2 = (const float*)d_in[6];
  const float* cw3 = (const float*)d_in[7];
  const float* cb3 = (const float*)d_in[8];
  const float* cw4 = (const float*)d_in[9];
  const float* cb4 = (const float*)d_in[10];
  const float* fW1 = (const float*)d_in[11];
  const float* fb1 = (const float*)d_in[12];
  const float* fW2 = (const float*)d_in[13];
  const float* fb2 = (const float*)d_in[14];
  const float* fW3 = (const float*)d_in[15];
  const float* fb3 = (const float*)d_in[16];
  const float* fW4 = (const float*)d_in[17];
  const float* fb4 = (const float*)d_in[18];
  const float* aW1 = (const float*)d_in[19];
  const float* ab1 = (const float*)d_in[20];
  const float* aW2 = (const float*)d_in[21];
  const float* ab2 = (const float*)d_in[22];
  const float* aW3 = (const float*)d_in[23];
  const float* ab3 = (const float*)d_in[24];
  float* out = (float*)d_out;
  const int B = in_sizes[0] / 15000;

  auto ALN = [](size_t x){ return (x + 255) & ~(size_t)255; };
  const size_t fixed = ALN(76800) + ALN(89088) + ALN(57344);

  int nc = 1;
  while (nc < 32){
    size_t Bc = (size_t)(B / nc);
    size_t need = fixed + ALN(Bc*169344) + ALN(Bc*54144) + ALN(Bc*12672)
                        + ALN(Bc*10240)  + ALN(Bc*400)   + ALN(Bc*4000);
    if (need <= ws_size) break;
    nc *= 2;
  }
  const int Bc = B / nc;

  char* ws = (char*)d_ws;
  size_t o = 0;
  auto alloc = [&](size_t bytes)->char*{ char* p = ws + o; o += ALN(bytes); return p; };
  f16* w2m = (f16*)alloc(76800);
  f16* w3m = (f16*)alloc(89088);
  f16* w4m = (f16*)alloc(57344);
  f16* a1  = (f16*)alloc((size_t)Bc*169344);
  f16* a2  = (f16*)alloc((size_t)Bc*54144);
  f16* a3  = (f16*)alloc((size_t)Bc*12672);
  f16* a4  = (f16*)alloc((size_t)Bc*10240);
  float* x1  = (float*)alloc((size_t)Bc*400);
  float* x1p = (float*)alloc((size_t)Bc*4000);

  repack2m_k<<<dim3(150), dim3(256), 0, stream>>>(w2m, cw2);
  repack3m_k<<<dim3(174), dim3(256), 0, stream>>>(w3m, cw3);
  repack4m_k<<<dim3(112), dim3(256), 0, stream>>>(w4m, cw4);

  for (int c = 0; c < nc; ++c){
    const int ib = c*Bc;
    conv1_k<<<dim3(Bc*7), dim3(128), 0, stream>>>(rgb, cw1, cb1, a1, ib);
    conv2_k<<<dim3(Bc*3), dim3(256), 0, stream>>>(a1, w2m, cb2, a2);
    conv3_k<<<dim3(Bc),   dim3(192), 0, stream>>>(a2, w3m, cb3, a3);
    conv4_k<<<dim3(Bc),   dim3(256), 0, stream>>>(a3, w4m, cb4, a4);
    fc1p_k<<<dim3(Bc/32, 10), dim3(256), 0, stream>>>(a4, fW1, x1p, Bc);
    fc1r_k<<<dim3((Bc*100+255)/256), dim3(256), 0, stream>>>(x1p, fb1, x1, Bc);
    tail_k<<<dim3(Bc/4), dim3(256), 0, stream>>>(x1, dist, speed,
        fW2, fb2, fW3, fb3, fW4, fb4, aW1, ab1, aW2, ab2, aW3, ab3, out, ib);
  }
}

// Round 7
// 342.736 us; speedup vs baseline: 7.3755x; 1.0680x over previous
//
#include <hip/hip_runtime.h>

typedef _Float16 f16;
typedef _Float16 f16x4 __attribute__((ext_vector_type(4)));
typedef _Float16 f16x8 __attribute__((ext_vector_type(8)));
typedef float f32x4 __attribute__((ext_vector_type(4)));

// ---------------------------------------------------------------- weight repacks (MFMA fragments)
// w2m: [s25][mt3][lane64][8] ; co = mt*16+(l&15), k = (l>>4)*8+i (ci, >=24 -> 0)
__global__ __launch_bounds__(256) void repack2m_k(f16* __restrict__ dst, const float* __restrict__ src){
  for (int idx = blockIdx.x*256 + threadIdx.x; idx < 38400; idx += gridDim.x*256){
    int i = idx & 7, l = (idx >> 3) & 63, rest = idx >> 9;
    int mt = rest % 3, s = rest / 3;
    int co = mt*16 + (l & 15);
    int kloc = (l >> 4)*8 + i;
    dst[idx] = (co < 36 && kloc < 24) ? (f16)src[(co*24 + kloc)*25 + s] : (f16)0.0f;
  }
}
// w3m: [s29][mt3][lane64][8] ; main s<25: k=ci 0..31 ; extra s=25+e: ke=e*32+(l>>4)*8+i ->
//   ke<100: p=ke>>2 (tap), ci=32+(ke&3) ; else 0.   cw3 (48,36,5,5)
__global__ __launch_bounds__(256) void repack3m_k(f16* __restrict__ dst, const float* __restrict__ src){
  for (int idx = blockIdx.x*256 + threadIdx.x; idx < 44544; idx += gridDim.x*256){
    int i = idx & 7, l = (idx >> 3) & 63, rest = idx >> 9;
    int mt = rest % 3, s = rest / 3;
    int co = mt*16 + (l & 15);
    f16 v = (f16)0.0f;
    if (s < 25){
      int ci = (l >> 4)*8 + i;
      v = (f16)src[(co*36 + ci)*25 + s];
    } else {
      int ke = (s - 25)*32 + (l >> 4)*8 + i;
      if (ke < 100){
        int p = ke >> 2, ci = 32 + (ke & 3);
        v = (f16)src[(co*36 + ci)*25 + p];
      }
    }
    dst[idx] = v;
  }
}
// w4m: [s14][mt4][lane64][8] ; k = s*32+(l>>4)*8+i ; k<432: pos=k/48, ci=k%48 ; else 0. cw4 (64,48,3,3)
__global__ __launch_bounds__(256) void repack4m_k(f16* __restrict__ dst, const float* __restrict__ src){
  for (int idx = blockIdx.x*256 + threadIdx.x; idx < 28672; idx += gridDim.x*256){
    int i = idx & 7, l = (idx >> 3) & 63, rest = idx >> 9;
    int mt = rest & 3, s = rest >> 2;
    int co = mt*16 + (l & 15);
    int k = s*32 + (l >> 4)*8 + i;
    f16 v = (f16)0.0f;
    if (k < 432){
      int pos = k / 48, ci = k - pos*48;
      v = (f16)src[(co*48 + ci)*9 + pos];
    }
    dst[idx] = v;
  }
}
// w1m (fc1): B-fragments [s160][nt7][lane64][8] ; j = nt*16+(l&15) (>=100 -> 0),
// k = s*32+(l>>4)*8+i (NHWC: k = sp*64+co) -> fc1W row = (k&63)*80 + (k>>6)
__global__ __launch_bounds__(256) void repackfc1_k(f16* __restrict__ dst, const float* __restrict__ src){
  for (int t = blockIdx.x*256 + threadIdx.x; t < 71680; t += gridDim.x*256){
    int l = t & 63, rest = t >> 6;
    int nt = rest % 7, s = rest / 7;
    int j = nt*16 + (l & 15);
    int kb = s*32 + (l >> 4)*8;
    union { f16 h[8]; f16x8 v; } pk;
    #pragma unroll
    for (int i=0;i<8;++i){
      int k = kb + i;
      int row = (k & 63)*80 + (k >> 6);
      pk.h[i] = (j < 100) ? (f16)src[(size_t)row*100 + j] : (f16)0.0f;
    }
    *(f16x8*)(dst + (size_t)t*8) = pk.v;
  }
}

// ---------------------------------------------------------------- conv1+conv2 fused
// rgb (B,15000) f32 [w75][h200] -> a2 NHWC (Bc,47,16,36). grid=Bc*6 (oh tiles of 8), block=256.
// Phase 0: stage+binarize rgb patch (41 h x 75 w). Phase 1: conv1 (VALU) -> xt parity tile.
// Phase 2: conv2 MFMA (validated fragment mapping), wave wv handles oh_l {2wv, 2wv+1}.
__global__ __launch_bounds__(256) void conv12_k(const float* __restrict__ rgb, const float* __restrict__ w1,
                                                const float* __restrict__ b1, const f16* __restrict__ w2m,
                                                const float* __restrict__ b2, f16* __restrict__ a2, int ib){
  __shared__ float xb[41][76];
  __shared__ float w1s[600];
  __shared__ float b1s[24];
  __shared__ __align__(16) f16 xt[2*19*18*24];   // [par][rr19][colp18][ci24] = 32832 B
  const int tid = threadIdx.x, bx = blockIdx.x;
  const int i = bx / 6, t = bx - i*6;
  const int r0 = t*16, h0 = t*32, oh0 = t*8;
  const float* img = rgb + (size_t)(ib + i)*15000;
  for (int idx = tid; idx < 3075; idx += 256){
    int w = idx / 41, hh = idx - w*41;
    int h = h0 + hh;
    float v = (h < 200) ? img[w*200 + h] : 0.0f;
    xb[hh][w] = (v > 0.f) ? 1.0f : 0.0f;
  }
  for (int idx = tid; idx < 600; idx += 256){
    int p = idx / 24, co = idx - p*24;
    w1s[idx] = w1[co*25 + p];
  }
  if (tid < 24) b1s[tid] = b1[tid];
  __syncthreads();
  // phase 1: conv1 into xt (19 rows x 36 cols x 24 ci)
  for (int task = tid; task < 684; task += 256){
    int rr = task / 36, ow = task - rr*36;
    const bool valid = (r0 + rr) < 98;
    float acc[24];
    #pragma unroll
    for (int c=0;c<24;++c) acc[c] = b1s[c];
    #pragma unroll 1
    for (int kh=0; kh<5; ++kh){
      #pragma unroll
      for (int kw=0; kw<5; ++kw){
        float x = xb[2*rr+kh][2*ow+kw];
        const float* wp = &w1s[(kh*5+kw)*24];
        #pragma unroll
        for (int c=0;c<24;++c) acc[c] = fmaf(x, wp[c], acc[c]);
      }
    }
    union { f16 h[24]; uint4 q[3]; } pk;
    #pragma unroll
    for (int c=0;c<24;++c){
      float r = (valid && acc[c] > 0.f) ? acc[c] : 0.f;
      pk.h[c] = (f16)r;
    }
    uint4* dst = (uint4*)(xt + (((ow & 1)*19 + rr)*18 + (ow >> 1))*24);
    dst[0]=pk.q[0]; dst[1]=pk.q[1]; dst[2]=pk.q[2];
  }
  __syncthreads();
  // phase 2: MFMA
  const int wv = tid >> 6, lane = tid & 63;
  const int n_ow = lane & 15;
  const int jgrp = lane >> 4;
  const int ci0 = (jgrp == 3) ? 0 : jgrp*8;
  f32x4 acc2[3][2];
  #pragma unroll
  for (int mt=0; mt<3; ++mt){
    f32x4 bv;
    #pragma unroll
    for (int reg=0; reg<4; ++reg){
      int co = mt*16 + jgrp*4 + reg;
      bv[reg] = (co < 36) ? b2[co] : 0.0f;
    }
    acc2[mt][0] = bv; acc2[mt][1] = bv;
  }
  const f16* agl = w2m + (size_t)lane*8;
  #pragma unroll 1
  for (int kh=0; kh<5; ++kh){
    #pragma unroll
    for (int kw=0; kw<5; ++kw){
      const int s = kh*5 + kw;
      f16x8 af[3];
      #pragma unroll
      for (int mt=0; mt<3; ++mt)
        af[mt] = *(const f16x8*)(agl + (size_t)(s*3 + mt)*512);
      const int par = kw & 1, kws = kw >> 1;
      const int colp = n_ow + kws;
      const f16* bb0 = xt + ((par*19 + kh)*18 + colp)*24 + ci0;   // + rr_local*432
      f16x8 bf[2];
      #pragma unroll
      for (int u=0; u<2; ++u)
        bf[u] = *(const f16x8*)(bb0 + (4*wv + 2*u)*432);
      #pragma unroll
      for (int mt=0; mt<3; ++mt)
        #pragma unroll
        for (int u=0; u<2; ++u)
          acc2[mt][u] = __builtin_amdgcn_mfma_f32_16x16x32_f16(af[mt], bf[u], acc2[mt][u], 0, 0, 0);
    }
  }
  #pragma unroll
  for (int u=0; u<2; ++u){
    const int oh = oh0 + 2*wv + u;
    if (oh >= 47) continue;
    #pragma unroll
    for (int mt=0; mt<3; ++mt){
      const int co0s = mt*16 + jgrp*4;
      if (co0s >= 36) continue;
      union { f16 h[4]; uint2 q; } pk;
      #pragma unroll
      for (int reg=0; reg<4; ++reg){
        float r = acc2[mt][u][reg]; if (r < 0.f) r = 0.f;
        pk.h[reg] = (f16)r;
      }
      *(uint2*)(a2 + (((size_t)i*47 + oh)*16 + n_ow)*36 + co0s) = pk.q;
    }
  }
}

// ---------------------------------------------------------------- conv3 (MFMA implicit GEMM)
// a2 NHWC (Bc,47,16,36) -> a3 NHWC (Bc,22,6,48). grid=Bc, block=192
__global__ __launch_bounds__(192) void conv3_k(const f16* __restrict__ a2, const f16* __restrict__ w3m,
                                               const float* __restrict__ b3, f16* __restrict__ a3){
  __shared__ __align__(16) f16 xt[47*680];   // 63920 B
  const int tid = threadIdx.x, i = blockIdx.x;
  {
    const uint2* s2 = (const uint2*)((const uint*)a2 + (size_t)i*13536);
    uint2* d = (uint2*)xt;
    for (int idx = tid; idx < 6768; idx += 192){
      int d2 = idx % 9, rc = idx / 9;
      int c = rc & 15, r = rc >> 4;
      int dwi = d2*2, jg = dwi >> 2, part = dwi & 3;
      d[(r*340 + jg*68 + c*4 + part) >> 1] = s2[idx];
    }
  }
  __syncthreads();
  const int wv = tid / 64, lane = tid & 63;
  const int npx = lane & 15, jg = lane >> 4;
  int baseq[3]; int ohl[3], owl[3];
  #pragma unroll
  for (int q=0;q<3;++q){
    int px = (wv*3+q)*16 + npx; if (px > 131) px = 131;
    ohl[q] = px/6; owl[q] = px - ohl[q]*6;
    baseq[q] = 2*ohl[q]*680 + jg*136 + 2*owl[q]*8;
  }
  f32x4 acc[3][3];
  #pragma unroll
  for (int mt=0;mt<3;++mt){
    f32x4 bv;
    #pragma unroll
    for (int reg=0;reg<4;++reg) bv[reg] = b3[mt*16 + jg*4 + reg];
    acc[mt][0]=bv; acc[mt][1]=bv; acc[mt][2]=bv;
  }
  const f16* agl = w3m + (size_t)lane*8;
  #pragma unroll 1
  for (int kh=0; kh<5; ++kh){
    #pragma unroll
    for (int kw=0; kw<5; ++kw){
      const int s = kh*5 + kw;
      f16x8 af[3];
      #pragma unroll
      for (int mt=0;mt<3;++mt)
        af[mt] = *(const f16x8*)(agl + (size_t)(s*3 + mt)*512);
      f16x8 bf[3];
      #pragma unroll
      for (int q=0;q<3;++q)
        bf[q] = *(const f16x8*)(xt + baseq[q] + kh*680 + kw*8);
      #pragma unroll
      for (int mt=0;mt<3;++mt)
        #pragma unroll
        for (int q=0;q<3;++q)
          acc[mt][q] = __builtin_amdgcn_mfma_f32_16x16x32_f16(af[mt], bf[q], acc[mt][q], 0, 0, 0);
    }
  }
  #pragma unroll
  for (int e=0;e<4;++e){
    const int s = 25 + e;
    f16x8 af[3];
    #pragma unroll
    for (int mt=0;mt<3;++mt)
      af[mt] = *(const f16x8*)(agl + (size_t)(s*3 + mt)*512);
    int p1 = e*8 + jg*2; int p2 = p1 + 1;
    if (p1 > 24) p1 = 24;
    if (p2 > 24) p2 = 24;
    const int kh1 = p1/5, kw1 = p1 - kh1*5;
    const int kh2 = p2/5, kw2 = p2 - kh2*5;
    #pragma unroll
    for (int q=0;q<3;++q){
      f16x4 lo = *(const f16x4*)(xt + (2*ohl[q]+kh1)*680 + 544 + (2*owl[q]+kw1)*8);
      f16x4 hi = *(const f16x4*)(xt + (2*ohl[q]+kh2)*680 + 544 + (2*owl[q]+kw2)*8);
      f16x8 bq = __builtin_shufflevector(lo, hi, 0,1,2,3,4,5,6,7);
      #pragma unroll
      for (int mt=0;mt<3;++mt)
        acc[mt][q] = __builtin_amdgcn_mfma_f32_16x16x32_f16(af[mt], bq, acc[mt][q], 0, 0, 0);
    }
  }
  #pragma unroll
  for (int q=0;q<3;++q){
    int px = (wv*3+q)*16 + npx;
    if (px >= 132) continue;
    int oh = px/6, ow = px - oh*6;
    #pragma unroll
    for (int mt=0;mt<3;++mt){
      union { f16 h[4]; uint2 q2; } pk;
      #pragma unroll
      for (int reg=0;reg<4;++reg){
        float r = acc[mt][q][reg]; if (r < 0.f) r = 0.f;
        pk.h[reg] = (f16)r;
      }
      *(uint2*)(a3 + (((size_t)i*22 + oh)*6 + ow)*48 + mt*16 + jg*4) = pk.q2;
    }
  }
}

// ---------------------------------------------------------------- conv4 (MFMA implicit GEMM)
// a3 NHWC (Bc,22,6,48) -> a4 (Bc, sp80, co64) f16. grid=Bc, block=256
__global__ __launch_bounds__(256) void conv4_k(const f16* __restrict__ a3, const f16* __restrict__ w4m,
                                               const float* __restrict__ b4, f16* __restrict__ a4){
  __shared__ __align__(16) f16 xt[22*6*56];   // 14784 B
  const int tid = threadIdx.x;
  const int i = blockIdx.x;
  {
    const uint4* s4 = (const uint4*)((const uint*)a3 + (size_t)i*3168);
    uint4* d = (uint4*)xt;
    for (int idx = tid; idx < 792; idx += 256){
      int d4 = idx % 6, sp = idx / 6;
      d[(sp*28 + d4*4) >> 2] = s4[idx];
    }
  }
  __syncthreads();
  const int wv = tid >> 6, lane = tid & 63;
  const int npx = lane & 15, jg = lane >> 4;
  f32x4 acc[5];
  {
    f32x4 bv;
    #pragma unroll
    for (int reg=0;reg<4;++reg) bv[reg] = b4[wv*16 + jg*4 + reg];
    #pragma unroll
    for (int nt=0;nt<5;++nt) acc[nt] = bv;
  }
  int ohn[5], own[5];
  #pragma unroll
  for (int nt=0;nt<5;++nt){
    int px = nt*16 + npx;
    ohn[nt] = px >> 2; own[nt] = px & 3;
  }
  const f16* agl = w4m + (size_t)lane*8;
  #pragma unroll 1
  for (int s=0; s<14; ++s){
    f16x8 af = *(const f16x8*)(agl + (size_t)(s*4 + wv)*512);
    int k8 = s*32 + jg*8;
    int pos, ci0;
    if (k8 >= 432){ pos = 8; ci0 = 40; }
    else { pos = k8 / 48; ci0 = k8 - pos*48; }
    const int kh = pos/3, kw = pos - kh*3;
    #pragma unroll
    for (int nt=0;nt<5;++nt){
      const int r = ohn[nt] + kh, c = own[nt] + kw;
      f16x8 bq = *(const f16x8*)(xt + (r*6 + c)*56 + ci0);
      acc[nt] = __builtin_amdgcn_mfma_f32_16x16x32_f16(af, bq, acc[nt], 0, 0, 0);
    }
  }
  #pragma unroll
  for (int nt=0;nt<5;++nt){
    int px = nt*16 + npx;
    union { f16 h[4]; uint2 q2; } pk;
    #pragma unroll
    for (int reg=0;reg<4;++reg){
      float r = acc[nt][reg]; if (r < 0.f) r = 0.f;
      pk.h[reg] = (f16)r;
    }
    *(uint2*)(a4 + ((size_t)i*80 + px)*64 + wv*16 + jg*4) = pk.q2;
  }
}

// ---------------------------------------------------------------- fc1 (single MFMA kernel)
// a4 (Bc,5120) f16 @ fc1W -> x1 (Bc,100) f32 with bias+ReLU. grid=Bc/16, block=256.
// M=16 imgs (A), N=112 (7 j-tiles, B=w1m frags), K=5120; 4 waves split K (40 steps each), LDS reduce.
__global__ __launch_bounds__(256) void fc1m_k(const f16* __restrict__ a4, const f16* __restrict__ w1m,
                                              const float* __restrict__ fc1b, float* __restrict__ x1){
  __shared__ float red[4][64][28];   // 28672 B
  const int tid = threadIdx.x;
  const int wv = tid >> 6, lane = tid & 63;
  const int img0 = blockIdx.x*16;
  f32x4 acc[7];
  #pragma unroll
  for (int nt=0;nt<7;++nt) acc[nt] = (f32x4){0.f,0.f,0.f,0.f};
  const f16* ap = a4 + (size_t)(img0 + (lane & 15))*5120 + (lane >> 4)*8;
  const f16* bp = w1m + (size_t)lane*8;
  #pragma unroll 1
  for (int s = wv*40; s < wv*40 + 40; ++s){
    f16x8 av = *(const f16x8*)(ap + s*32);
    #pragma unroll
    for (int nt=0;nt<7;++nt){
      f16x8 bv = *(const f16x8*)(bp + (size_t)(s*7 + nt)*512);
      acc[nt] = __builtin_amdgcn_mfma_f32_16x16x32_f16(av, bv, acc[nt], 0, 0, 0);
    }
  }
  #pragma unroll
  for (int nt=0;nt<7;++nt)
    #pragma unroll
    for (int reg=0;reg<4;++reg)
      red[wv][lane][nt*4+reg] = acc[nt][reg];
  __syncthreads();
  for (int idx = tid; idx < 1792; idx += 256){
    int imgl = idx / 112, j = idx - imgl*112;
    if (j >= 100) continue;
    int l = ((imgl >> 2) << 4) | (j & 15);
    int c = (j >> 4)*4 + (imgl & 3);
    float s = red[0][l][c] + red[1][l][c] + red[2][l][c] + red[3][l][c] + fc1b[j];
    x1[(size_t)(img0 + imgl)*100 + j] = s > 0.f ? s : 0.f;
  }
}

// ---------------------------------------------------------------- fc2..fc4 + AEBS head
__global__ __launch_bounds__(256) void tail_k(const float* __restrict__ x1,
    const float* __restrict__ dist, const float* __restrict__ speed,
    const float* __restrict__ fW2, const float* __restrict__ fb2,
    const float* __restrict__ fW3, const float* __restrict__ fb3,
    const float* __restrict__ fW4, const float* __restrict__ fb4,
    const float* __restrict__ aW1, const float* __restrict__ ab1,
    const float* __restrict__ aW2, const float* __restrict__ ab2,
    const float* __restrict__ aW3, const float* __restrict__ ab3,
    float* __restrict__ out, int ib){
  __shared__ float w2s[5000], b2s[50], w3s[500], b3s[10], w4s[10];
  __shared__ float wa1s[36], ba1s[12], wa2s[288], ba2s[24], wa3s[96], ba3s[4];
  __shared__ float b4s;
  __shared__ float x1s[4][100], h2[4][50], h3[4][10], stg[4], hb1[4][12], hb2[4][24];
  const int tid = threadIdx.x;
  for (int j=tid;j<5000;j+=256) w2s[j]=fW2[j];
  for (int j=tid;j<500;j+=256)  w3s[j]=fW3[j];
  for (int j=tid;j<288;j+=256)  wa2s[j]=aW2[j];
  if (tid<50) b2s[tid]=fb2[tid];
  if (tid<10) b3s[tid]=fb3[tid];
  if (tid<10) w4s[tid]=fW4[tid];
  if (tid==0) b4s=fb4[0];
  if (tid<36) wa1s[tid]=aW1[tid];
  if (tid<12) ba1s[tid]=ab1[tid];
  if (tid<24) ba2s[tid]=ab2[tid];
  if (tid<96) wa3s[tid]=aW3[tid];
  if (tid<4)  ba3s[tid]=ab3[tid];
  for (int idx=tid; idx<400; idx+=256){
    int gg = idx/100, k = idx-gg*100;
    x1s[gg][k] = x1[(size_t)(blockIdx.x*4+gg)*100 + k];
  }
  __syncthreads();
  const int g = tid >> 6, lane = tid & 63;
  const int img_l = blockIdx.x*4 + g;
  if (lane < 50){
    float s = b2s[lane];
    #pragma unroll 4
    for (int k=0;k<100;++k) s = fmaf(x1s[g][k], w2s[k*50+lane], s);
    h2[g][lane] = s > 0.f ? s : 0.f;
  }
  __syncthreads();
  if (lane < 10){
    float s = b3s[lane];
    #pragma unroll
    for (int k=0;k<50;++k) s = fmaf(h2[g][k], w3s[k*10+lane], s);
    h3[g][lane] = s > 0.f ? s : 0.f;
  }
  __syncthreads();
  if (lane == 0){
    float s = b4s;
    #pragma unroll
    for (int k=0;k<10;++k) s = fmaf(h3[g][k], w4s[k], s);
    stg[g] = s;
  }
  __syncthreads();
  if (lane < 12){
    float s0 = stg[g], dd = dist[ib+img_l], sp = speed[ib+img_l];
    float s = ba1s[lane] + s0*wa1s[lane] + dd*wa1s[12+lane] + sp*wa1s[24+lane];
    hb1[g][lane] = s > 0.f ? s : 0.f;
  }
  __syncthreads();
  if (lane < 24){
    float s = ba2s[lane];
    #pragma unroll
    for (int k=0;k<12;++k) s = fmaf(hb1[g][k], wa2s[k*24+lane], s);
    hb2[g][lane] = s > 0.f ? s : 0.f;
  }
  __syncthreads();
  if (lane < 4){
    float s = ba3s[lane];
    #pragma unroll
    for (int k=0;k<24;++k) s = fmaf(hb2[g][k], wa3s[k*4+lane], s);
    out[(size_t)(ib+img_l)*4 + lane] = s;
  }
}

// ================================================================ host
extern "C" void kernel_launch(void* const* d_in, const int* in_sizes, int n_in,
                              void* d_out, int out_size, void* d_ws, size_t ws_size,
                              hipStream_t stream){
  const float* rgb   = (const float*)d_in[0];
  const float* dist  = (const float*)d_in[1];
  const float* speed = (const float*)d_in[2];
  const float* cw1 = (const float*)d_in[3];
  const float* cb1 = (const float*)d_in[4];
  const float* cw2 = (const float*)d_in[5];
  const float* cb2 = (const float*)d_in[6];
  const float* cw3 = (const float*)d_in[7];
  const float* cb3 = (const float*)d_in[8];
  const float* cw4 = (const float*)d_in[9];
  const float* cb4 = (const float*)d_in[10];
  const float* fW1 = (const float*)d_in[11];
  const float* fb1 = (const float*)d_in[12];
  const float* fW2 = (const float*)d_in[13];
  const float* fb2 = (const float*)d_in[14];
  const float* fW3 = (const float*)d_in[15];
  const float* fb3 = (const float*)d_in[16];
  const float* fW4 = (const float*)d_in[17];
  const float* fb4 = (const float*)d_in[18];
  const float* aW1 = (const float*)d_in[19];
  const float* ab1 = (const float*)d_in[20];
  const float* aW2 = (const float*)d_in[21];
  const float* ab2 = (const float*)d_in[22];
  const float* aW3 = (const float*)d_in[23];
  const float* ab3 = (const float*)d_in[24];
  float* out = (float*)d_out;
  const int B = in_sizes[0] / 15000;

  auto ALN = [](size_t x){ return (x + 255) & ~(size_t)255; };
  const size_t fixed = ALN(76800) + ALN(89088) + ALN(57344) + ALN(1146880);

  int nc = 1;
  while (nc < 32){
    size_t Bc = (size_t)(B / nc);
    size_t need = fixed + ALN(Bc*54144) + ALN(Bc*12672) + ALN(Bc*10240) + ALN(Bc*400);
    if (need <= ws_size) break;
    nc *= 2;
  }
  const int Bc = B / nc;

  char* ws = (char*)d_ws;
  size_t o = 0;
  auto alloc = [&](size_t bytes)->char*{ char* p = ws + o; o += ALN(bytes); return p; };
  f16* w2m = (f16*)alloc(76800);
  f16* w3m = (f16*)alloc(89088);
  f16* w4m = (f16*)alloc(57344);
  f16* w1m = (f16*)alloc(1146880);
  f16* a2  = (f16*)alloc((size_t)Bc*54144);
  f16* a3  = (f16*)alloc((size_t)Bc*12672);
  f16* a4  = (f16*)alloc((size_t)Bc*10240);
  float* x1  = (float*)alloc((size_t)Bc*400);

  repack2m_k<<<dim3(150), dim3(256), 0, stream>>>(w2m, cw2);
  repack3m_k<<<dim3(174), dim3(256), 0, stream>>>(w3m, cw3);
  repack4m_k<<<dim3(112), dim3(256), 0, stream>>>(w4m, cw4);
  repackfc1_k<<<dim3(280), dim3(256), 0, stream>>>(w1m, fW1);

  for (int c = 0; c < nc; ++c){
    const int ib = c*Bc;
    conv12_k<<<dim3(Bc*6), dim3(256), 0, stream>>>(rgb, cw1, cb1, w2m, cb2, a2, ib);
    conv3_k<<<dim3(Bc),   dim3(192), 0, stream>>>(a2, w3m, cb3, a3);
    conv4_k<<<dim3(Bc),   dim3(256), 0, stream>>>(a3, w4m, cb4, a4);
    fc1m_k<<<dim3(Bc/16), dim3(256), 0, stream>>>(a4, w1m, fb1, x1);
    tail_k<<<dim3(Bc/4),  dim3(256), 0, stream>>>(x1, dist, speed,
        fW2, fb2, fW3, fb3, fW4, fb4, aW1, ab1, aW2, ab2, aW3, ab3, out, ib);
  }
}

// Round 8
// 229.931 us; speedup vs baseline: 10.9939x; 1.4906x over previous
//
#include <hip/hip_runtime.h>

typedef _Float16 f16;
typedef _Float16 f16x4 __attribute__((ext_vector_type(4)));
typedef _Float16 f16x8 __attribute__((ext_vector_type(8)));
typedef float f32x4 __attribute__((ext_vector_type(4)));

// ---------------------------------------------------------------- weight repacks (MFMA fragments)
// w1m: [mt2][lane64][8] ; co = mt*16+(l&15) (<24), k = (l>>4)*8+i = tap (<25). cw1 (24,1,5,5)
__global__ __launch_bounds__(256) void repack1m_k(f16* __restrict__ dst, const float* __restrict__ src){
  int idx = blockIdx.x*256 + threadIdx.x;
  if (idx >= 1024) return;
  int i = idx & 7, l = (idx >> 3) & 63, mt = idx >> 9;
  int co = mt*16 + (l & 15);
  int k = (l >> 4)*8 + i;
  dst[idx] = (co < 24 && k < 25) ? (f16)src[co*25 + k] : (f16)0.0f;
}
// w2m: [s25][mt3][lane64][8] ; co = mt*16+(l&15), k = (l>>4)*8+i (ci, >=24 -> 0)
__global__ __launch_bounds__(256) void repack2m_k(f16* __restrict__ dst, const float* __restrict__ src){
  for (int idx = blockIdx.x*256 + threadIdx.x; idx < 38400; idx += gridDim.x*256){
    int i = idx & 7, l = (idx >> 3) & 63, rest = idx >> 9;
    int mt = rest % 3, s = rest / 3;
    int co = mt*16 + (l & 15);
    int kloc = (l >> 4)*8 + i;
    dst[idx] = (co < 36 && kloc < 24) ? (f16)src[(co*24 + kloc)*25 + s] : (f16)0.0f;
  }
}
// w3m: [s29][mt3][lane64][8]
__global__ __launch_bounds__(256) void repack3m_k(f16* __restrict__ dst, const float* __restrict__ src){
  for (int idx = blockIdx.x*256 + threadIdx.x; idx < 44544; idx += gridDim.x*256){
    int i = idx & 7, l = (idx >> 3) & 63, rest = idx >> 9;
    int mt = rest % 3, s = rest / 3;
    int co = mt*16 + (l & 15);
    f16 v = (f16)0.0f;
    if (s < 25){
      int ci = (l >> 4)*8 + i;
      v = (f16)src[(co*36 + ci)*25 + s];
    } else {
      int ke = (s - 25)*32 + (l >> 4)*8 + i;
      if (ke < 100){
        int p = ke >> 2, ci = 32 + (ke & 3);
        v = (f16)src[(co*36 + ci)*25 + p];
      }
    }
    dst[idx] = v;
  }
}
// w4m: [s14][mt4][lane64][8]
__global__ __launch_bounds__(256) void repack4m_k(f16* __restrict__ dst, const float* __restrict__ src){
  for (int idx = blockIdx.x*256 + threadIdx.x; idx < 28672; idx += gridDim.x*256){
    int i = idx & 7, l = (idx >> 3) & 63, rest = idx >> 9;
    int mt = rest & 3, s = rest >> 2;
    int co = mt*16 + (l & 15);
    int k = s*32 + (l >> 4)*8 + i;
    f16 v = (f16)0.0f;
    if (k < 432){
      int pos = k / 48, ci = k - pos*48;
      v = (f16)src[(co*48 + ci)*9 + pos];
    }
    dst[idx] = v;
  }
}
// w1m (fc1): B-fragments [s160][nt7][lane64][8]
__global__ __launch_bounds__(256) void repackfc1_k(f16* __restrict__ dst, const float* __restrict__ src){
  for (int t = blockIdx.x*256 + threadIdx.x; t < 71680; t += gridDim.x*256){
    int l = t & 63, rest = t >> 6;
    int nt = rest % 7, s = rest / 7;
    int j = nt*16 + (l & 15);
    int kb = s*32 + (l >> 4)*8;
    union { f16 h[8]; f16x8 v; } pk;
    #pragma unroll
    for (int i=0;i<8;++i){
      int k = kb + i;
      int row = (k & 63)*80 + (k >> 6);
      pk.h[i] = (j < 100) ? (f16)src[(size_t)row*100 + j] : (f16)0.0f;
    }
    *(f16x8*)(dst + (size_t)t*8) = pk.v;
  }
}

// ---------------------------------------------------------------- conv1+conv2 fused (both MFMA)
// rgb (B,15000) f32 [w75][h200] -> a2 NHWC (Bc,47,16,36). grid=Bc*6 (oh tiles of 8), block=256.
// Phase 0: stage+binarize rgb slab (41h x 75w) -> xb f16.
// Phase 1: conv1 MFMA: B-frag gathered from xb (per-lane tap offsets), A = w1m (regs), C -> xt parity tile.
// Phase 2: conv2 MFMA (validated), wave wv handles oh_l {2wv, 2wv+1}.
__global__ __launch_bounds__(256) void conv12_k(const float* __restrict__ rgb, const f16* __restrict__ w1m,
                                                const float* __restrict__ b1, const f16* __restrict__ w2m,
                                                const float* __restrict__ b2, f16* __restrict__ a2, int ib){
  __shared__ __align__(16) f16 xb[41*76];          // 6232 B
  __shared__ __align__(16) f16 xt[2*19*18*24];     // [par][row19][colp18][ci24] = 32832 B
  const int tid = threadIdx.x, bx = blockIdx.x;
  const int i = bx / 6, t = bx - i*6;
  const int h0 = t*32, oh0 = t*8;
  const float* img = rgb + (size_t)(ib + i)*15000;
  for (int idx = tid; idx < 3075; idx += 256){
    int w = idx / 41, hh = idx - w*41;
    int h = h0 + hh;
    float v = (h < 200) ? img[w*200 + h] : 0.0f;
    xb[hh*76 + w] = (v > 0.f) ? (f16)1.0f : (f16)0.0f;
  }
  __syncthreads();
  const int wv = tid >> 6, lane = tid & 63;
  const int jgrp = lane >> 4, npx = lane & 15;
  // ---- phase 1: conv1 MFMA into xt
  {
    f16x8 a1f0 = *(const f16x8*)(w1m + (size_t)lane*8);
    f16x8 a1f1 = *(const f16x8*)(w1m + (size_t)(64 + lane)*8);
    int koff[8];
    #pragma unroll
    for (int ii=0; ii<8; ++ii){
      int k = jgrp*8 + ii;
      if (k >= 25) k = 0;
      int kh = k/5, kw = k - kh*5;
      koff[ii] = kh*76 + kw;
    }
    f32x4 bv0, bv1;
    #pragma unroll
    for (int reg=0; reg<4; ++reg){
      int c0 = jgrp*4 + reg;        // mt0: 0..15
      int c1 = 16 + jgrp*4 + reg;   // mt1: 16..31
      bv0[reg] = b1[c0];
      bv1[reg] = (c1 < 24) ? b1[c1] : 0.f;
    }
    for (int q=0; q<11; ++q){
      int nt = wv + 4*q;
      if (nt > 42) break;
      int pxt = nt*16 + npx;
      int px = (pxt > 683) ? 683 : pxt;
      int rr = px/36, ow = px - rr*36;
      int pb = rr*152 + ow*2;
      union { f16 h[8]; f16x8 v; } bq;
      #pragma unroll
      for (int ii=0; ii<8; ++ii) bq.h[ii] = xb[pb + koff[ii]];
      f32x4 c0 = __builtin_amdgcn_mfma_f32_16x16x32_f16(a1f0, bq.v, bv0, 0, 0, 0);
      f32x4 c1 = __builtin_amdgcn_mfma_f32_16x16x32_f16(a1f1, bq.v, bv1, 0, 0, 0);
      if (pxt <= 683){
        f16* dst = xt + (((ow & 1)*19 + rr)*18 + (ow >> 1))*24;
        union { f16 h[4]; uint2 q2; } pk;
        #pragma unroll
        for (int reg=0; reg<4; ++reg){ float r = c0[reg]; if (r<0.f) r=0.f; pk.h[reg]=(f16)r; }
        *(uint2*)(dst + jgrp*4) = pk.q2;
        if (jgrp < 2){
          #pragma unroll
          for (int reg=0; reg<4; ++reg){ float r = c1[reg]; if (r<0.f) r=0.f; pk.h[reg]=(f16)r; }
          *(uint2*)(dst + 16 + jgrp*4) = pk.q2;
        }
      }
    }
  }
  __syncthreads();
  // ---- phase 2: conv2 MFMA
  const int n_ow = npx;
  const int ci0 = (jgrp == 3) ? 0 : jgrp*8;
  f32x4 acc2[3][2];
  #pragma unroll
  for (int mt=0; mt<3; ++mt){
    f32x4 bv;
    #pragma unroll
    for (int reg=0; reg<4; ++reg){
      int co = mt*16 + jgrp*4 + reg;
      bv[reg] = (co < 36) ? b2[co] : 0.0f;
    }
    acc2[mt][0] = bv; acc2[mt][1] = bv;
  }
  const f16* agl = w2m + (size_t)lane*8;
  #pragma unroll 1
  for (int kh=0; kh<5; ++kh){
    #pragma unroll
    for (int kw=0; kw<5; ++kw){
      const int s = kh*5 + kw;
      f16x8 af[3];
      #pragma unroll
      for (int mt=0; mt<3; ++mt)
        af[mt] = *(const f16x8*)(agl + (size_t)(s*3 + mt)*512);
      const int par = kw & 1, kws = kw >> 1;
      const int colp = n_ow + kws;
      const f16* bb0 = xt + ((par*19 + kh)*18 + colp)*24 + ci0;
      f16x8 bf[2];
      #pragma unroll
      for (int u=0; u<2; ++u)
        bf[u] = *(const f16x8*)(bb0 + (4*wv + 2*u)*432);
      #pragma unroll
      for (int mt=0; mt<3; ++mt)
        #pragma unroll
        for (int u=0; u<2; ++u)
          acc2[mt][u] = __builtin_amdgcn_mfma_f32_16x16x32_f16(af[mt], bf[u], acc2[mt][u], 0, 0, 0);
    }
  }
  #pragma unroll
  for (int u=0; u<2; ++u){
    const int oh = oh0 + 2*wv + u;
    if (oh >= 47) continue;
    #pragma unroll
    for (int mt=0; mt<3; ++mt){
      const int co0s = mt*16 + jgrp*4;
      if (co0s >= 36) continue;
      union { f16 h[4]; uint2 q; } pk;
      #pragma unroll
      for (int reg=0; reg<4; ++reg){
        float r = acc2[mt][u][reg]; if (r < 0.f) r = 0.f;
        pk.h[reg] = (f16)r;
      }
      *(uint2*)(a2 + (((size_t)i*47 + oh)*16 + n_ow)*36 + co0s) = pk.q;
    }
  }
}

// ---------------------------------------------------------------- conv3 (MFMA implicit GEMM)
__global__ __launch_bounds__(192) void conv3_k(const f16* __restrict__ a2, const f16* __restrict__ w3m,
                                               const float* __restrict__ b3, f16* __restrict__ a3){
  __shared__ __align__(16) f16 xt[47*680];   // 63920 B
  const int tid = threadIdx.x, i = blockIdx.x;
  {
    const uint2* s2 = (const uint2*)((const uint*)a2 + (size_t)i*13536);
    uint2* d = (uint2*)xt;
    for (int idx = tid; idx < 6768; idx += 192){
      int d2 = idx % 9, rc = idx / 9;
      int c = rc & 15, r = rc >> 4;
      int dwi = d2*2, jg = dwi >> 2, part = dwi & 3;
      d[(r*340 + jg*68 + c*4 + part) >> 1] = s2[idx];
    }
  }
  __syncthreads();
  const int wv = tid / 64, lane = tid & 63;
  const int npx = lane & 15, jg = lane >> 4;
  int baseq[3]; int ohl[3], owl[3];
  #pragma unroll
  for (int q=0;q<3;++q){
    int px = (wv*3+q)*16 + npx; if (px > 131) px = 131;
    ohl[q] = px/6; owl[q] = px - ohl[q]*6;
    baseq[q] = 2*ohl[q]*680 + jg*136 + 2*owl[q]*8;
  }
  f32x4 acc[3][3];
  #pragma unroll
  for (int mt=0;mt<3;++mt){
    f32x4 bv;
    #pragma unroll
    for (int reg=0;reg<4;++reg) bv[reg] = b3[mt*16 + jg*4 + reg];
    acc[mt][0]=bv; acc[mt][1]=bv; acc[mt][2]=bv;
  }
  const f16* agl = w3m + (size_t)lane*8;
  #pragma unroll 1
  for (int kh=0; kh<5; ++kh){
    #pragma unroll
    for (int kw=0; kw<5; ++kw){
      const int s = kh*5 + kw;
      f16x8 af[3];
      #pragma unroll
      for (int mt=0;mt<3;++mt)
        af[mt] = *(const f16x8*)(agl + (size_t)(s*3 + mt)*512);
      f16x8 bf[3];
      #pragma unroll
      for (int q=0;q<3;++q)
        bf[q] = *(const f16x8*)(xt + baseq[q] + kh*680 + kw*8);
      #pragma unroll
      for (int mt=0;mt<3;++mt)
        #pragma unroll
        for (int q=0;q<3;++q)
          acc[mt][q] = __builtin_amdgcn_mfma_f32_16x16x32_f16(af[mt], bf[q], acc[mt][q], 0, 0, 0);
    }
  }
  #pragma unroll
  for (int e=0;e<4;++e){
    const int s = 25 + e;
    f16x8 af[3];
    #pragma unroll
    for (int mt=0;mt<3;++mt)
      af[mt] = *(const f16x8*)(agl + (size_t)(s*3 + mt)*512);
    int p1 = e*8 + jg*2; int p2 = p1 + 1;
    if (p1 > 24) p1 = 24;
    if (p2 > 24) p2 = 24;
    const int kh1 = p1/5, kw1 = p1 - kh1*5;
    const int kh2 = p2/5, kw2 = p2 - kh2*5;
    #pragma unroll
    for (int q=0;q<3;++q){
      f16x4 lo = *(const f16x4*)(xt + (2*ohl[q]+kh1)*680 + 544 + (2*owl[q]+kw1)*8);
      f16x4 hi = *(const f16x4*)(xt + (2*ohl[q]+kh2)*680 + 544 + (2*owl[q]+kw2)*8);
      f16x8 bq = __builtin_shufflevector(lo, hi, 0,1,2,3,4,5,6,7);
      #pragma unroll
      for (int mt=0;mt<3;++mt)
        acc[mt][q] = __builtin_amdgcn_mfma_f32_16x16x32_f16(af[mt], bq, acc[mt][q], 0, 0, 0);
    }
  }
  #pragma unroll
  for (int q=0;q<3;++q){
    int px = (wv*3+q)*16 + npx;
    if (px >= 132) continue;
    int oh = px/6, ow = px - oh*6;
    #pragma unroll
    for (int mt=0;mt<3;++mt){
      union { f16 h[4]; uint2 q2; } pk;
      #pragma unroll
      for (int reg=0;reg<4;++reg){
        float r = acc[mt][q][reg]; if (r < 0.f) r = 0.f;
        pk.h[reg] = (f16)r;
      }
      *(uint2*)(a3 + (((size_t)i*22 + oh)*6 + ow)*48 + mt*16 + jg*4) = pk.q2;
    }
  }
}

// ---------------------------------------------------------------- conv4 (MFMA implicit GEMM)
__global__ __launch_bounds__(256) void conv4_k(const f16* __restrict__ a3, const f16* __restrict__ w4m,
                                               const float* __restrict__ b4, f16* __restrict__ a4){
  __shared__ __align__(16) f16 xt[22*6*56];   // 14784 B
  const int tid = threadIdx.x;
  const int i = blockIdx.x;
  {
    const uint4* s4 = (const uint4*)((const uint*)a3 + (size_t)i*3168);
    uint4* d = (uint4*)xt;
    for (int idx = tid; idx < 792; idx += 256){
      int d4 = idx % 6, sp = idx / 6;
      d[(sp*28 + d4*4) >> 2] = s4[idx];
    }
  }
  __syncthreads();
  const int wv = tid >> 6, lane = tid & 63;
  const int npx = lane & 15, jg = lane >> 4;
  f32x4 acc[5];
  {
    f32x4 bv;
    #pragma unroll
    for (int reg=0;reg<4;++reg) bv[reg] = b4[wv*16 + jg*4 + reg];
    #pragma unroll
    for (int nt=0;nt<5;++nt) acc[nt] = bv;
  }
  int ohn[5], own[5];
  #pragma unroll
  for (int nt=0;nt<5;++nt){
    int px = nt*16 + npx;
    ohn[nt] = px >> 2; own[nt] = px & 3;
  }
  const f16* agl = w4m + (size_t)lane*8;
  #pragma unroll 1
  for (int s=0; s<14; ++s){
    f16x8 af = *(const f16x8*)(agl + (size_t)(s*4 + wv)*512);
    int k8 = s*32 + jg*8;
    int pos, ci0;
    if (k8 >= 432){ pos = 8; ci0 = 40; }
    else { pos = k8 / 48; ci0 = k8 - pos*48; }
    const int kh = pos/3, kw = pos - kh*3;
    #pragma unroll
    for (int nt=0;nt<5;++nt){
      const int r = ohn[nt] + kh, c = own[nt] + kw;
      f16x8 bq = *(const f16x8*)(xt + (r*6 + c)*56 + ci0);
      acc[nt] = __builtin_amdgcn_mfma_f32_16x16x32_f16(af, bq, acc[nt], 0, 0, 0);
    }
  }
  #pragma unroll
  for (int nt=0;nt<5;++nt){
    int px = nt*16 + npx;
    union { f16 h[4]; uint2 q2; } pk;
    #pragma unroll
    for (int reg=0;reg<4;++reg){
      float r = acc[nt][reg]; if (r < 0.f) r = 0.f;
      pk.h[reg] = (f16)r;
    }
    *(uint2*)(a4 + ((size_t)i*80 + px)*64 + wv*16 + jg*4) = pk.q2;
  }
}

// ---------------------------------------------------------------- fc1 (single MFMA kernel)
__global__ __launch_bounds__(256) void fc1m_k(const f16* __restrict__ a4, const f16* __restrict__ w1m,
                                              const float* __restrict__ fc1b, float* __restrict__ x1){
  __shared__ float red[4][64][28];   // 28672 B
  const int tid = threadIdx.x;
  const int wv = tid >> 6, lane = tid & 63;
  const int img0 = blockIdx.x*16;
  f32x4 acc[7];
  #pragma unroll
  for (int nt=0;nt<7;++nt) acc[nt] = (f32x4){0.f,0.f,0.f,0.f};
  const f16* ap = a4 + (size_t)(img0 + (lane & 15))*5120 + (lane >> 4)*8;
  const f16* bp = w1m + (size_t)lane*8;
  #pragma unroll 1
  for (int s = wv*40; s < wv*40 + 40; ++s){
    f16x8 av = *(const f16x8*)(ap + s*32);
    #pragma unroll
    for (int nt=0;nt<7;++nt){
      f16x8 bv = *(const f16x8*)(bp + (size_t)(s*7 + nt)*512);
      acc[nt] = __builtin_amdgcn_mfma_f32_16x16x32_f16(av, bv, acc[nt], 0, 0, 0);
    }
  }
  #pragma unroll
  for (int nt=0;nt<7;++nt)
    #pragma unroll
    for (int reg=0;reg<4;++reg)
      red[wv][lane][nt*4+reg] = acc[nt][reg];
  __syncthreads();
  for (int idx = tid; idx < 1792; idx += 256){
    int imgl = idx / 112, j = idx - imgl*112;
    if (j >= 100) continue;
    int l = ((imgl >> 2) << 4) | (j & 15);
    int c = (j >> 4)*4 + (imgl & 3);
    float s = red[0][l][c] + red[1][l][c] + red[2][l][c] + red[3][l][c] + fc1b[j];
    x1[(size_t)(img0 + imgl)*100 + j] = s > 0.f ? s : 0.f;
  }
}

// ---------------------------------------------------------------- fc2..fc4 + AEBS head
__global__ __launch_bounds__(256) void tail_k(const float* __restrict__ x1,
    const float* __restrict__ dist, const float* __restrict__ speed,
    const float* __restrict__ fW2, const float* __restrict__ fb2,
    const float* __restrict__ fW3, const float* __restrict__ fb3,
    const float* __restrict__ fW4, const float* __restrict__ fb4,
    const float* __restrict__ aW1, const float* __restrict__ ab1,
    const float* __restrict__ aW2, const float* __restrict__ ab2,
    const float* __restrict__ aW3, const float* __restrict__ ab3,
    float* __restrict__ out, int ib){
  __shared__ float w2s[5000], b2s[50], w3s[500], b3s[10], w4s[10];
  __shared__ float wa1s[36], ba1s[12], wa2s[288], ba2s[24], wa3s[96], ba3s[4];
  __shared__ float b4s;
  __shared__ float x1s[4][100], h2[4][50], h3[4][10], stg[4], hb1[4][12], hb2[4][24];
  const int tid = threadIdx.x;
  for (int j=tid;j<5000;j+=256) w2s[j]=fW2[j];
  for (int j=tid;j<500;j+=256)  w3s[j]=fW3[j];
  for (int j=tid;j<288;j+=256)  wa2s[j]=aW2[j];
  if (tid<50) b2s[tid]=fb2[tid];
  if (tid<10) b3s[tid]=fb3[tid];
  if (tid<10) w4s[tid]=fW4[tid];
  if (tid==0) b4s=fb4[0];
  if (tid<36) wa1s[tid]=aW1[tid];
  if (tid<12) ba1s[tid]=ab1[tid];
  if (tid<24) ba2s[tid]=ab2[tid];
  if (tid<96) wa3s[tid]=aW3[tid];
  if (tid<4)  ba3s[tid]=ab3[tid];
  for (int idx=tid; idx<400; idx+=256){
    int gg = idx/100, k = idx-gg*100;
    x1s[gg][k] = x1[(size_t)(blockIdx.x*4+gg)*100 + k];
  }
  __syncthreads();
  const int g = tid >> 6, lane = tid & 63;
  const int img_l = blockIdx.x*4 + g;
  if (lane < 50){
    float s = b2s[lane];
    #pragma unroll 4
    for (int k=0;k<100;++k) s = fmaf(x1s[g][k], w2s[k*50+lane], s);
    h2[g][lane] = s > 0.f ? s : 0.f;
  }
  __syncthreads();
  if (lane < 10){
    float s = b3s[lane];
    #pragma unroll
    for (int k=0;k<50;++k) s = fmaf(h2[g][k], w3s[k*10+lane], s);
    h3[g][lane] = s > 0.f ? s : 0.f;
  }
  __syncthreads();
  if (lane == 0){
    float s = b4s;
    #pragma unroll
    for (int k=0;k<10;++k) s = fmaf(h3[g][k], w4s[k], s);
    stg[g] = s;
  }
  __syncthreads();
  if (lane < 12){
    float s0 = stg[g], dd = dist[ib+img_l], sp = speed[ib+img_l];
    float s = ba1s[lane] + s0*wa1s[lane] + dd*wa1s[12+lane] + sp*wa1s[24+lane];
    hb1[g][lane] = s > 0.f ? s : 0.f;
  }
  __syncthreads();
  if (lane < 24){
    float s = ba2s[lane];
    #pragma unroll
    for (int k=0;k<12;++k) s = fmaf(hb1[g][k], wa2s[k*24+lane], s);
    hb2[g][lane] = s > 0.f ? s : 0.f;
  }
  __syncthreads();
  if (lane < 4){
    float s = ba3s[lane];
    #pragma unroll
    for (int k=0;k<24;++k) s = fmaf(hb2[g][k], wa3s[k*4+lane], s);
    out[(size_t)(ib+img_l)*4 + lane] = s;
  }
}

// ================================================================ host
extern "C" void kernel_launch(void* const* d_in, const int* in_sizes, int n_in,
                              void* d_out, int out_size, void* d_ws, size_t ws_size,
                              hipStream_t stream){
  const float* rgb   = (const float*)d_in[0];
  const float* dist  = (const float*)d_in[1];
  const float* speed = (const float*)d_in[2];
  const float* cw1 = (const float*)d_in[3];
  const float* cb1 = (const float*)d_in[4];
  const float* cw2 = (const float*)d_in[5];
  const float* cb2 = (const float*)d_in[6];
  const float* cw3 = (const float*)d_in[7];
  const float* cb3 = (const float*)d_in[8];
  const float* cw4 = (const float*)d_in[9];
  const float* cb4 = (const float*)d_in[10];
  const float* fW1 = (const float*)d_in[11];
  const float* fb1 = (const float*)d_in[12];
  const float* fW2 = (const float*)d_in[13];
  const float* fb2 = (const float*)d_in[14];
  const float* fW3 = (const float*)d_in[15];
  const float* fb3 = (const float*)d_in[16];
  const float* fW4 = (const float*)d_in[17];
  const float* fb4 = (const float*)d_in[18];
  const float* aW1 = (const float*)d_in[19];
  const float* ab1 = (const float*)d_in[20];
  const float* aW2 = (const float*)d_in[21];
  const float* ab2 = (const float*)d_in[22];
  const float* aW3 = (const float*)d_in[23];
  const float* ab3 = (const float*)d_in[24];
  float* out = (float*)d_out;
  const int B = in_sizes[0] / 15000;

  auto ALN = [](size_t x){ return (x + 255) & ~(size_t)255; };
  const size_t fixed = ALN(2048) + ALN(76800) + ALN(89088) + ALN(57344) + ALN(1146880);

  int nc = 1;
  while (nc < 32){
    size_t Bc = (size_t)(B / nc);
    size_t need = fixed + ALN(Bc*54144) + ALN(Bc*12672) + ALN(Bc*10240) + ALN(Bc*400);
    if (need <= ws_size) break;
    nc *= 2;
  }
  const int Bc = B / nc;

  char* ws = (char*)d_ws;
  size_t o = 0;
  auto alloc = [&](size_t bytes)->char*{ char* p = ws + o; o += ALN(bytes); return p; };
  f16* w1c = (f16*)alloc(2048);
  f16* w2m = (f16*)alloc(76800);
  f16* w3m = (f16*)alloc(89088);
  f16* w4m = (f16*)alloc(57344);
  f16* w1m = (f16*)alloc(1146880);
  f16* a2  = (f16*)alloc((size_t)Bc*54144);
  f16* a3  = (f16*)alloc((size_t)Bc*12672);
  f16* a4  = (f16*)alloc((size_t)Bc*10240);
  float* x1  = (float*)alloc((size_t)Bc*400);

  repack1m_k<<<dim3(4),   dim3(256), 0, stream>>>(w1c, cw1);
  repack2m_k<<<dim3(150), dim3(256), 0, stream>>>(w2m, cw2);
  repack3m_k<<<dim3(174), dim3(256), 0, stream>>>(w3m, cw3);
  repack4m_k<<<dim3(112), dim3(256), 0, stream>>>(w4m, cw4);
  repackfc1_k<<<dim3(280), dim3(256), 0, stream>>>(w1m, fW1);

  for (int c = 0; c < nc; ++c){
    const int ib = c*Bc;
    conv12_k<<<dim3(Bc*6), dim3(256), 0, stream>>>(rgb, w1c, cb1, w2m, cb2, a2, ib);
    conv3_k<<<dim3(Bc),   dim3(192), 0, stream>>>(a2, w3m, cb3, a3);
    conv4_k<<<dim3(Bc),   dim3(256), 0, stream>>>(a3, w4m, cb4, a4);
    fc1m_k<<<dim3(Bc/16), dim3(256), 0, stream>>>(a4, w1m, fb1, x1);
    tail_k<<<dim3(Bc/4),  dim3(256), 0, stream>>>(x1, dist, speed,
        fW2, fb2, fW3, fb3, fW4, fb4, aW1, ab1, aW2, ab2, aW3, ab3, out, ib);
  }
}

// Round 9
// 208.432 us; speedup vs baseline: 12.1278x; 1.1031x over previous
//
#include <hip/hip_runtime.h>

typedef _Float16 f16;
typedef _Float16 f16x4 __attribute__((ext_vector_type(4)));
typedef _Float16 f16x8 __attribute__((ext_vector_type(8)));
typedef float f32x4 __attribute__((ext_vector_type(4)));

// ---------------------------------------------------------------- weight repacks (MFMA fragments)
// w1c (conv1): [mt2][lane64][8] ; co = mt*16+(l&15) (<24), k = (l>>4)*8+i = tap (<25). cw1 (24,1,5,5)
__global__ __launch_bounds__(256) void repack1m_k(f16* __restrict__ dst, const float* __restrict__ src){
  int idx = blockIdx.x*256 + threadIdx.x;
  if (idx >= 1024) return;
  int i = idx & 7, l = (idx >> 3) & 63, mt = idx >> 9;
  int co = mt*16 + (l & 15);
  int k = (l >> 4)*8 + i;
  dst[idx] = (co < 24 && k < 25) ? (f16)src[co*25 + k] : (f16)0.0f;
}
// w2c (conv2, K-packed): [s19][mt3][lane64][8] ; co = mt*16+(l&15), k = s*32+(l>>4)*8+i ;
// valid k<600: tap=k/24, ci=k%24 -> src[(co*24+ci)*25 + tap]. cw2 (36,24,5,5)
__global__ __launch_bounds__(256) void repack2c_k(f16* __restrict__ dst, const float* __restrict__ src){
  for (int idx = blockIdx.x*256 + threadIdx.x; idx < 29184; idx += gridDim.x*256){
    int i = idx & 7, l = (idx >> 3) & 63, rest = idx >> 9;
    int mt = rest % 3, s = rest / 3;
    int co = mt*16 + (l & 15);
    int k = s*32 + (l >> 4)*8 + i;
    f16 v = (f16)0.0f;
    if (co < 36 && k < 600){
      int tap = k / 24, ci = k - tap*24;
      v = (f16)src[(co*24 + ci)*25 + tap];
    }
    dst[idx] = v;
  }
}
// w3m: [s29][mt3][lane64][8]
__global__ __launch_bounds__(256) void repack3m_k(f16* __restrict__ dst, const float* __restrict__ src){
  for (int idx = blockIdx.x*256 + threadIdx.x; idx < 44544; idx += gridDim.x*256){
    int i = idx & 7, l = (idx >> 3) & 63, rest = idx >> 9;
    int mt = rest % 3, s = rest / 3;
    int co = mt*16 + (l & 15);
    f16 v = (f16)0.0f;
    if (s < 25){
      int ci = (l >> 4)*8 + i;
      v = (f16)src[(co*36 + ci)*25 + s];
    } else {
      int ke = (s - 25)*32 + (l >> 4)*8 + i;
      if (ke < 100){
        int p = ke >> 2, ci = 32 + (ke & 3);
        v = (f16)src[(co*36 + ci)*25 + p];
      }
    }
    dst[idx] = v;
  }
}
// w4m: [s14][mt4][lane64][8]
__global__ __launch_bounds__(256) void repack4m_k(f16* __restrict__ dst, const float* __restrict__ src){
  for (int idx = blockIdx.x*256 + threadIdx.x; idx < 28672; idx += gridDim.x*256){
    int i = idx & 7, l = (idx >> 3) & 63, rest = idx >> 9;
    int mt = rest & 3, s = rest >> 2;
    int co = mt*16 + (l & 15);
    int k = s*32 + (l >> 4)*8 + i;
    f16 v = (f16)0.0f;
    if (k < 432){
      int pos = k / 48, ci = k - pos*48;
      v = (f16)src[(co*48 + ci)*9 + pos];
    }
    dst[idx] = v;
  }
}
// w1m (fc1): B-fragments [s160][nt7][lane64][8]
__global__ __launch_bounds__(256) void repackfc1_k(f16* __restrict__ dst, const float* __restrict__ src){
  for (int t = blockIdx.x*256 + threadIdx.x; t < 71680; t += gridDim.x*256){
    int l = t & 63, rest = t >> 6;
    int nt = rest % 7, s = rest / 7;
    int j = nt*16 + (l & 15);
    int kb = s*32 + (l >> 4)*8;
    union { f16 h[8]; f16x8 v; } pk;
    #pragma unroll
    for (int i=0;i<8;++i){
      int k = kb + i;
      int row = (k & 63)*80 + (k >> 6);
      pk.h[i] = (j < 100) ? (f16)src[(size_t)row*100 + j] : (f16)0.0f;
    }
    *(f16x8*)(dst + (size_t)t*8) = pk.v;
  }
}

// ---------------------------------------------------------------- conv1+conv2 fused (both MFMA, K-packed conv2)
// rgb (B,15000) f32 [w75][h200] -> a2 NHWC (Bc,47,16,36). grid=Bc*6 (oh tiles of 8), block=256.
__global__ __launch_bounds__(256) void conv12_k(const float* __restrict__ rgb, const f16* __restrict__ w1m,
                                                const float* __restrict__ b1, const f16* __restrict__ w2c,
                                                const float* __restrict__ b2, f16* __restrict__ a2, int ib){
  __shared__ __align__(16) f16 xb[41*76];          // 6232 B
  __shared__ __align__(16) f16 xt[2*19*18*24];     // [par][row19][colp18][ci24] = 32832 B
  const int tid = threadIdx.x, bx = blockIdx.x;
  const int i = bx / 6, t = bx - i*6;
  const int h0 = t*32, oh0 = t*8;
  const float* img = rgb + (size_t)(ib + i)*15000;
  for (int idx = tid; idx < 3075; idx += 256){
    int w = idx / 41, hh = idx - w*41;
    int h = h0 + hh;
    float v = (h < 200) ? img[w*200 + h] : 0.0f;
    xb[hh*76 + w] = (v > 0.f) ? (f16)1.0f : (f16)0.0f;
  }
  __syncthreads();
  const int wv = tid >> 6, lane = tid & 63;
  const int jgrp = lane >> 4, npx = lane & 15;
  // ---- phase 1: conv1 MFMA into xt
  {
    f16x8 a1f0 = *(const f16x8*)(w1m + (size_t)lane*8);
    f16x8 a1f1 = *(const f16x8*)(w1m + (size_t)(64 + lane)*8);
    int koff[8];
    #pragma unroll
    for (int ii=0; ii<8; ++ii){
      int k = jgrp*8 + ii;
      if (k >= 25) k = 0;
      int kh = k/5, kw = k - kh*5;
      koff[ii] = kh*76 + kw;
    }
    f32x4 bv0, bv1;
    #pragma unroll
    for (int reg=0; reg<4; ++reg){
      int c0 = jgrp*4 + reg;
      int c1 = 16 + jgrp*4 + reg;
      bv0[reg] = b1[c0];
      bv1[reg] = (c1 < 24) ? b1[c1] : 0.f;
    }
    for (int q=0; q<11; ++q){
      int nt = wv + 4*q;
      if (nt > 42) break;
      int pxt = nt*16 + npx;
      int px = (pxt > 683) ? 683 : pxt;
      int rr = px/36, ow = px - rr*36;
      int pb = rr*152 + ow*2;
      union { f16 h[8]; f16x8 v; } bq;
      #pragma unroll
      for (int ii=0; ii<8; ++ii) bq.h[ii] = xb[pb + koff[ii]];
      f32x4 c0 = __builtin_amdgcn_mfma_f32_16x16x32_f16(a1f0, bq.v, bv0, 0, 0, 0);
      f32x4 c1 = __builtin_amdgcn_mfma_f32_16x16x32_f16(a1f1, bq.v, bv1, 0, 0, 0);
      if (pxt <= 683){
        f16* dst = xt + (((ow & 1)*19 + rr)*18 + (ow >> 1))*24;
        union { f16 h[4]; uint2 q2; } pk;
        #pragma unroll
        for (int reg=0; reg<4; ++reg){ float r = c0[reg]; if (r<0.f) r=0.f; pk.h[reg]=(f16)r; }
        *(uint2*)(dst + jgrp*4) = pk.q2;
        if (jgrp < 2){
          #pragma unroll
          for (int reg=0; reg<4; ++reg){ float r = c1[reg]; if (r<0.f) r=0.f; pk.h[reg]=(f16)r; }
          *(uint2*)(dst + 16 + jgrp*4) = pk.q2;
        }
      }
    }
  }
  __syncthreads();
  // ---- phase 2: conv2 MFMA, K-packed (19 steps of 32 over k = tap*24 + ci)
  // per-lane B base address table (per s): tap = (4s+jgrp)/3, ci0 = ((4s+jgrp)%3)*8
  int baddr[19];
  #pragma unroll
  for (int s=0; s<19; ++s){
    int m = s*4 + jgrp;
    int tap = m / 3, r3 = m - tap*3;
    if (m >= 75){ tap = 24; r3 = 0; }
    int kh = tap / 5, kw = tap - kh*5;
    int par = kw & 1, kws = kw >> 1;
    baddr[s] = ((par*19 + kh)*18 + npx + kws)*24 + r3*8;
  }
  f32x4 acc2[3][2];
  #pragma unroll
  for (int mt=0; mt<3; ++mt){
    f32x4 bv;
    #pragma unroll
    for (int reg=0; reg<4; ++reg){
      int co = mt*16 + jgrp*4 + reg;
      bv[reg] = (co < 36) ? b2[co] : 0.0f;
    }
    acc2[mt][0] = bv; acc2[mt][1] = bv;
  }
  const f16* agl = w2c + (size_t)lane*8;
  const int rowo = 4*wv*432;
  #pragma unroll
  for (int s=0; s<19; ++s){
    f16x8 af[3];
    #pragma unroll
    for (int mt=0; mt<3; ++mt)
      af[mt] = *(const f16x8*)(agl + (size_t)(s*3 + mt)*512);
    const f16* bb0 = xt + baddr[s] + rowo;
    f16x8 bf[2];
    bf[0] = *(const f16x8*)(bb0);
    bf[1] = *(const f16x8*)(bb0 + 2*432);
    #pragma unroll
    for (int mt=0; mt<3; ++mt)
      #pragma unroll
      for (int u=0; u<2; ++u)
        acc2[mt][u] = __builtin_amdgcn_mfma_f32_16x16x32_f16(af[mt], bf[u], acc2[mt][u], 0, 0, 0);
  }
  #pragma unroll
  for (int u=0; u<2; ++u){
    const int oh = oh0 + 2*wv + u;
    if (oh >= 47) continue;
    #pragma unroll
    for (int mt=0; mt<3; ++mt){
      const int co0s = mt*16 + jgrp*4;
      if (co0s >= 36) continue;
      union { f16 h[4]; uint2 q; } pk;
      #pragma unroll
      for (int reg=0; reg<4; ++reg){
        float r = acc2[mt][u][reg]; if (r < 0.f) r = 0.f;
        pk.h[reg] = (f16)r;
      }
      *(uint2*)(a2 + (((size_t)i*47 + oh)*16 + npx)*36 + co0s) = pk.q;
    }
  }
}

// ---------------------------------------------------------------- conv3 (MFMA implicit GEMM, 2 oh-tiles/img)
// a2 NHWC (Bc,47,16,36) -> a3 NHWC (Bc,22,6,48). grid=Bc*2 (oh tiles of 11), block=192 (3 waves)
__global__ __launch_bounds__(192) void conv3_k(const f16* __restrict__ a2, const f16* __restrict__ w3m,
                                               const float* __restrict__ b3, f16* __restrict__ a3){
  __shared__ __align__(16) f16 xt[25*680];   // 34000 B
  const int tid = threadIdx.x, bx = blockIdx.x;
  const int i = bx >> 1, t = bx & 1;
  const int oh0 = t*11, r0 = t*22;   // input rows r0..r0+24 (max 46 < 47: no clamp)
  {
    const uint2* s2 = (const uint2*)((const uint*)a2 + (size_t)i*13536);
    uint2* d = (uint2*)xt;
    for (int idx = tid; idx < 3600; idx += 192){
      int d2 = idx % 9, rc = idx / 9;
      int c = rc & 15, r = rc >> 4;
      int dwi = d2*2, jg = dwi >> 2, part = dwi & 3;
      d[(r*340 + jg*68 + c*4 + part) >> 1] = s2[((r0 + r)*16 + c)*9 + d2];
    }
  }
  __syncthreads();
  const int wv = tid / 64, lane = tid & 63;
  const int npx = lane & 15, jg = lane >> 4;
  int baseq[2]; int ohl[2], owl[2];
  #pragma unroll
  for (int q=0;q<2;++q){
    int px = (wv*2+q)*16 + npx; if (px > 65) px = 65;
    ohl[q] = px/6; owl[q] = px - ohl[q]*6;
    baseq[q] = 2*ohl[q]*680 + jg*136 + 2*owl[q]*8;
  }
  f32x4 acc[3][2];
  #pragma unroll
  for (int mt=0;mt<3;++mt){
    f32x4 bv;
    #pragma unroll
    for (int reg=0;reg<4;++reg) bv[reg] = b3[mt*16 + jg*4 + reg];
    acc[mt][0]=bv; acc[mt][1]=bv;
  }
  const f16* agl = w3m + (size_t)lane*8;
  #pragma unroll 1
  for (int kh=0; kh<5; ++kh){
    #pragma unroll
    for (int kw=0; kw<5; ++kw){
      const int s = kh*5 + kw;
      f16x8 af[3];
      #pragma unroll
      for (int mt=0;mt<3;++mt)
        af[mt] = *(const f16x8*)(agl + (size_t)(s*3 + mt)*512);
      f16x8 bf[2];
      #pragma unroll
      for (int q=0;q<2;++q)
        bf[q] = *(const f16x8*)(xt + baseq[q] + kh*680 + kw*8);
      #pragma unroll
      for (int mt=0;mt<3;++mt)
        #pragma unroll
        for (int q=0;q<2;++q)
          acc[mt][q] = __builtin_amdgcn_mfma_f32_16x16x32_f16(af[mt], bf[q], acc[mt][q], 0, 0, 0);
    }
  }
  #pragma unroll
  for (int e=0;e<4;++e){
    const int s = 25 + e;
    f16x8 af[3];
    #pragma unroll
    for (int mt=0;mt<3;++mt)
      af[mt] = *(const f16x8*)(agl + (size_t)(s*3 + mt)*512);
    int p1 = e*8 + jg*2; int p2 = p1 + 1;
    if (p1 > 24) p1 = 24;
    if (p2 > 24) p2 = 24;
    const int kh1 = p1/5, kw1 = p1 - kh1*5;
    const int kh2 = p2/5, kw2 = p2 - kh2*5;
    #pragma unroll
    for (int q=0;q<2;++q){
      f16x4 lo = *(const f16x4*)(xt + (2*ohl[q]+kh1)*680 + 544 + (2*owl[q]+kw1)*8);
      f16x4 hi = *(const f16x4*)(xt + (2*ohl[q]+kh2)*680 + 544 + (2*owl[q]+kw2)*8);
      f16x8 bq = __builtin_shufflevector(lo, hi, 0,1,2,3,4,5,6,7);
      #pragma unroll
      for (int mt=0;mt<3;++mt)
        acc[mt][q] = __builtin_amdgcn_mfma_f32_16x16x32_f16(af[mt], bq, acc[mt][q], 0, 0, 0);
    }
  }
  #pragma unroll
  for (int q=0;q<2;++q){
    int px = (wv*2+q)*16 + npx;
    if (px >= 66) continue;
    int oh = oh0 + px/6, ow = px % 6;
    #pragma unroll
    for (int mt=0;mt<3;++mt){
      union { f16 h[4]; uint2 q2; } pk;
      #pragma unroll
      for (int reg=0;reg<4;++reg){
        float r = acc[mt][q][reg]; if (r < 0.f) r = 0.f;
        pk.h[reg] = (f16)r;
      }
      *(uint2*)(a3 + (((size_t)i*22 + oh)*6 + ow)*48 + mt*16 + jg*4) = pk.q2;
    }
  }
}

// ---------------------------------------------------------------- conv4 (MFMA implicit GEMM)
__global__ __launch_bounds__(256) void conv4_k(const f16* __restrict__ a3, const f16* __restrict__ w4m,
                                               const float* __restrict__ b4, f16* __restrict__ a4){
  __shared__ __align__(16) f16 xt[22*6*56];   // 14784 B
  const int tid = threadIdx.x;
  const int i = blockIdx.x;
  {
    const uint4* s4 = (const uint4*)((const uint*)a3 + (size_t)i*3168);
    uint4* d = (uint4*)xt;
    for (int idx = tid; idx < 792; idx += 256){
      int d4 = idx % 6, sp = idx / 6;
      d[(sp*28 + d4*4) >> 2] = s4[idx];
    }
  }
  __syncthreads();
  const int wv = tid >> 6, lane = tid & 63;
  const int npx = lane & 15, jg = lane >> 4;
  f32x4 acc[5];
  {
    f32x4 bv;
    #pragma unroll
    for (int reg=0;reg<4;++reg) bv[reg] = b4[wv*16 + jg*4 + reg];
    #pragma unroll
    for (int nt=0;nt<5;++nt) acc[nt] = bv;
  }
  int ohn[5], own[5];
  #pragma unroll
  for (int nt=0;nt<5;++nt){
    int px = nt*16 + npx;
    ohn[nt] = px >> 2; own[nt] = px & 3;
  }
  const f16* agl = w4m + (size_t)lane*8;
  #pragma unroll 1
  for (int s=0; s<14; ++s){
    f16x8 af = *(const f16x8*)(agl + (size_t)(s*4 + wv)*512);
    int k8 = s*32 + jg*8;
    int pos, ci0;
    if (k8 >= 432){ pos = 8; ci0 = 40; }
    else { pos = k8 / 48; ci0 = k8 - pos*48; }
    const int kh = pos/3, kw = pos - kh*3;
    #pragma unroll
    for (int nt=0;nt<5;++nt){
      const int r = ohn[nt] + kh, c = own[nt] + kw;
      f16x8 bq = *(const f16x8*)(xt + (r*6 + c)*56 + ci0);
      acc[nt] = __builtin_amdgcn_mfma_f32_16x16x32_f16(af, bq, acc[nt], 0, 0, 0);
    }
  }
  #pragma unroll
  for (int nt=0;nt<5;++nt){
    int px = nt*16 + npx;
    union { f16 h[4]; uint2 q2; } pk;
    #pragma unroll
    for (int reg=0;reg<4;++reg){
      float r = acc[nt][reg]; if (r < 0.f) r = 0.f;
      pk.h[reg] = (f16)r;
    }
    *(uint2*)(a4 + ((size_t)i*80 + px)*64 + wv*16 + jg*4) = pk.q2;
  }
}

// ---------------------------------------------------------------- fc1 (single MFMA kernel)
__global__ __launch_bounds__(256) void fc1m_k(const f16* __restrict__ a4, const f16* __restrict__ w1m,
                                              const float* __restrict__ fc1b, float* __restrict__ x1){
  __shared__ float red[4][64][28];   // 28672 B
  const int tid = threadIdx.x;
  const int wv = tid >> 6, lane = tid & 63;
  const int img0 = blockIdx.x*16;
  f32x4 acc[7];
  #pragma unroll
  for (int nt=0;nt<7;++nt) acc[nt] = (f32x4){0.f,0.f,0.f,0.f};
  const f16* ap = a4 + (size_t)(img0 + (lane & 15))*5120 + (lane >> 4)*8;
  const f16* bp = w1m + (size_t)lane*8;
  #pragma unroll 1
  for (int s = wv*40; s < wv*40 + 40; ++s){
    f16x8 av = *(const f16x8*)(ap + s*32);
    #pragma unroll
    for (int nt=0;nt<7;++nt){
      f16x8 bv = *(const f16x8*)(bp + (size_t)(s*7 + nt)*512);
      acc[nt] = __builtin_amdgcn_mfma_f32_16x16x32_f16(av, bv, acc[nt], 0, 0, 0);
    }
  }
  #pragma unroll
  for (int nt=0;nt<7;++nt)
    #pragma unroll
    for (int reg=0;reg<4;++reg)
      red[wv][lane][nt*4+reg] = acc[nt][reg];
  __syncthreads();
  for (int idx = tid; idx < 1792; idx += 256){
    int imgl = idx / 112, j = idx - imgl*112;
    if (j >= 100) continue;
    int l = ((imgl >> 2) << 4) | (j & 15);
    int c = (j >> 4)*4 + (imgl & 3);
    float s = red[0][l][c] + red[1][l][c] + red[2][l][c] + red[3][l][c] + fc1b[j];
    x1[(size_t)(img0 + imgl)*100 + j] = s > 0.f ? s : 0.f;
  }
}

// ---------------------------------------------------------------- fc2..fc4 + AEBS head
__global__ __launch_bounds__(256) void tail_k(const float* __restrict__ x1,
    const float* __restrict__ dist, const float* __restrict__ speed,
    const float* __restrict__ fW2, const float* __restrict__ fb2,
    const float* __restrict__ fW3, const float* __restrict__ fb3,
    const float* __restrict__ fW4, const float* __restrict__ fb4,
    const float* __restrict__ aW1, const float* __restrict__ ab1,
    const float* __restrict__ aW2, const float* __restrict__ ab2,
    const float* __restrict__ aW3, const float* __restrict__ ab3,
    float* __restrict__ out, int ib){
  __shared__ float w2s[5000], b2s[50], w3s[500], b3s[10], w4s[10];
  __shared__ float wa1s[36], ba1s[12], wa2s[288], ba2s[24], wa3s[96], ba3s[4];
  __shared__ float b4s;
  __shared__ float x1s[4][100], h2[4][50], h3[4][10], stg[4], hb1[4][12], hb2[4][24];
  const int tid = threadIdx.x;
  for (int j=tid;j<5000;j+=256) w2s[j]=fW2[j];
  for (int j=tid;j<500;j+=256)  w3s[j]=fW3[j];
  for (int j=tid;j<288;j+=256)  wa2s[j]=aW2[j];
  if (tid<50) b2s[tid]=fb2[tid];
  if (tid<10) b3s[tid]=fb3[tid];
  if (tid<10) w4s[tid]=fW4[tid];
  if (tid==0) b4s=fb4[0];
  if (tid<36) wa1s[tid]=aW1[tid];
  if (tid<12) ba1s[tid]=ab1[tid];
  if (tid<24) ba2s[tid]=ab2[tid];
  if (tid<96) wa3s[tid]=aW3[tid];
  if (tid<4)  ba3s[tid]=ab3[tid];
  for (int idx=tid; idx<400; idx+=256){
    int gg = idx/100, k = idx-gg*100;
    x1s[gg][k] = x1[(size_t)(blockIdx.x*4+gg)*100 + k];
  }
  __syncthreads();
  const int g = tid >> 6, lane = tid & 63;
  const int img_l = blockIdx.x*4 + g;
  if (lane < 50){
    float s = b2s[lane];
    #pragma unroll 4
    for (int k=0;k<100;++k) s = fmaf(x1s[g][k], w2s[k*50+lane], s);
    h2[g][lane] = s > 0.f ? s : 0.f;
  }
  __syncthreads();
  if (lane < 10){
    float s = b3s[lane];
    #pragma unroll
    for (int k=0;k<50;++k) s = fmaf(h2[g][k], w3s[k*10+lane], s);
    h3[g][lane] = s > 0.f ? s : 0.f;
  }
  __syncthreads();
  if (lane == 0){
    float s = b4s;
    #pragma unroll
    for (int k=0;k<10;++k) s = fmaf(h3[g][k], w4s[k], s);
    stg[g] = s;
  }
  __syncthreads();
  if (lane < 12){
    float s0 = stg[g], dd = dist[ib+img_l], sp = speed[ib+img_l];
    float s = ba1s[lane] + s0*wa1s[lane] + dd*wa1s[12+lane] + sp*wa1s[24+lane];
    hb1[g][lane] = s > 0.f ? s : 0.f;
  }
  __syncthreads();
  if (lane < 24){
    float s = ba2s[lane];
    #pragma unroll
    for (int k=0;k<12;++k) s = fmaf(hb1[g][k], wa2s[k*24+lane], s);
    hb2[g][lane] = s > 0.f ? s : 0.f;
  }
  __syncthreads();
  if (lane < 4){
    float s = ba3s[lane];
    #pragma unroll
    for (int k=0;k<24;++k) s = fmaf(hb2[g][k], wa3s[k*4+lane], s);
    out[(size_t)(ib+img_l)*4 + lane] = s;
  }
}

// ================================================================ host
extern "C" void kernel_launch(void* const* d_in, const int* in_sizes, int n_in,
                              void* d_out, int out_size, void* d_ws, size_t ws_size,
                              hipStream_t stream){
  const float* rgb   = (const float*)d_in[0];
  const float* dist  = (const float*)d_in[1];
  const float* speed = (const float*)d_in[2];
  const float* cw1 = (const float*)d_in[3];
  const float* cb1 = (const float*)d_in[4];
  const float* cw2 = (const float*)d_in[5];
  const float* cb2 = (const float*)d_in[6];
  const float* cw3 = (const float*)d_in[7];
  const float* cb3 = (const float*)d_in[8];
  const float* cw4 = (const float*)d_in[9];
  const float* cb4 = (const float*)d_in[10];
  const float* fW1 = (const float*)d_in[11];
  const float* fb1 = (const float*)d_in[12];
  const float* fW2 = (const float*)d_in[13];
  const float* fb2 = (const float*)d_in[14];
  const float* fW3 = (const float*)d_in[15];
  const float* fb3 = (const float*)d_in[16];
  const float* fW4 = (const float*)d_in[17];
  const float* fb4 = (const float*)d_in[18];
  const float* aW1 = (const float*)d_in[19];
  const float* ab1 = (const float*)d_in[20];
  const float* aW2 = (const float*)d_in[21];
  const float* ab2 = (const float*)d_in[22];
  const float* aW3 = (const float*)d_in[23];
  const float* ab3 = (const float*)d_in[24];
  float* out = (float*)d_out;
  const int B = in_sizes[0] / 15000;

  auto ALN = [](size_t x){ return (x + 255) & ~(size_t)255; };
  const size_t fixed = ALN(2048) + ALN(58368) + ALN(89088) + ALN(57344) + ALN(1146880);

  int nc = 1;
  while (nc < 32){
    size_t Bc = (size_t)(B / nc);
    size_t need = fixed + ALN(Bc*54144) + ALN(Bc*12672) + ALN(Bc*10240) + ALN(Bc*400);
    if (need <= ws_size) break;
    nc *= 2;
  }
  const int Bc = B / nc;

  char* ws = (char*)d_ws;
  size_t o = 0;
  auto alloc = [&](size_t bytes)->char*{ char* p = ws + o; o += ALN(bytes); return p; };
  f16* w1c = (f16*)alloc(2048);
  f16* w2c = (f16*)alloc(58368);
  f16* w3m = (f16*)alloc(89088);
  f16* w4m = (f16*)alloc(57344);
  f16* w1m = (f16*)alloc(1146880);
  f16* a2  = (f16*)alloc((size_t)Bc*54144);
  f16* a3  = (f16*)alloc((size_t)Bc*12672);
  f16* a4  = (f16*)alloc((size_t)Bc*10240);
  float* x1  = (float*)alloc((size_t)Bc*400);

  repack1m_k<<<dim3(4),   dim3(256), 0, stream>>>(w1c, cw1);
  repack2c_k<<<dim3(114), dim3(256), 0, stream>>>(w2c, cw2);
  repack3m_k<<<dim3(174), dim3(256), 0, stream>>>(w3m, cw3);
  repack4m_k<<<dim3(112), dim3(256), 0, stream>>>(w4m, cw4);
  repackfc1_k<<<dim3(280), dim3(256), 0, stream>>>(w1m, fW1);

  for (int c = 0; c < nc; ++c){
    const int ib = c*Bc;
    conv12_k<<<dim3(Bc*6), dim3(256), 0, stream>>>(rgb, w1c, cb1, w2c, cb2, a2, ib);
    conv3_k<<<dim3(Bc*2), dim3(192), 0, stream>>>(a2, w3m, cb3, a3);
    conv4_k<<<dim3(Bc),   dim3(256), 0, stream>>>(a3, w4m, cb4, a4);
    fc1m_k<<<dim3(Bc/16), dim3(256), 0, stream>>>(a4, w1m, fb1, x1);
    tail_k<<<dim3(Bc/4),  dim3(256), 0, stream>>>(x1, dist, speed,
        fW2, fb2, fW3, fb3, fW4, fb4, aW1, ab1, aW2, ab2, aW3, ab3, out, ib);
  }
}

// Round 10
// 195.201 us; speedup vs baseline: 12.9499x; 1.0678x over previous
//
#include <hip/hip_runtime.h>

typedef _Float16 f16;
typedef _Float16 f16x4 __attribute__((ext_vector_type(4)));
typedef _Float16 f16x8 __attribute__((ext_vector_type(8)));
typedef float f32x4 __attribute__((ext_vector_type(4)));

// ---------------------------------------------------------------- weight repacks (MFMA fragments)
// w1c (conv1): [mt2][lane64][8] ; co = mt*16+(l&15) (<24), K COLUMN-major taps: k -> (kw=k/5, kh=k%5)
__global__ __launch_bounds__(256) void repack1m_k(f16* __restrict__ dst, const float* __restrict__ src){
  int idx = blockIdx.x*256 + threadIdx.x;
  if (idx >= 1024) return;
  int i = idx & 7, l = (idx >> 3) & 63, mt = idx >> 9;
  int co = mt*16 + (l & 15);
  int k = (l >> 4)*8 + i;
  f16 v = (f16)0.0f;
  if (co < 24 && k < 25){
    int kw = k / 5, kh = k - kw*5;
    v = (f16)src[co*25 + kh*5 + kw];
  }
  dst[idx] = v;
}
// w2c (conv2, K-packed): [s19][mt3][lane64][8] ; k<600: tap=k/24, ci=k%24
__global__ __launch_bounds__(256) void repack2c_k(f16* __restrict__ dst, const float* __restrict__ src){
  for (int idx = blockIdx.x*256 + threadIdx.x; idx < 29184; idx += gridDim.x*256){
    int i = idx & 7, l = (idx >> 3) & 63, rest = idx >> 9;
    int mt = rest % 3, s = rest / 3;
    int co = mt*16 + (l & 15);
    int k = s*32 + (l >> 4)*8 + i;
    f16 v = (f16)0.0f;
    if (co < 36 && k < 600){
      int tap = k / 24, ci = k - tap*24;
      v = (f16)src[(co*24 + ci)*25 + tap];
    }
    dst[idx] = v;
  }
}
// w3m: [s29][mt3][lane64][8]
__global__ __launch_bounds__(256) void repack3m_k(f16* __restrict__ dst, const float* __restrict__ src){
  for (int idx = blockIdx.x*256 + threadIdx.x; idx < 44544; idx += gridDim.x*256){
    int i = idx & 7, l = (idx >> 3) & 63, rest = idx >> 9;
    int mt = rest % 3, s = rest / 3;
    int co = mt*16 + (l & 15);
    f16 v = (f16)0.0f;
    if (s < 25){
      int ci = (l >> 4)*8 + i;
      v = (f16)src[(co*36 + ci)*25 + s];
    } else {
      int ke = (s - 25)*32 + (l >> 4)*8 + i;
      if (ke < 100){
        int p = ke >> 2, ci = 32 + (ke & 3);
        v = (f16)src[(co*36 + ci)*25 + p];
      }
    }
    dst[idx] = v;
  }
}
// w4m: [s14][mt4][lane64][8]
__global__ __launch_bounds__(256) void repack4m_k(f16* __restrict__ dst, const float* __restrict__ src){
  for (int idx = blockIdx.x*256 + threadIdx.x; idx < 28672; idx += gridDim.x*256){
    int i = idx & 7, l = (idx >> 3) & 63, rest = idx >> 9;
    int mt = rest & 3, s = rest >> 2;
    int co = mt*16 + (l & 15);
    int k = s*32 + (l >> 4)*8 + i;
    f16 v = (f16)0.0f;
    if (k < 432){
      int pos = k / 48, ci = k - pos*48;
      v = (f16)src[(co*48 + ci)*9 + pos];
    }
    dst[idx] = v;
  }
}
// w1m (fc1): B-fragments [s160][nt7][lane64][8]
__global__ __launch_bounds__(256) void repackfc1_k(f16* __restrict__ dst, const float* __restrict__ src){
  for (int t = blockIdx.x*256 + threadIdx.x; t < 71680; t += gridDim.x*256){
    int l = t & 63, rest = t >> 6;
    int nt = rest % 7, s = rest / 7;
    int j = nt*16 + (l & 15);
    int kb = s*32 + (l >> 4)*8;
    union { f16 h[8]; f16x8 v; } pk;
    #pragma unroll
    for (int i=0;i<8;++i){
      int k = kb + i;
      int row = (k & 63)*80 + (k >> 6);
      pk.h[i] = (j < 100) ? (f16)src[(size_t)row*100 + j] : (f16)0.0f;
    }
    *(f16x8*)(dst + (size_t)t*8) = pk.v;
  }
}

// ---------------------------------------------------------------- conv1+conv2 fused (both MFMA)
__global__ __launch_bounds__(256) void conv12_k(const float* __restrict__ rgb, const f16* __restrict__ w1m,
                                                const float* __restrict__ b1, const f16* __restrict__ w2c,
                                                const float* __restrict__ b2, f16* __restrict__ a2, int ib){
  __shared__ __align__(16) f16 xb[75*44 + 8];      // [w][hh] stride 44, 6616 B
  __shared__ __align__(16) f16 xt[2*19*18*24];     // 32832 B
  const int tid = threadIdx.x, bx = blockIdx.x;
  const int i = bx / 6, t = bx - i*6;
  const int h0 = t*32, oh0 = t*8;
  const float* img = rgb + (size_t)(ib + i)*15000;
  for (int idx = tid; idx < 825; idx += 256){
    int w = idx / 11, h4 = idx - w*11;
    int h = h0 + h4*4;
    union { f16 hv[4]; uint2 u; } pk;
    if (h < 200){
      float4 v = *(const float4*)(img + w*200 + h);
      pk.hv[0] = (v.x > 0.f) ? (f16)1.0f : (f16)0.0f;
      pk.hv[1] = (v.y > 0.f) ? (f16)1.0f : (f16)0.0f;
      pk.hv[2] = (v.z > 0.f) ? (f16)1.0f : (f16)0.0f;
      pk.hv[3] = (v.w > 0.f) ? (f16)1.0f : (f16)0.0f;
    } else {
      pk.u.x = 0u; pk.u.y = 0u;
    }
    *(uint2*)(xb + w*44 + h4*4) = pk.u;
  }
  __syncthreads();
  const int wv = tid >> 6, lane = tid & 63;
  const int jgrp = lane >> 4, npx = lane & 15;
  // ---- phase 1: conv1 MFMA into xt
  {
    f16x8 a1f0 = *(const f16x8*)(w1m + (size_t)lane*8);
    f16x8 a1f1 = *(const f16x8*)(w1m + (size_t)(64 + lane)*8);
    int koff[8];
    #pragma unroll
    for (int ii=0; ii<8; ++ii){
      int k = jgrp*8 + ii;
      if (k >= 25) k = 0;
      int kw = k / 5, kh = k - kw*5;
      koff[ii] = kw*44 + kh;
    }
    f32x4 bv0, bv1;
    #pragma unroll
    for (int reg=0; reg<4; ++reg){
      int c0 = jgrp*4 + reg;
      int c1 = 16 + jgrp*4 + reg;
      bv0[reg] = b1[c0];
      bv1[reg] = (c1 < 24) ? b1[c1] : 0.f;
    }
    for (int q=0; q<11; ++q){
      int nt = wv + 4*q;
      if (nt > 42) break;
      int pxt = nt*16 + npx;
      int px = (pxt > 683) ? 683 : pxt;
      int rr = px/36, ow = px - rr*36;
      const f16* gp = xb + 2*ow*44 + 2*rr;
      union { f16 h[8]; f16x8 v; } bq;
      #pragma unroll
      for (int ii=0; ii<8; ++ii) bq.h[ii] = gp[koff[ii]];
      f32x4 c0 = __builtin_amdgcn_mfma_f32_16x16x32_f16(a1f0, bq.v, bv0, 0, 0, 0);
      f32x4 c1 = __builtin_amdgcn_mfma_f32_16x16x32_f16(a1f1, bq.v, bv1, 0, 0, 0);
      if (pxt <= 683){
        f16* dst = xt + (((ow & 1)*19 + rr)*18 + (ow >> 1))*24;
        union { f16 h[4]; uint2 q2; } pk;
        #pragma unroll
        for (int reg=0; reg<4; ++reg){ float r = c0[reg]; if (r<0.f) r=0.f; pk.h[reg]=(f16)r; }
        *(uint2*)(dst + jgrp*4) = pk.q2;
        if (jgrp < 2){
          #pragma unroll
          for (int reg=0; reg<4; ++reg){ float r = c1[reg]; if (r<0.f) r=0.f; pk.h[reg]=(f16)r; }
          *(uint2*)(dst + 16 + jgrp*4) = pk.q2;
        }
      }
    }
  }
  __syncthreads();
  // ---- phase 2: conv2 MFMA, K-packed
  int baddr[19];
  #pragma unroll
  for (int s=0; s<19; ++s){
    int m = s*4 + jgrp;
    int tap = m / 3, r3 = m - tap*3;
    if (m >= 75){ tap = 24; r3 = 0; }
    int kh = tap / 5, kw = tap - kh*5;
    int par = kw & 1, kws = kw >> 1;
    baddr[s] = ((par*19 + kh)*18 + npx + kws)*24 + r3*8;
  }
  f32x4 acc2[3][2];
  #pragma unroll
  for (int mt=0; mt<3; ++mt){
    f32x4 bv;
    #pragma unroll
    for (int reg=0; reg<4; ++reg){
      int co = mt*16 + jgrp*4 + reg;
      bv[reg] = (co < 36) ? b2[co] : 0.0f;
    }
    acc2[mt][0] = bv; acc2[mt][1] = bv;
  }
  const f16* agl = w2c + (size_t)lane*8;
  const int rowo = 4*wv*432;
  #pragma unroll
  for (int s=0; s<19; ++s){
    f16x8 af[3];
    #pragma unroll
    for (int mt=0; mt<3; ++mt)
      af[mt] = *(const f16x8*)(agl + (size_t)(s*3 + mt)*512);
    const f16* bb0 = xt + baddr[s] + rowo;
    f16x8 bf[2];
    bf[0] = *(const f16x8*)(bb0);
    bf[1] = *(const f16x8*)(bb0 + 2*432);
    #pragma unroll
    for (int mt=0; mt<3; ++mt)
      #pragma unroll
      for (int u=0; u<2; ++u)
        acc2[mt][u] = __builtin_amdgcn_mfma_f32_16x16x32_f16(af[mt], bf[u], acc2[mt][u], 0, 0, 0);
  }
  #pragma unroll
  for (int u=0; u<2; ++u){
    const int oh = oh0 + 2*wv + u;
    if (oh >= 47) continue;
    #pragma unroll
    for (int mt=0; mt<3; ++mt){
      const int co0s = mt*16 + jgrp*4;
      if (co0s >= 36) continue;
      union { f16 h[4]; uint2 q; } pk;
      #pragma unroll
      for (int reg=0; reg<4; ++reg){
        float r = acc2[mt][u][reg]; if (r < 0.f) r = 0.f;
        pk.h[reg] = (f16)r;
      }
      *(uint2*)(a2 + (((size_t)i*47 + oh)*16 + npx)*36 + co0s) = pk.q;
    }
  }
}

// ---------------------------------------------------------------- conv3+conv4 fused (per half-image)
__global__ __launch_bounds__(256) void conv34_k(const f16* __restrict__ a2, const f16* __restrict__ w3m,
                                                const float* __restrict__ b3, const f16* __restrict__ w4m,
                                                const float* __restrict__ b4, f16* __restrict__ a4){
  __shared__ __align__(16) f16 xt[27*680];     // 36720 B
  __shared__ __align__(16) f16 a3t[12*6*56];   // 8064 B
  const int tid = threadIdx.x, bx = blockIdx.x;
  const int i = bx >> 1, t = bx & 1;
  const int r0 = t*20, obase = t*10;
  {
    const uint2* s2 = (const uint2*)((const uint*)a2 + (size_t)i*13536);
    uint2* d = (uint2*)xt;
    for (int idx = tid; idx < 3888; idx += 256){
      int d2 = idx % 9, rc = idx / 9;
      int c = rc & 15, r = rc >> 4;
      int dwi = d2*2, jg = dwi >> 2, part = dwi & 3;
      d[(r*340 + jg*68 + c*4 + part) >> 1] = s2[((size_t)(r0 + r)*16 + c)*9 + d2];
    }
  }
  __syncthreads();
  const int wv = tid >> 6, lane = tid & 63;
  const int npx = lane & 15, jg = lane >> 4;
  {
    int baseq[2], ohl[2], owl[2];
    #pragma unroll
    for (int q=0;q<2;++q){
      int px = (wv*2+q)*16 + npx; if (px > 71) px = 71;
      ohl[q] = px/6; owl[q] = px - ohl[q]*6;
      baseq[q] = 2*ohl[q]*680 + jg*136 + 2*owl[q]*8;
    }
    f32x4 acc[3][2];
    #pragma unroll
    for (int mt=0;mt<3;++mt){
      f32x4 bv;
      #pragma unroll
      for (int reg=0;reg<4;++reg) bv[reg] = b3[mt*16 + jg*4 + reg];
      acc[mt][0]=bv; acc[mt][1]=bv;
    }
    const f16* agl = w3m + (size_t)lane*8;
    #pragma unroll 1
    for (int kh=0; kh<5; ++kh){
      #pragma unroll
      for (int kw=0; kw<5; ++kw){
        const int s = kh*5 + kw;
        f16x8 af[3];
        #pragma unroll
        for (int mt=0;mt<3;++mt)
          af[mt] = *(const f16x8*)(agl + (size_t)(s*3 + mt)*512);
        f16x8 bf[2];
        #pragma unroll
        for (int q=0;q<2;++q)
          bf[q] = *(const f16x8*)(xt + baseq[q] + kh*680 + kw*8);
        #pragma unroll
        for (int mt=0;mt<3;++mt)
          #pragma unroll
          for (int q=0;q<2;++q)
            acc[mt][q] = __builtin_amdgcn_mfma_f32_16x16x32_f16(af[mt], bf[q], acc[mt][q], 0, 0, 0);
      }
    }
    #pragma unroll
    for (int e=0;e<4;++e){
      const int s = 25 + e;
      f16x8 af[3];
      #pragma unroll
      for (int mt=0;mt<3;++mt)
        af[mt] = *(const f16x8*)(agl + (size_t)(s*3 + mt)*512);
      int p1 = e*8 + jg*2; int p2 = p1 + 1;
      if (p1 > 24) p1 = 24;
      if (p2 > 24) p2 = 24;
      const int kh1 = p1/5, kw1 = p1 - kh1*5;
      const int kh2 = p2/5, kw2 = p2 - kh2*5;
      #pragma unroll
      for (int q=0;q<2;++q){
        f16x4 lo = *(const f16x4*)(xt + (2*ohl[q]+kh1)*680 + 544 + (2*owl[q]+kw1)*8);
        f16x4 hi = *(const f16x4*)(xt + (2*ohl[q]+kh2)*680 + 544 + (2*owl[q]+kw2)*8);
        f16x8 bq = __builtin_shufflevector(lo, hi, 0,1,2,3,4,5,6,7);
        #pragma unroll
        for (int mt=0;mt<3;++mt)
          acc[mt][q] = __builtin_amdgcn_mfma_f32_16x16x32_f16(af[mt], bq, acc[mt][q], 0, 0, 0);
      }
    }
    #pragma unroll
    for (int q=0;q<2;++q){
      int px = (wv*2+q)*16 + npx;
      if (px >= 72) continue;
      #pragma unroll
      for (int mt=0;mt<3;++mt){
        union { f16 h[4]; uint2 q2; } pk;
        #pragma unroll
        for (int reg=0;reg<4;++reg){
          float r = acc[mt][q][reg]; if (r < 0.f) r = 0.f;
          pk.h[reg] = (f16)r;
        }
        *(uint2*)(a3t + px*56 + mt*16 + jg*4) = pk.q2;
      }
    }
  }
  __syncthreads();
  {
    f32x4 acc4[3];
    {
      f32x4 bv;
      #pragma unroll
      for (int reg=0;reg<4;++reg) bv[reg] = b4[wv*16 + jg*4 + reg];
      acc4[0]=bv; acc4[1]=bv; acc4[2]=bv;
    }
    int ohn[3], own[3];
    #pragma unroll
    for (int nt=0;nt<3;++nt){
      int px = nt*16 + npx; if (px > 39) px = 39;
      ohn[nt] = px >> 2; own[nt] = px & 3;
    }
    const f16* agl = w4m + (size_t)lane*8;
    #pragma unroll 1
    for (int s=0; s<14; ++s){
      f16x8 af = *(const f16x8*)(agl + (size_t)(s*4 + wv)*512);
      int k8 = s*32 + jg*8;
      int pos, ci0;
      if (k8 >= 432){ pos = 8; ci0 = 40; }
      else { pos = k8 / 48; ci0 = k8 - pos*48; }
      const int kh = pos/3, kw = pos - kh*3;
      #pragma unroll
      for (int nt=0;nt<3;++nt){
        const int r = ohn[nt] + kh, c = own[nt] + kw;
        f16x8 bq = *(const f16x8*)(a3t + (r*6 + c)*56 + ci0);
        acc4[nt] = __builtin_amdgcn_mfma_f32_16x16x32_f16(af, bq, acc4[nt], 0, 0, 0);
      }
    }
    #pragma unroll
    for (int nt=0;nt<3;++nt){
      int px = nt*16 + npx;
      if (px >= 40) continue;
      union { f16 h[4]; uint2 q2; } pk;
      #pragma unroll
      for (int reg=0;reg<4;++reg){
        float r = acc4[nt][reg]; if (r < 0.f) r = 0.f;
        pk.h[reg] = (f16)r;
      }
      *(uint2*)(a4 + ((size_t)i*80 + obase*4 + px)*64 + wv*16 + jg*4) = pk.q2;
    }
  }
}

// ---------------------------------------------------------------- fc1 (MFMA) + fc2..fc4 + AEBS fused
__global__ __launch_bounds__(256) void fc1tail_k(const f16* __restrict__ a4, const f16* __restrict__ w1m,
    const float* __restrict__ fc1b, const float* __restrict__ dist, const float* __restrict__ speed,
    const float* __restrict__ fW2, const float* __restrict__ fb2,
    const float* __restrict__ fW3, const float* __restrict__ fb3,
    const float* __restrict__ fW4, const float* __restrict__ fb4,
    const float* __restrict__ aW1, const float* __restrict__ ab1,
    const float* __restrict__ aW2, const float* __restrict__ ab2,
    const float* __restrict__ aW3, const float* __restrict__ ab3,
    float* __restrict__ out, int ib){
  __shared__ float red[4][64][28];
  __shared__ float x1s[16][100];
  __shared__ float h2s[16][50];
  __shared__ float h3s[16][10];
  __shared__ float stg[16];
  __shared__ float hb1[16][12];
  __shared__ float hb2[16][24];
  const int tid = threadIdx.x;
  const int wv = tid >> 6, lane = tid & 63;
  const int img0 = blockIdx.x*16;
  f32x4 acc[7];
  #pragma unroll
  for (int nt=0;nt<7;++nt) acc[nt] = (f32x4){0.f,0.f,0.f,0.f};
  const f16* ap = a4 + (size_t)(img0 + (lane & 15))*5120 + (lane >> 4)*8;
  const f16* bp = w1m + (size_t)lane*8;
  #pragma unroll 1
  for (int s = wv*40; s < wv*40 + 40; ++s){
    f16x8 av = *(const f16x8*)(ap + s*32);
    #pragma unroll
    for (int nt=0;nt<7;++nt){
      f16x8 bv = *(const f16x8*)(bp + (size_t)(s*7 + nt)*512);
      acc[nt] = __builtin_amdgcn_mfma_f32_16x16x32_f16(av, bv, acc[nt], 0, 0, 0);
    }
  }
  #pragma unroll
  for (int nt=0;nt<7;++nt)
    #pragma unroll
    for (int reg=0;reg<4;++reg)
      red[wv][lane][nt*4+reg] = acc[nt][reg];
  __syncthreads();
  for (int idx = tid; idx < 1792; idx += 256){
    int imgl = idx / 112, j = idx - imgl*112;
    if (j >= 100) continue;
    int l = ((imgl >> 2) << 4) | (j & 15);
    int c = (j >> 4)*4 + (imgl & 3);
    float s = red[0][l][c] + red[1][l][c] + red[2][l][c] + red[3][l][c] + fc1b[j];
    x1s[imgl][j] = s > 0.f ? s : 0.f;
  }
  __syncthreads();
  const int g = tid >> 4, l16 = tid & 15;
  const int img = ib + img0 + g;
  for (int j = l16; j < 50; j += 16){
    float s = fb2[j];
    #pragma unroll 4
    for (int k = 0; k < 100; ++k) s = fmaf(x1s[g][k], fW2[k*50+j], s);
    h2s[g][j] = s > 0.f ? s : 0.f;
  }
  __syncthreads();
  if (l16 < 10){
    float s = fb3[l16];
    #pragma unroll
    for (int k = 0; k < 50; ++k) s = fmaf(h2s[g][k], fW3[k*10+l16], s);
    h3s[g][l16] = s > 0.f ? s : 0.f;
  }
  __syncthreads();
  if (l16 == 0){
    float s = fb4[0];
    #pragma unroll
    for (int k = 0; k < 10; ++k) s = fmaf(h3s[g][k], fW4[k], s);
    stg[g] = s;
  }
  __syncthreads();
  if (l16 < 12){
    float s0 = stg[g], dd = dist[img], sp = speed[img];
    float s = ab1[l16] + s0*aW1[l16] + dd*aW1[12+l16] + sp*aW1[24+l16];
    hb1[g][l16] = s > 0.f ? s : 0.f;
  }
  __syncthreads();
  for (int j = l16; j < 24; j += 16){
    float s = ab2[j];
    #pragma unroll
    for (int k=0;k<12;++k) s = fmaf(hb1[g][k], aW2[k*24+j], s);
    hb2[g][j] = s > 0.f ? s : 0.f;
  }
  __syncthreads();
  if (l16 < 4){
    float s = ab3[l16];
    #pragma unroll
    for (int k=0;k<24;++k) s = fmaf(hb2[g][k], aW3[k*4+l16], s);
    out[(size_t)img*4 + l16] = s;
  }
}

// ================================================================ host
extern "C" void kernel_launch(void* const* d_in, const int* in_sizes, int n_in,
                              void* d_out, int out_size, void* d_ws, size_t ws_size,
                              hipStream_t stream){
  const float* rgb   = (const float*)d_in[0];
  const float* dist  = (const float*)d_in[1];
  const float* speed = (const float*)d_in[2];
  const float* cw1 = (const float*)d_in[3];
  const float* cb1 = (const float*)d_in[4];
  const float* cw2 = (const float*)d_in[5];
  const float* cb2 = (const float*)d_in[6];
  const float* cw3 = (const float*)d_in[7];
  const float* cb3 = (const float*)d_in[8];
  const float* cw4 = (const float*)d_in[9];
  const float* cb4 = (const float*)d_in[10];
  const float* fW1 = (const float*)d_in[11];
  const float* fb1 = (const float*)d_in[12];
  const float* fW2 = (const float*)d_in[13];
  const float* fb2 = (const float*)d_in[14];
  const float* fW3 = (const float*)d_in[15];
  const float* fb3 = (const float*)d_in[16];
  const float* fW4 = (const float*)d_in[17];
  const float* fb4 = (const float*)d_in[18];
  const float* aW1 = (const float*)d_in[19];
  const float* ab1 = (const float*)d_in[20];
  const float* aW2 = (const float*)d_in[21];
  const float* ab2 = (const float*)d_in[22];
  const float* aW3 = (const float*)d_in[23];
  const float* ab3 = (const float*)d_in[24];
  float* out = (float*)d_out;
  const int B = in_sizes[0] / 15000;

  auto ALN = [](size_t x){ return (x + 255) & ~(size_t)255; };
  const size_t fixed = ALN(2048) + ALN(58368) + ALN(89088) + ALN(57344) + ALN(1146880);

  int nc = 1;
  while (nc < 32){
    size_t Bc = (size_t)(B / nc);
    size_t need = fixed + ALN(Bc*54144) + ALN(Bc*10240);
    if (need <= ws_size) break;
    nc *= 2;
  }
  const int Bc = B / nc;

  char* ws = (char*)d_ws;
  size_t o = 0;
  auto alloc = [&](size_t bytes)->char*{ char* p = ws + o; o += ALN(bytes); return p; };
  f16* w1c = (f16*)alloc(2048);
  f16* w2c = (f16*)alloc(58368);
  f16* w3m = (f16*)alloc(89088);
  f16* w4m = (f16*)alloc(57344);
  f16* w1m = (f16*)alloc(1146880);
  f16* a2  = (f16*)alloc((size_t)Bc*54144);
  f16* a4  = (f16*)alloc((size_t)Bc*10240);

  repack1m_k<<<dim3(4),   dim3(256), 0, stream>>>(w1c, cw1);
  repack2c_k<<<dim3(114), dim3(256), 0, stream>>>(w2c, cw2);
  repack3m_k<<<dim3(174), dim3(256), 0, stream>>>(w3m, cw3);
  repack4m_k<<<dim3(112), dim3(256), 0, stream>>>(w4m, cw4);
  repackfc1_k<<<dim3(280), dim3(256), 0, stream>>>(w1m, fW1);

  for (int c = 0; c < nc; ++c){
    const int ib = c*Bc;
    conv12_k<<<dim3(Bc*6),   dim3(256), 0, stream>>>(rgb, w1c, cb1, w2c, cb2, a2, ib);
    conv34_k<<<dim3(Bc*2),   dim3(256), 0, stream>>>(a2, w3m, cb3, w4m, cb4, a4);
    fc1tail_k<<<dim3(Bc/16), dim3(256), 0, stream>>>(a4, w1m, fb1, dist, speed,
        fW2, fb2, fW3, fb3, fW4, fb4, aW1, ab1, aW2, ab2, aW3, ab3, out, ib);
  }
}